// Round 1
// baseline (3406.915 us; speedup 1.0000x reference)
//
#include <hip/hip_runtime.h>

#define NVV 100000
#define NSV 50000
#define E_VV 1600000
#define E_H  800000
#define E_IN 800000
#define E_SS 800000
#define DIN 5
#define HD 64

// ---------------- Phase A: v-graph (RGCN + TAG in 5-dim space) ----------------

__global__ void k_rgcn_edge(const float* __restrict__ x,
                            const int* __restrict__ src, const int* __restrict__ dst,
                            const int* __restrict__ et,
                            float* __restrict__ relsum, float* __restrict__ relcnt) {
  int e = blockIdx.x * 256 + threadIdx.x;
  if (e >= E_VV) return;
  int s = src[e], d = dst[e], r = et[e];
  const float* xs = x + s * DIN;
  float* rs = relsum + (r * NVV + d) * DIN;
#pragma unroll
  for (int j = 0; j < DIN; j++) atomicAdd(rs + j, xs[j]);
  atomicAdd(relcnt + r * NVV + d, 1.0f);
}

__global__ void k_dinv_v(const float* __restrict__ relcnt, float* __restrict__ dinv) {
  int i = blockIdx.x * 256 + threadIdx.x;
  if (i >= NVV) return;
  float d = relcnt[i] + relcnt[NVV + i] + relcnt[2 * NVV + i];
  dinv[i] = d > 0.f ? rsqrtf(d) : 0.f;
}

__global__ void k_tag_hop5(const float* __restrict__ hin,
                           const int* __restrict__ src, const int* __restrict__ dst,
                           const float* __restrict__ dinv, float* __restrict__ hout) {
  int e = blockIdx.x * 256 + threadIdx.x;
  if (e >= E_VV) return;
  int s = src[e], d = dst[e];
  float w = dinv[s] * dinv[d];
  const float* hs = hin + s * DIN;
  float* ho = hout + d * DIN;
#pragma unroll
  for (int j = 0; j < DIN; j++) atomicAdd(ho + j, w * hs[j]);
}

// gx[v] = x@(W1_root+W12_0) + sum_r (relsum_r/max(c,1))@W1_rel[r] + sum_k h_k@W12[k] + (b1+b12)
__global__ __launch_bounds__(256)
void k_combine_gx(const float* __restrict__ x,
                  const float* __restrict__ relsum, const float* __restrict__ relcnt,
                  const float* __restrict__ hbuf,
                  const float* __restrict__ W1_rel, const float* __restrict__ W1_root,
                  const float* __restrict__ b1,
                  const float* __restrict__ W12, const float* __restrict__ b12,
                  float* __restrict__ gx) {
  __shared__ float Ws[7 * 320];
  __shared__ float bs[64];
  int tid = threadIdx.x;
  for (int i = tid; i < 320; i += 256) {
    Ws[i]        = W1_root[i] + W12[i];       // term 0: x
    Ws[320 + i]  = W1_rel[i];                 // terms 1-3: relation means
    Ws[640 + i]  = W1_rel[320 + i];
    Ws[960 + i]  = W1_rel[640 + i];
    Ws[1280 + i] = W12[320 + i];              // terms 4-6: TAG hops
    Ws[1600 + i] = W12[640 + i];
    Ws[1920 + i] = W12[960 + i];
  }
  if (tid < 64) bs[tid] = b1[tid] + b12[tid];
  __syncthreads();
  int v = blockIdx.x * 4 + (tid >> 6);
  if (v >= NVV) return;
  int f = tid & 63;
  float in[35];
#pragma unroll
  for (int j = 0; j < DIN; j++) in[j] = x[v * DIN + j];
#pragma unroll
  for (int r = 0; r < 3; r++) {
    float inv = 1.0f / fmaxf(relcnt[r * NVV + v], 1.0f);
#pragma unroll
    for (int j = 0; j < DIN; j++) in[5 + r * 5 + j] = relsum[(r * NVV + v) * DIN + j] * inv;
  }
#pragma unroll
  for (int kk = 0; kk < 3; kk++)
#pragma unroll
    for (int j = 0; j < DIN; j++) in[20 + kk * 5 + j] = hbuf[kk * NVV * DIN + v * DIN + j];
  float acc = bs[f];
#pragma unroll
  for (int t = 0; t < 35; t++) acc += in[t] * Ws[t * 64 + f];
  gx[v * 64 + f] = acc;
}

// ---------------- 64-dim edge aggregation (wave-per-edge, lane=feature) ----------------

__global__ void k_agg_h(const float* __restrict__ gx,
                        const int* __restrict__ src, const int* __restrict__ dst,
                        const float* __restrict__ ew,
                        float* __restrict__ aggw, float* __restrict__ aggu,
                        float* __restrict__ cnt) {
  int gid = blockIdx.x * 256 + threadIdx.x;
  int e = gid >> 6, f = gid & 63;
  if (e >= E_H) return;
  int s = src[e], d = dst[e];
  float v = gx[s * 64 + f];
  atomicAdd(aggu + d * 64 + f, v);
  atomicAdd(aggw + d * 64 + f, ew[e] * v);
  if (f == 0) atomicAdd(cnt + d, 1.0f);
}

__global__ void k_agg_u(const float* __restrict__ xsrc,
                        const int* __restrict__ src, const int* __restrict__ dst,
                        float* __restrict__ agg, float* __restrict__ cnt, int ne) {
  int gid = blockIdx.x * 256 + threadIdx.x;
  int e = gid >> 6, f = gid & 63;
  if (e >= ne) return;
  int s = src[e], d = dst[e];
  atomicAdd(agg + d * 64 + f, xsrc[s * 64 + f]);
  if (f == 0 && cnt) atomicAdd(cnt + d, 1.0f);
}

__global__ void k_deg(const int* __restrict__ dst, float* __restrict__ deg, int ne) {
  int e = blockIdx.x * 256 + threadIdx.x;
  if (e >= ne) return;
  atomicAdd(deg + dst[e], 1.0f);
}

__global__ void k_rsqrt_deg(const float* __restrict__ deg, float* __restrict__ dinv, int n) {
  int i = blockIdx.x * 256 + threadIdx.x;
  if (i >= n) return;
  float d = deg[i];
  dinv[i] = d > 0.f ? rsqrtf(d) : 0.f;
}

__global__ void k_tag_hop64(const float* __restrict__ hin,
                            const int* __restrict__ src, const int* __restrict__ dst,
                            const float* __restrict__ dinv, float* __restrict__ hout, int ne) {
  int gid = blockIdx.x * 256 + threadIdx.x;
  int e = gid >> 6, f = gid & 63;
  if (e >= ne) return;
  int s = src[e], d = dst[e];
  float w = dinv[s] * dinv[d];
  atomicAdd(hout + d * 64 + f, w * hin[s * 64 + f]);
}

// ---------------- Fused node matmul: out = [relu]( [out +] A'@WA + B@WB + bias ) ----------------
// A' = A / max(cntA,1) if cntA. 64 nodes/block; each lane: 4 nodes x 4 feats.

__global__ __launch_bounds__(256)
void k_node_mm(const float* __restrict__ A, const float* __restrict__ cntA,
               const float* __restrict__ WA,
               const float* __restrict__ B, int DB,
               const float* __restrict__ WB,
               const float* __restrict__ bias,
               float* __restrict__ out, int n, int dorelu, int accum) {
  __shared__ float WAs[64 * 64];
  __shared__ float WBs[64 * 64];
  __shared__ float bs[64];
  __shared__ float as[64 * 68];
  const int tid = threadIdx.x;
  {
    const float4* w4 = (const float4*)WA;
    float4* s4 = (float4*)WAs;
    for (int i = tid; i < 1024; i += 256) s4[i] = w4[i];
    if (B) {
      const float4* wb4 = (const float4*)WB;
      float4* sb4 = (float4*)WBs;
      int nb = DB * 16;
      for (int i = tid; i < nb; i += 256) sb4[i] = wb4[i];
    }
    if (tid < 64) bs[tid] = bias ? bias[tid] : 0.0f;
  }
  const int gb = blockIdx.x * 64;
  // stage A (optionally mean-scaled), float4, padded stride 68 (16B-aligned, 2-way-free banks)
  for (int i = tid; i < 1024; i += 256) {
    int nl = i >> 4, k4 = i & 15;
    int g = gb + nl;
    float4 v = make_float4(0.f, 0.f, 0.f, 0.f);
    if (g < n) {
      v = ((const float4*)A)[g * 16 + k4];
      if (cntA) {
        float sc = 1.0f / fmaxf(cntA[g], 1.0f);
        v.x *= sc; v.y *= sc; v.z *= sc; v.w *= sc;
      }
    }
    *(float4*)(&as[nl * 68 + k4 * 4]) = v;
  }
  __syncthreads();
  const int lane = tid & 63;
  const int fq = lane & 15, nq = lane >> 4;
  const int f0 = fq * 4;
  const int nl0 = (tid >> 6) * 16 + nq * 4;
  float acc[4][4];
#pragma unroll
  for (int j = 0; j < 4; j++)
#pragma unroll
    for (int jj = 0; jj < 4; jj++) acc[j][jj] = 0.f;
#pragma unroll 4
  for (int k = 0; k < 64; k++) {
    float4 w = *(const float4*)(&WAs[k * 64 + f0]);
#pragma unroll
    for (int j = 0; j < 4; j++) {
      float a = as[(nl0 + j) * 68 + k];
      acc[j][0] += a * w.x; acc[j][1] += a * w.y; acc[j][2] += a * w.z; acc[j][3] += a * w.w;
    }
  }
  if (B) {
    __syncthreads();
    if (DB == 64) {
      for (int i = tid; i < 1024; i += 256) {
        int nl = i >> 4, k4 = i & 15;
        int g = gb + nl;
        float4 v = make_float4(0.f, 0.f, 0.f, 0.f);
        if (g < n) v = ((const float4*)B)[g * 16 + k4];
        *(float4*)(&as[nl * 68 + k4 * 4]) = v;
      }
    } else {
      for (int i = tid; i < 64 * DB; i += 256) {
        int nl = i / DB, k = i - nl * DB;
        int g = gb + nl;
        as[nl * 68 + k] = (g < n) ? B[g * DB + k] : 0.f;
      }
    }
    __syncthreads();
    for (int k = 0; k < DB; k++) {
      float4 w = *(const float4*)(&WBs[k * 64 + f0]);
#pragma unroll
      for (int j = 0; j < 4; j++) {
        float a = as[(nl0 + j) * 68 + k];
        acc[j][0] += a * w.x; acc[j][1] += a * w.y; acc[j][2] += a * w.z; acc[j][3] += a * w.w;
      }
    }
  }
#pragma unroll
  for (int j = 0; j < 4; j++) {
    int g = gb + nl0 + j;
    if (g < n) {
#pragma unroll
      for (int jj = 0; jj < 4; jj++) {
        int f = f0 + jj;
        float v = acc[j][jj] + bs[f];
        if (accum) v += out[g * 64 + f];
        if (dorelu) v = fmaxf(v, 0.f);
        out[g * 64 + f] = v;
      }
    }
  }
}

// ---------------- Final projection: out = X @ Wl + bl  (64 -> 8) ----------------

__global__ void k_final(const float* __restrict__ X, const float* __restrict__ Wl,
                        const float* __restrict__ bl, float* __restrict__ out) {
  __shared__ float Ws[64 * 8];
  __shared__ float bsh[8];
  int tid = threadIdx.x;
  for (int i = tid; i < 512; i += 256) Ws[i] = Wl[i];
  if (tid < 8) bsh[tid] = bl[tid];
  __syncthreads();
  int gid = blockIdx.x * 256 + tid;
  if (gid >= NSV * 8) return;
  int v = gid >> 3, f = gid & 7;
  float acc = bsh[f];
  const float* xr = X + v * 64;
#pragma unroll 8
  for (int k = 0; k < 64; k++) acc += xr[k] * Ws[k * 8 + f];
  out[gid] = acc;
}

// ---------------- Host ----------------

extern "C" void kernel_launch(void* const* d_in, const int* in_sizes, int n_in,
                              void* d_out, int out_size, void* d_ws, size_t ws_size,
                              hipStream_t stream) {
  const float* game_x  = (const float*)d_in[0];
  const float* state_x = (const float*)d_in[1];
  const int*   ei_vv   = (const int*)d_in[2];
  const int*   et_vv   = (const int*)d_in[3];
  const int*   ei_h    = (const int*)d_in[4];
  const float* ew_h    = (const float*)d_in[5];
  const int*   ei_in   = (const int*)d_in[6];
  const int*   ei_ss   = (const int*)d_in[7];
  const float* W1_rel  = (const float*)d_in[8];
  const float* W1_root = (const float*)d_in[9];
  const float* b1      = (const float*)d_in[10];
  const float* W12     = (const float*)d_in[11];
  const float* b12     = (const float*)d_in[12];
  const float* W2      = (const float*)d_in[13];
  const float* b2      = (const float*)d_in[14];
  const float* W3_rel  = (const float*)d_in[15];
  const float* W3_root = (const float*)d_in[16];
  const float* b3      = (const float*)d_in[17];
  const float* W32_l   = (const float*)d_in[18];
  const float* W32_r   = (const float*)d_in[19];
  const float* b32     = (const float*)d_in[20];
  const float* W4_l    = (const float*)d_in[21];
  const float* W4_r    = (const float*)d_in[22];
  const float* b4      = (const float*)d_in[23];
  const float* W42_l   = (const float*)d_in[24];
  const float* W42_r   = (const float*)d_in[25];
  const float* b42     = (const float*)d_in[26];
  const float* W5_l    = (const float*)d_in[27];
  const float* W5_r    = (const float*)d_in[28];
  const float* b5      = (const float*)d_in[29];
  const float* Wl      = (const float*)d_in[30];
  const float* bl      = (const float*)d_in[31];

  // Workspace layout (floats), ~99.4 MiB total, phase-based reuse:
  float* ws     = (float*)d_ws;
  float* relsum = ws + 0;          // 1,500,000   [phase A]
  float* relcnt = ws + 1500000;    //   300,000   [phase A]
  float* hbuf   = ws + 1800000;    // 1,500,000   [phase A] h1,h2,h3
  float* dinv_v = ws + 3300000;    //   100,000   [phase A]
  float* gx     = ws + 3400000;    // 6,400,000   [A->B]; reused as t1,t2 in D
  float* t1     = gx;
  float* t2     = gx + 3200000;
  float* t3     = ws + 0;          // reuse relsum/relcnt/hbuf region (dead after combine_gx)
  float* aggHw  = ws + 9800000;    // 3,200,000   [B->C]; reused as aggSS in E
  float* aggHu  = ws + 13000000;   // 3,200,000
  float* aggIN  = ws + 16200000;   // 3,200,000
  float* cntH   = ws + 19400000;   //    64,000
  float* cntIN  = ws + 19464000;   //    64,000
  float* S1     = ws + 19528000;   // 3,200,000   ping
  float* S2     = ws + 22728000;   // 3,200,000   pong
  float* degS   = ws + 25928000;   //    64,000
  float* dinvS  = ws + 25992000;   //    64,000   => total 26,056,000 floats
  float* aggSS  = aggHw;

  const int* src_vv = ei_vv;  const int* dst_vv = ei_vv + E_VV;
  const int* src_h  = ei_h;   const int* dst_h  = ei_h + E_H;
  const int* src_in = ei_in;  const int* dst_in = ei_in + E_IN;
  const int* src_ss = ei_ss;  const int* dst_ss = ei_ss + E_SS;

  auto nblk = [](long long n) { return dim3((unsigned)((n + 255) / 256)); };

  // ---- Phase A: v-graph, 5-dim aggregation ----
  hipMemsetAsync(relsum, 0, 3300000 * sizeof(float), stream);  // relsum+relcnt+hbuf
  k_rgcn_edge<<<nblk(E_VV), 256, 0, stream>>>(game_x, src_vv, dst_vv, et_vv, relsum, relcnt);
  k_dinv_v<<<nblk(NVV), 256, 0, stream>>>(relcnt, dinv_v);
  k_tag_hop5<<<nblk(E_VV), 256, 0, stream>>>(game_x, src_vv, dst_vv, dinv_v, hbuf);
  k_tag_hop5<<<nblk(E_VV), 256, 0, stream>>>(hbuf, src_vv, dst_vv, dinv_v, hbuf + 500000);
  k_tag_hop5<<<nblk(E_VV), 256, 0, stream>>>(hbuf + 500000, src_vv, dst_vv, dinv_v, hbuf + 1000000);
  k_combine_gx<<<dim3((NVV + 3) / 4), 256, 0, stream>>>(game_x, relsum, relcnt, hbuf,
                                                        W1_rel, W1_root, b1, W12, b12, gx);

  // ---- Phase B: aggregate gx into state nodes (EH: weighted+plain+count; EIN: plain+count) ----
  hipMemsetAsync(aggHw, 0, 9728000 * sizeof(float), stream);
  k_agg_h<<<nblk((long long)E_H * 64), 256, 0, stream>>>(gx, src_h, dst_h, ew_h, aggHw, aggHu, cntH);
  k_agg_u<<<nblk((long long)E_IN * 64), 256, 0, stream>>>(gx, src_in, dst_in, aggIN, cntIN, E_IN);

  // ---- Phase C: graph_conv + 3x SAGE (fused node matmuls) ----
  const int NB = (NSV + 63) / 64;
  k_node_mm<<<NB, 256, 0, stream>>>(aggHw, nullptr, W3_rel, state_x, 5, W3_root, b3, S1, NSV, 1, 0);
  k_node_mm<<<NB, 256, 0, stream>>>(aggHu, cntH,   W32_l, S1, 64, W32_r, b32, S2, NSV, 1, 0);
  k_node_mm<<<NB, 256, 0, stream>>>(aggIN, cntIN,  W4_l,  S2, 64, W4_r,  b4,  S1, NSV, 1, 0);
  k_node_mm<<<NB, 256, 0, stream>>>(aggIN, cntIN,  W42_l, S1, 64, W42_r, b42, S2, NSV, 1, 0);  // sx42

  // ---- Phase D: TAG on s-s graph (64-dim hops) ----
  hipMemsetAsync(t1, 0, 6400000 * sizeof(float), stream);   // t1,t2 (old gx region)
  hipMemsetAsync(t3, 0, 3200000 * sizeof(float), stream);
  hipMemsetAsync(degS, 0, 64000 * sizeof(float), stream);
  k_deg<<<nblk(E_SS), 256, 0, stream>>>(dst_ss, degS, E_SS);
  k_rsqrt_deg<<<nblk(NSV), 256, 0, stream>>>(degS, dinvS, NSV);
  k_tag_hop64<<<nblk((long long)E_SS * 64), 256, 0, stream>>>(S2, src_ss, dst_ss, dinvS, t1, E_SS);
  k_tag_hop64<<<nblk((long long)E_SS * 64), 256, 0, stream>>>(t1, src_ss, dst_ss, dinvS, t2, E_SS);
  k_tag_hop64<<<nblk((long long)E_SS * 64), 256, 0, stream>>>(t2, src_ss, dst_ss, dinvS, t3, E_SS);
  k_node_mm<<<NB, 256, 0, stream>>>(S2, nullptr, W2,          t1, 64, W2 + 4096,  b2,      S1, NSV, 0, 0);
  k_node_mm<<<NB, 256, 0, stream>>>(t2, nullptr, W2 + 8192,   t3, 64, W2 + 12288, nullptr, S1, NSV, 1, 1); // sx6

  // ---- Phase E: SAGE on s-s ----
  hipMemsetAsync(aggSS, 0, 3200000 * sizeof(float), stream);
  k_agg_u<<<nblk((long long)E_SS * 64), 256, 0, stream>>>(S1, src_ss, dst_ss, aggSS, nullptr, E_SS);
  k_node_mm<<<NB, 256, 0, stream>>>(aggSS, degS, W5_l, S1, 64, W5_r, b5, S2, NSV, 1, 0);

  // ---- Final projection ----
  k_final<<<nblk(NSV * 8), 256, 0, stream>>>(S2, Wl, bl, (float*)d_out);
}

// Round 2
// 1384.739 us; speedup vs baseline: 2.4603x; 2.4603x over previous
//
#include <hip/hip_runtime.h>

#define NVV 100000
#define NSV 50000
#define E_VV 1600000
#define E_H  800000
#define E_IN 800000
#define E_SS 800000
#define DIN 5
#define HD 64

// ====================== CSR build (per-call, int-only) ======================

__global__ void k_count(const int* __restrict__ dst, int* __restrict__ cnt, int ne) {
  int e = blockIdx.x * 256 + threadIdx.x;
  if (e >= ne) return;
  atomicAdd(&cnt[dst[e]], 1);
}

// pass 1: per-block (1024 elems) totals
__global__ void k_scan_bsum(const int* __restrict__ cnt, int* __restrict__ bsum, int n) {
  int tid = threadIdx.x, b = blockIdx.x;
  int base = b * 1024 + tid * 4;
  int s = 0;
#pragma unroll
  for (int i = 0; i < 4; i++) { int idx = base + i; if (idx < n) s += cnt[idx]; }
  __shared__ int sd[256];
  sd[tid] = s; __syncthreads();
  for (int off = 128; off > 0; off >>= 1) {
    if (tid < off) sd[tid] += sd[tid + off];
    __syncthreads();
  }
  if (tid == 0) bsum[b] = sd[0];
}

// pass 2: single-block exclusive scan of block sums (g <= 256)
__global__ void k_scan_carry(const int* __restrict__ bsum, int* __restrict__ bscan, int g) {
  int tid = threadIdx.x;
  __shared__ int sd[256];
  int my = (tid < g) ? bsum[tid] : 0;
  sd[tid] = my; __syncthreads();
  for (int off = 1; off < 256; off <<= 1) {
    int t = (tid >= off) ? sd[tid - off] : 0;
    __syncthreads();
    sd[tid] += t;
    __syncthreads();
  }
  if (tid < g) bscan[tid] = sd[tid] - my;
}

// pass 3: final exclusive scan -> rowstart, and an identical mutable cursor copy
__global__ void k_scan_write(const int* __restrict__ cnt, const int* __restrict__ bscan,
                             int* __restrict__ rowstart, int* __restrict__ cursor, int n) {
  int tid = threadIdx.x, b = blockIdx.x;
  int base = b * 1024 + tid * 4;
  int v[4]; int s = 0;
#pragma unroll
  for (int i = 0; i < 4; i++) { int idx = base + i; v[i] = (idx < n) ? cnt[idx] : 0; s += v[i]; }
  __shared__ int sd[256];
  sd[tid] = s; __syncthreads();
  for (int off = 1; off < 256; off <<= 1) {
    int t = (tid >= off) ? sd[tid - off] : 0;
    __syncthreads();
    sd[tid] += t;
    __syncthreads();
  }
  int run = bscan[b] + sd[tid] - s;   // exclusive offset for this thread's 4 elems
#pragma unroll
  for (int i = 0; i < 4; i++) {
    int idx = base + i;
    if (idx < n) { rowstart[idx] = run; cursor[idx] = run; run += v[i]; }
  }
}

__global__ void k_fill_vv(const int* __restrict__ src, const int* __restrict__ dst,
                          const int* __restrict__ et,
                          int* __restrict__ cursor, int* __restrict__ payload) {
  int e = blockIdx.x * 256 + threadIdx.x;
  if (e >= E_VV) return;
  int p = atomicAdd(&cursor[dst[e]], 1);
  payload[p] = (et[e] << 20) | src[e];   // src < 2^17, rel < 4
}

__global__ void k_fill_w(const int* __restrict__ src, const int* __restrict__ dst,
                         const float* __restrict__ ew,
                         int* __restrict__ cursor, int* __restrict__ srcs,
                         float* __restrict__ wout, int ne) {
  int e = blockIdx.x * 256 + threadIdx.x;
  if (e >= ne) return;
  int p = atomicAdd(&cursor[dst[e]], 1);
  srcs[p] = src[e]; wout[p] = ew[e];
}

__global__ void k_fill(const int* __restrict__ src, const int* __restrict__ dst,
                       int* __restrict__ cursor, int* __restrict__ srcs, int ne) {
  int e = blockIdx.x * 256 + threadIdx.x;
  if (e >= ne) return;
  int p = atomicAdd(&cursor[dst[e]], 1);
  srcs[p] = src[e];
}

__global__ void k_rsqrt_deg(const int* __restrict__ deg, float* __restrict__ dinv, int n) {
  int i = blockIdx.x * 256 + threadIdx.x;
  if (i >= n) return;
  float d = (float)deg[i];
  dinv[i] = d > 0.f ? rsqrtf(d) : 0.f;
}

// ====================== Phase A: v-graph (5-dim, gather) ======================

// Fused: RGCN per-rel sums+counts AND TAG hop-1, one gather pass. Thread per dst.
__global__ void k_vv_pass1(const float* __restrict__ x,
                           const int* __restrict__ rowstart, const int* __restrict__ cnt,
                           const int* __restrict__ payload, const float* __restrict__ dinv,
                           float* __restrict__ relagg,   // [NVV][15]
                           float* __restrict__ relcnt3,  // [NVV][3]
                           float* __restrict__ h1) {     // [NVV][5]
  int d = blockIdx.x * 256 + threadIdx.x;
  if (d >= NVV) return;
  int rs = rowstart[d], c = cnt[d];
  float a0[5] = {0,0,0,0,0}, a1[5] = {0,0,0,0,0}, a2[5] = {0,0,0,0,0}, h[5] = {0,0,0,0,0};
  int c0 = 0, c1 = 0, c2 = 0;
  for (int j = 0; j < c; j++) {
    int p = payload[rs + j];
    int s = p & 0xFFFFF, r = p >> 20;
    float xs[5];
#pragma unroll
    for (int k = 0; k < 5; k++) xs[k] = x[s * 5 + k];
    float w = dinv[s];
#pragma unroll
    for (int k = 0; k < 5; k++) h[k] += w * xs[k];
    if (r == 0) {
#pragma unroll
      for (int k = 0; k < 5; k++) a0[k] += xs[k];
      c0++;
    } else if (r == 1) {
#pragma unroll
      for (int k = 0; k < 5; k++) a1[k] += xs[k];
      c1++;
    } else {
#pragma unroll
      for (int k = 0; k < 5; k++) a2[k] += xs[k];
      c2++;
    }
  }
  float dv = dinv[d];
#pragma unroll
  for (int k = 0; k < 5; k++) {
    relagg[d * 15 + k]      = a0[k];
    relagg[d * 15 + 5 + k]  = a1[k];
    relagg[d * 15 + 10 + k] = a2[k];
    h1[d * 5 + k] = dv * h[k];
  }
  relcnt3[d * 3 + 0] = (float)c0;
  relcnt3[d * 3 + 1] = (float)c1;
  relcnt3[d * 3 + 2] = (float)c2;
}

// One sym-normalized 5-dim hop: hout[d] = dinv[d] * sum_j dinv[src] * hin[src]
__global__ void k_vv_hop(const float* __restrict__ hin,
                         const int* __restrict__ rowstart, const int* __restrict__ cnt,
                         const int* __restrict__ payload, const float* __restrict__ dinv,
                         float* __restrict__ hout) {
  int d = blockIdx.x * 256 + threadIdx.x;
  if (d >= NVV) return;
  int rs = rowstart[d], c = cnt[d];
  float h[5] = {0,0,0,0,0};
  for (int j = 0; j < c; j++) {
    int s = payload[rs + j] & 0xFFFFF;
    float w = dinv[s];
#pragma unroll
    for (int k = 0; k < 5; k++) h[k] += w * hin[s * 5 + k];
  }
  float dv = dinv[d];
#pragma unroll
  for (int k = 0; k < 5; k++) hout[d * 5 + k] = dv * h[k];
}

// gx[v] = x@(W1_root+W12_0) + sum_r mean_r@W1_rel[r] + sum_k h_k@W12[k] + (b1+b12)
__global__ __launch_bounds__(256)
void k_combine_gx(const float* __restrict__ x,
                  const float* __restrict__ relagg, const float* __restrict__ relcnt3,
                  const float* __restrict__ hbuf,
                  const float* __restrict__ W1_rel, const float* __restrict__ W1_root,
                  const float* __restrict__ b1,
                  const float* __restrict__ W12, const float* __restrict__ b12,
                  float* __restrict__ gx) {
  __shared__ float Ws[7 * 320];
  __shared__ float bs[64];
  int tid = threadIdx.x;
  for (int i = tid; i < 320; i += 256) {
    Ws[i]        = W1_root[i] + W12[i];       // term 0: x
    Ws[320 + i]  = W1_rel[i];                 // terms 1-3: relation means
    Ws[640 + i]  = W1_rel[320 + i];
    Ws[960 + i]  = W1_rel[640 + i];
    Ws[1280 + i] = W12[320 + i];              // terms 4-6: TAG hops
    Ws[1600 + i] = W12[640 + i];
    Ws[1920 + i] = W12[960 + i];
  }
  if (tid < 64) bs[tid] = b1[tid] + b12[tid];
  __syncthreads();
  int v = blockIdx.x * 4 + (tid >> 6);
  if (v >= NVV) return;
  int f = tid & 63;
  float in[35];
#pragma unroll
  for (int j = 0; j < DIN; j++) in[j] = x[v * DIN + j];
#pragma unroll
  for (int r = 0; r < 3; r++) {
    float inv = 1.0f / fmaxf(relcnt3[v * 3 + r], 1.0f);
#pragma unroll
    for (int j = 0; j < DIN; j++) in[5 + r * 5 + j] = relagg[v * 15 + r * 5 + j] * inv;
  }
#pragma unroll
  for (int kk = 0; kk < 3; kk++)
#pragma unroll
    for (int j = 0; j < DIN; j++) in[20 + kk * 5 + j] = hbuf[kk * NVV * DIN + v * DIN + j];
  float acc = bs[f];
#pragma unroll
  for (int t = 0; t < 35; t++) acc += in[t] * Ws[t * 64 + f];
  gx[v * 64 + f] = acc;
}

// ================= 64-dim CSR aggregation (wave per dst, lane=feature) =================

// h-graph: weighted sum + plain sum in one pass
__global__ __launch_bounds__(256)
void k_agg_h64(const float* __restrict__ X,
               const int* __restrict__ rowstart, const int* __restrict__ cnt,
               const int* __restrict__ srcs, const float* __restrict__ w,
               float* __restrict__ outw, float* __restrict__ outu) {
  int wid = blockIdx.x * 4 + (threadIdx.x >> 6);
  if (wid >= NSV) return;
  int lane = threadIdx.x & 63;
  int rs = rowstart[wid], c = cnt[wid];
  float aw = 0.f, au = 0.f;
  for (int j = 0; j < c; j++) {
    int s = srcs[rs + j];          // wave-broadcast
    float we = w[rs + j];          // wave-broadcast
    float v = X[s * 64 + lane];    // coalesced 256B line
    au += v; aw += we * v;
  }
  outw[wid * 64 + lane] = aw;
  outu[wid * 64 + lane] = au;
}

// plain sum
__global__ __launch_bounds__(256)
void k_agg64(const float* __restrict__ X,
             const int* __restrict__ rowstart, const int* __restrict__ cnt,
             const int* __restrict__ srcs, float* __restrict__ out, int n) {
  int wid = blockIdx.x * 4 + (threadIdx.x >> 6);
  if (wid >= n) return;
  int lane = threadIdx.x & 63;
  int rs = rowstart[wid], c = cnt[wid];
  float a = 0.f;
  for (int j = 0; j < c; j++) {
    int s = srcs[rs + j];
    a += X[s * 64 + lane];
  }
  out[wid * 64 + lane] = a;
}

// sym-normalized hop: out[d] = dinv[d] * sum dinv[s]*X[s]
__global__ __launch_bounds__(256)
void k_tag64(const float* __restrict__ X,
             const int* __restrict__ rowstart, const int* __restrict__ cnt,
             const int* __restrict__ srcs, const float* __restrict__ dinv,
             float* __restrict__ out, int n) {
  int wid = blockIdx.x * 4 + (threadIdx.x >> 6);
  if (wid >= n) return;
  int lane = threadIdx.x & 63;
  int rs = rowstart[wid], c = cnt[wid];
  float a = 0.f;
  for (int j = 0; j < c; j++) {
    int s = srcs[rs + j];
    float ws = dinv[s];
    a += ws * X[s * 64 + lane];
  }
  out[wid * 64 + lane] = dinv[wid] * a;
}

// ---------------- Fused node matmul: out = [relu]( [out +] A'@WA + B@WB + bias ) ----------------
// A' = A / max(cntA,1) if cntA (int counts). 64 nodes/block; each lane: 4 nodes x 4 feats.

__global__ __launch_bounds__(256)
void k_node_mm(const float* __restrict__ A, const int* __restrict__ cntA,
               const float* __restrict__ WA,
               const float* __restrict__ B, int DB,
               const float* __restrict__ WB,
               const float* __restrict__ bias,
               float* __restrict__ out, int n, int dorelu, int accum) {
  __shared__ float WAs[64 * 64];
  __shared__ float WBs[64 * 64];
  __shared__ float bs[64];
  __shared__ float as[64 * 68];
  const int tid = threadIdx.x;
  {
    const float4* w4 = (const float4*)WA;
    float4* s4 = (float4*)WAs;
    for (int i = tid; i < 1024; i += 256) s4[i] = w4[i];
    if (B) {
      const float4* wb4 = (const float4*)WB;
      float4* sb4 = (float4*)WBs;
      int nb = DB * 16;
      for (int i = tid; i < nb; i += 256) sb4[i] = wb4[i];
    }
    if (tid < 64) bs[tid] = bias ? bias[tid] : 0.0f;
  }
  const int gb = blockIdx.x * 64;
  for (int i = tid; i < 1024; i += 256) {
    int nl = i >> 4, k4 = i & 15;
    int g = gb + nl;
    float4 v = make_float4(0.f, 0.f, 0.f, 0.f);
    if (g < n) {
      v = ((const float4*)A)[g * 16 + k4];
      if (cntA) {
        float sc = 1.0f / fmaxf((float)cntA[g], 1.0f);
        v.x *= sc; v.y *= sc; v.z *= sc; v.w *= sc;
      }
    }
    *(float4*)(&as[nl * 68 + k4 * 4]) = v;
  }
  __syncthreads();
  const int lane = tid & 63;
  const int fq = lane & 15, nq = lane >> 4;
  const int f0 = fq * 4;
  const int nl0 = (tid >> 6) * 16 + nq * 4;
  float acc[4][4];
#pragma unroll
  for (int j = 0; j < 4; j++)
#pragma unroll
    for (int jj = 0; jj < 4; jj++) acc[j][jj] = 0.f;
#pragma unroll 4
  for (int k = 0; k < 64; k++) {
    float4 w = *(const float4*)(&WAs[k * 64 + f0]);
#pragma unroll
    for (int j = 0; j < 4; j++) {
      float a = as[(nl0 + j) * 68 + k];
      acc[j][0] += a * w.x; acc[j][1] += a * w.y; acc[j][2] += a * w.z; acc[j][3] += a * w.w;
    }
  }
  if (B) {
    __syncthreads();
    if (DB == 64) {
      for (int i = tid; i < 1024; i += 256) {
        int nl = i >> 4, k4 = i & 15;
        int g = gb + nl;
        float4 v = make_float4(0.f, 0.f, 0.f, 0.f);
        if (g < n) v = ((const float4*)B)[g * 16 + k4];
        *(float4*)(&as[nl * 68 + k4 * 4]) = v;
      }
    } else {
      for (int i = tid; i < 64 * DB; i += 256) {
        int nl = i / DB, k = i - nl * DB;
        int g = gb + nl;
        as[nl * 68 + k] = (g < n) ? B[g * DB + k] : 0.f;
      }
    }
    __syncthreads();
    for (int k = 0; k < DB; k++) {
      float4 w = *(const float4*)(&WBs[k * 64 + f0]);
#pragma unroll
      for (int j = 0; j < 4; j++) {
        float a = as[(nl0 + j) * 68 + k];
        acc[j][0] += a * w.x; acc[j][1] += a * w.y; acc[j][2] += a * w.z; acc[j][3] += a * w.w;
      }
    }
  }
#pragma unroll
  for (int j = 0; j < 4; j++) {
    int g = gb + nl0 + j;
    if (g < n) {
#pragma unroll
      for (int jj = 0; jj < 4; jj++) {
        int f = f0 + jj;
        float v = acc[j][jj] + bs[f];
        if (accum) v += out[g * 64 + f];
        if (dorelu) v = fmaxf(v, 0.f);
        out[g * 64 + f] = v;
      }
    }
  }
}

// ---------------- Final projection: out = X @ Wl + bl  (64 -> 8) ----------------

__global__ void k_final(const float* __restrict__ X, const float* __restrict__ Wl,
                        const float* __restrict__ bl, float* __restrict__ out) {
  __shared__ float Ws[64 * 8];
  __shared__ float bsh[8];
  int tid = threadIdx.x;
  for (int i = tid; i < 512; i += 256) Ws[i] = Wl[i];
  if (tid < 8) bsh[tid] = bl[tid];
  __syncthreads();
  int gid = blockIdx.x * 256 + tid;
  if (gid >= NSV * 8) return;
  int v = gid >> 3, f = gid & 7;
  float acc = bsh[f];
  const float* xr = X + v * 64;
#pragma unroll 8
  for (int k = 0; k < 64; k++) acc += xr[k] * Ws[k * 8 + f];
  out[gid] = acc;
}

// ---------------- Host ----------------

extern "C" void kernel_launch(void* const* d_in, const int* in_sizes, int n_in,
                              void* d_out, int out_size, void* d_ws, size_t ws_size,
                              hipStream_t stream) {
  const float* game_x  = (const float*)d_in[0];
  const float* state_x = (const float*)d_in[1];
  const int*   ei_vv   = (const int*)d_in[2];
  const int*   et_vv   = (const int*)d_in[3];
  const int*   ei_h    = (const int*)d_in[4];
  const float* ew_h    = (const float*)d_in[5];
  const int*   ei_in   = (const int*)d_in[6];
  const int*   ei_ss   = (const int*)d_in[7];
  const float* W1_rel  = (const float*)d_in[8];
  const float* W1_root = (const float*)d_in[9];
  const float* b1      = (const float*)d_in[10];
  const float* W12     = (const float*)d_in[11];
  const float* b12     = (const float*)d_in[12];
  const float* W2      = (const float*)d_in[13];
  const float* b2      = (const float*)d_in[14];
  const float* W3_rel  = (const float*)d_in[15];
  const float* W3_root = (const float*)d_in[16];
  const float* b3      = (const float*)d_in[17];
  const float* W32_l   = (const float*)d_in[18];
  const float* W32_r   = (const float*)d_in[19];
  const float* b32     = (const float*)d_in[20];
  const float* W4_l    = (const float*)d_in[21];
  const float* W4_r    = (const float*)d_in[22];
  const float* b4      = (const float*)d_in[23];
  const float* W42_l   = (const float*)d_in[24];
  const float* W42_r   = (const float*)d_in[25];
  const float* b42     = (const float*)d_in[26];
  const float* W5_l    = (const float*)d_in[27];
  const float* W5_r    = (const float*)d_in[28];
  const float* b5      = (const float*)d_in[29];
  const float* Wl      = (const float*)d_in[30];
  const float* bl      = (const float*)d_in[31];

  // Workspace layout (4B slots), max 26,056,000 slots ≈ 104.2 MiB (same as round 1).
  float* ws = (float*)d_ws;
  // Region R0 [0, 3.4M): phase A outputs, then CSR-h/in, then t3 in phase D.
  float* relagg  = ws + 0;         // [NVV][15]
  float* relcnt3 = ws + 1500000;   // [NVV][3]
  float* hbuf    = ws + 1800000;   // [3][NVV][5]
  float* dinv_v  = ws + 3300000;   // [NVV]
  int*   srcs_h  = (int*)(ws + 0);        // 0.8M   (after combine_gx)
  float* w_h     = ws + 800000;           // 0.8M
  int*   rs_h    = (int*)(ws + 1600000);
  int*   cur_h   = (int*)(ws + 1650000);
  int*   cnt_h   = (int*)(ws + 1700000);
  int*   bsum_h  = (int*)(ws + 1750000);
  int*   bscan_h = (int*)(ws + 1751024);
  int*   srcs_in = (int*)(ws + 1800000);  // 0.8M
  int*   rs_in   = (int*)(ws + 2600000);
  int*   cur_in  = (int*)(ws + 2650000);
  int*   cnt_in  = (int*)(ws + 2700000);
  int*   bsum_in = (int*)(ws + 2750000);
  int*   bscan_in= (int*)(ws + 2751024);
  // gx region [3.4M, 9.8M): gx in phases A-B; t1/t2 in phase D.
  float* gx = ws + 3400000;
  float* t1 = gx;
  float* t2 = gx + 3200000;
  float* t3 = ws + 0;              // 3.2M, phase D (R0 dead)
  // [9.8M, 13M): CSR-vv during phase A; aggHw in B-C; aggSS in E.
  int*   payload_vv = (int*)(ws + 9800000);  // 1.6M
  int*   rs_vv      = (int*)(ws + 11400000);
  int*   cur_vv     = (int*)(ws + 11500000);
  int*   cnt_vv     = (int*)(ws + 11600000);
  int*   bsum_vv    = (int*)(ws + 11700000);
  int*   bscan_vv   = (int*)(ws + 11701024);
  float* aggHw = ws + 9800000;
  float* aggSS = aggHw;
  // [13M, 16.2M): aggHu in B-C; CSR-ss in D-E.
  float* aggHu   = ws + 13000000;
  int*   srcs_ss = (int*)(ws + 13000000);
  int*   rs_ss   = (int*)(ws + 13800000);
  int*   cur_ss  = (int*)(ws + 13850000);
  int*   cnt_ss  = (int*)(ws + 13900000);
  int*   bsum_ss = (int*)(ws + 13950000);
  int*   bscan_ss= (int*)(ws + 13951024);
  // [16.2M, 19.4M): aggIN (phase B-C).
  float* aggIN = ws + 16200000;
  // [19.528M, 26.056M): S1, S2, dinvS.
  float* S1    = ws + 19528000;
  float* S2    = ws + 22728000;
  float* dinvS = ws + 25928000;

  const int* src_vv = ei_vv;  const int* dst_vv = ei_vv + E_VV;
  const int* src_h  = ei_h;   const int* dst_h  = ei_h + E_H;
  const int* src_in = ei_in;  const int* dst_in = ei_in + E_IN;
  const int* src_ss = ei_ss;  const int* dst_ss = ei_ss + E_SS;

  auto nblk = [](long long n) { return dim3((unsigned)((n + 255) / 256)); };
  const int GVV = (NVV + 1023) / 1024;   // 98
  const int GS  = (NSV + 1023) / 1024;   // 49
  const int NB64 = (NSV + 3) / 4;        // wave-per-dst grids
  const int NB   = (NSV + 63) / 64;      // node_mm grid

  // ---- Phase A: CSR-vv + fused 5-dim aggregation ----
  hipMemsetAsync(cnt_vv, 0, NVV * sizeof(int), stream);
  k_count<<<nblk(E_VV), 256, 0, stream>>>(dst_vv, cnt_vv, E_VV);
  k_scan_bsum<<<GVV, 256, 0, stream>>>(cnt_vv, bsum_vv, NVV);
  k_scan_carry<<<1, 256, 0, stream>>>(bsum_vv, bscan_vv, GVV);
  k_scan_write<<<GVV, 256, 0, stream>>>(cnt_vv, bscan_vv, rs_vv, cur_vv, NVV);
  k_fill_vv<<<nblk(E_VV), 256, 0, stream>>>(src_vv, dst_vv, et_vv, cur_vv, payload_vv);
  k_rsqrt_deg<<<nblk(NVV), 256, 0, stream>>>(cnt_vv, dinv_v, NVV);
  k_vv_pass1<<<nblk(NVV), 256, 0, stream>>>(game_x, rs_vv, cnt_vv, payload_vv, dinv_v,
                                            relagg, relcnt3, hbuf);
  k_vv_hop<<<nblk(NVV), 256, 0, stream>>>(hbuf, rs_vv, cnt_vv, payload_vv, dinv_v, hbuf + 500000);
  k_vv_hop<<<nblk(NVV), 256, 0, stream>>>(hbuf + 500000, rs_vv, cnt_vv, payload_vv, dinv_v, hbuf + 1000000);
  k_combine_gx<<<dim3((NVV + 3) / 4), 256, 0, stream>>>(game_x, relagg, relcnt3, hbuf,
                                                        W1_rel, W1_root, b1, W12, b12, gx);

  // ---- Phase B: CSR-h + CSR-in, 64-dim gather aggregations of gx ----
  hipMemsetAsync(cnt_h, 0, NSV * sizeof(int), stream);
  hipMemsetAsync(cnt_in, 0, NSV * sizeof(int), stream);
  k_count<<<nblk(E_H), 256, 0, stream>>>(dst_h, cnt_h, E_H);
  k_count<<<nblk(E_IN), 256, 0, stream>>>(dst_in, cnt_in, E_IN);
  k_scan_bsum<<<GS, 256, 0, stream>>>(cnt_h, bsum_h, NSV);
  k_scan_carry<<<1, 256, 0, stream>>>(bsum_h, bscan_h, GS);
  k_scan_write<<<GS, 256, 0, stream>>>(cnt_h, bscan_h, rs_h, cur_h, NSV);
  k_scan_bsum<<<GS, 256, 0, stream>>>(cnt_in, bsum_in, NSV);
  k_scan_carry<<<1, 256, 0, stream>>>(bsum_in, bscan_in, GS);
  k_scan_write<<<GS, 256, 0, stream>>>(cnt_in, bscan_in, rs_in, cur_in, NSV);
  k_fill_w<<<nblk(E_H), 256, 0, stream>>>(src_h, dst_h, ew_h, cur_h, srcs_h, w_h, E_H);
  k_fill<<<nblk(E_IN), 256, 0, stream>>>(src_in, dst_in, cur_in, srcs_in, E_IN);
  k_agg_h64<<<NB64, 256, 0, stream>>>(gx, rs_h, cnt_h, srcs_h, w_h, aggHw, aggHu);
  k_agg64<<<NB64, 256, 0, stream>>>(gx, rs_in, cnt_in, srcs_in, aggIN, NSV);

  // ---- Phase C: graph_conv + 3x SAGE ----
  k_node_mm<<<NB, 256, 0, stream>>>(aggHw, nullptr, W3_rel, state_x, 5, W3_root, b3, S1, NSV, 1, 0);
  k_node_mm<<<NB, 256, 0, stream>>>(aggHu, cnt_h,   W32_l, S1, 64, W32_r, b32, S2, NSV, 1, 0);
  k_node_mm<<<NB, 256, 0, stream>>>(aggIN, cnt_in,  W4_l,  S2, 64, W4_r,  b4,  S1, NSV, 1, 0);
  k_node_mm<<<NB, 256, 0, stream>>>(aggIN, cnt_in,  W42_l, S1, 64, W42_r, b42, S2, NSV, 1, 0);

  // ---- Phase D: CSR-ss + TAG on s-s (64-dim gather hops) ----
  hipMemsetAsync(cnt_ss, 0, NSV * sizeof(int), stream);
  k_count<<<nblk(E_SS), 256, 0, stream>>>(dst_ss, cnt_ss, E_SS);
  k_scan_bsum<<<GS, 256, 0, stream>>>(cnt_ss, bsum_ss, NSV);
  k_scan_carry<<<1, 256, 0, stream>>>(bsum_ss, bscan_ss, GS);
  k_scan_write<<<GS, 256, 0, stream>>>(cnt_ss, bscan_ss, rs_ss, cur_ss, NSV);
  k_fill<<<nblk(E_SS), 256, 0, stream>>>(src_ss, dst_ss, cur_ss, srcs_ss, E_SS);
  k_rsqrt_deg<<<nblk(NSV), 256, 0, stream>>>(cnt_ss, dinvS, NSV);
  k_tag64<<<NB64, 256, 0, stream>>>(S2, rs_ss, cnt_ss, srcs_ss, dinvS, t1, NSV);
  k_tag64<<<NB64, 256, 0, stream>>>(t1, rs_ss, cnt_ss, srcs_ss, dinvS, t2, NSV);
  k_tag64<<<NB64, 256, 0, stream>>>(t2, rs_ss, cnt_ss, srcs_ss, dinvS, t3, NSV);
  k_node_mm<<<NB, 256, 0, stream>>>(S2, nullptr, W2,        t1, 64, W2 + 4096,  b2,      S1, NSV, 0, 0);
  k_node_mm<<<NB, 256, 0, stream>>>(t2, nullptr, W2 + 8192, t3, 64, W2 + 12288, nullptr, S1, NSV, 1, 1);

  // ---- Phase E: SAGE on s-s ----
  k_agg64<<<NB64, 256, 0, stream>>>(S1, rs_ss, cnt_ss, srcs_ss, aggSS, NSV);
  k_node_mm<<<NB, 256, 0, stream>>>(aggSS, cnt_ss, W5_l, S1, 64, W5_r, b5, S2, NSV, 1, 0);

  // ---- Final projection ----
  k_final<<<nblk(NSV * 8), 256, 0, stream>>>(S2, Wl, bl, (float*)d_out);
}

// Round 3
// 1332.535 us; speedup vs baseline: 2.5567x; 1.0392x over previous
//
#include <hip/hip_runtime.h>

#define NVV 100000
#define NSV 50000
#define E_VV 1600000
#define E_H  800000
#define E_IN 800000
#define E_SS 800000
#define DIN 5
#define HD 64

__device__ __forceinline__ unsigned short f2bf(float x) {
  unsigned b = __float_as_uint(x);
  return (unsigned short)((b + 0x7FFFu + ((b >> 16) & 1u)) >> 16);
}
__device__ __forceinline__ float bf2f(unsigned short u) {
  return __uint_as_float(((unsigned)u) << 16);
}

// ====================== CSR build ======================

__global__ void k_count(const int* __restrict__ dst, int* __restrict__ cnt, int ne) {
  int e = blockIdx.x * 256 + threadIdx.x;
  if (e >= ne) return;
  atomicAdd(&cnt[dst[e]], 1);
}

__global__ void k_scan_bsum(const int* __restrict__ cnt, int* __restrict__ bsum, int n) {
  int tid = threadIdx.x, b = blockIdx.x;
  int base = b * 1024 + tid * 4;
  int s = 0;
#pragma unroll
  for (int i = 0; i < 4; i++) { int idx = base + i; if (idx < n) s += cnt[idx]; }
  __shared__ int sd[256];
  sd[tid] = s; __syncthreads();
  for (int off = 128; off > 0; off >>= 1) {
    if (tid < off) sd[tid] += sd[tid + off];
    __syncthreads();
  }
  if (tid == 0) bsum[b] = sd[0];
}

__global__ void k_scan_carry(const int* __restrict__ bsum, int* __restrict__ bscan, int g) {
  int tid = threadIdx.x;
  __shared__ int sd[256];
  int my = (tid < g) ? bsum[tid] : 0;
  sd[tid] = my; __syncthreads();
  for (int off = 1; off < 256; off <<= 1) {
    int t = (tid >= off) ? sd[tid - off] : 0;
    __syncthreads();
    sd[tid] += t;
    __syncthreads();
  }
  if (tid < g) bscan[tid] = sd[tid] - my;
}

__global__ void k_scan_write(const int* __restrict__ cnt, const int* __restrict__ bscan,
                             int* __restrict__ rowstart, int* __restrict__ cursor, int n) {
  int tid = threadIdx.x, b = blockIdx.x;
  int base = b * 1024 + tid * 4;
  int v[4]; int s = 0;
#pragma unroll
  for (int i = 0; i < 4; i++) { int idx = base + i; v[i] = (idx < n) ? cnt[idx] : 0; s += v[i]; }
  __shared__ int sd[256];
  sd[tid] = s; __syncthreads();
  for (int off = 1; off < 256; off <<= 1) {
    int t = (tid >= off) ? sd[tid - off] : 0;
    __syncthreads();
    sd[tid] += t;
    __syncthreads();
  }
  int run = bscan[b] + sd[tid] - s;
#pragma unroll
  for (int i = 0; i < 4; i++) {
    int idx = base + i;
    if (idx < n) { rowstart[idx] = run; cursor[idx] = run; run += v[i]; }
  }
}

__global__ void k_fill_vv(const int* __restrict__ src, const int* __restrict__ dst,
                          const int* __restrict__ et,
                          int* __restrict__ cursor, int* __restrict__ payload) {
  int e = blockIdx.x * 256 + threadIdx.x;
  if (e >= E_VV) return;
  int p = atomicAdd(&cursor[dst[e]], 1);
  payload[p] = (et[e] << 20) | src[e];
}

// h-graph: single 8B packed store (src, weight bits)
__global__ void k_fill_h(const int* __restrict__ src, const int* __restrict__ dst,
                         const float* __restrict__ ew,
                         int* __restrict__ cursor, int2* __restrict__ eh) {
  int e = blockIdx.x * 256 + threadIdx.x;
  if (e >= E_H) return;
  int p = atomicAdd(&cursor[dst[e]], 1);
  eh[p] = make_int2(src[e], __float_as_int(ew[e]));
}

__global__ void k_fill(const int* __restrict__ src, const int* __restrict__ dst,
                       int* __restrict__ cursor, int* __restrict__ srcs, int ne) {
  int e = blockIdx.x * 256 + threadIdx.x;
  if (e >= ne) return;
  int p = atomicAdd(&cursor[dst[e]], 1);
  srcs[p] = src[e];
}

__global__ void k_rsqrt_deg(const int* __restrict__ deg, float* __restrict__ dinv, int n) {
  int i = blockIdx.x * 256 + threadIdx.x;
  if (i >= n) return;
  float d = (float)deg[i];
  dinv[i] = d > 0.f ? rsqrtf(d) : 0.f;
}

// ====================== Phase A: v-graph (5-dim, padded rows) ======================

// x_pad[v] = {x0..x4, dinv_v, 0, 0}
__global__ void k_prep_x(const float* __restrict__ x, const int* __restrict__ cnt,
                         float4* __restrict__ xp) {
  int v = blockIdx.x * 256 + threadIdx.x;
  if (v >= NVV) return;
  float d = (float)cnt[v];
  float di = d > 0.f ? rsqrtf(d) : 0.f;
  const float* xr = x + v * 5;
  xp[v * 2]     = make_float4(xr[0], xr[1], xr[2], xr[3]);
  xp[v * 2 + 1] = make_float4(xr[4], di, 0.f, 0.f);
}

// Fused RGCN rel-sums/counts + TAG hop-1. Branch-free masked accumulation.
__global__ __launch_bounds__(256)
void k_vv_pass1(const float4* __restrict__ xp,
                const int* __restrict__ rowstart, const int* __restrict__ cnt,
                const int* __restrict__ payload,
                float* __restrict__ relall, float4* __restrict__ h1p) {
  int d = blockIdx.x * 256 + threadIdx.x;
  if (d >= NVV) return;
  int rs = rowstart[d], c = cnt[d];
  float a0[5] = {0,0,0,0,0}, a1[5] = {0,0,0,0,0}, a2[5] = {0,0,0,0,0}, h[5] = {0,0,0,0,0};
  float c0 = 0.f, c1 = 0.f, c2 = 0.f;
  for (int j = 0; j < c; j++) {
    int p = payload[rs + j];
    int s = p & 0xFFFFF, r = p >> 20;
    float4 x0 = xp[s * 2], x1 = xp[s * 2 + 1];
    float xs[5] = {x0.x, x0.y, x0.z, x0.w, x1.x};
    float wsc = x1.y;
    float m0 = (r == 0) ? 1.f : 0.f, m1 = (r == 1) ? 1.f : 0.f, m2 = (r == 2) ? 1.f : 0.f;
    c0 += m0; c1 += m1; c2 += m2;
#pragma unroll
    for (int k = 0; k < 5; k++) {
      h[k] += wsc * xs[k];
      a0[k] += m0 * xs[k]; a1[k] += m1 * xs[k]; a2[k] += m2 * xs[k];
    }
  }
  float dv = xp[d * 2 + 1].y;
  float* ra = relall + d * 18;
#pragma unroll
  for (int k = 0; k < 5; k++) { ra[k] = a0[k]; ra[5 + k] = a1[k]; ra[10 + k] = a2[k]; }
  ra[15] = c0; ra[16] = c1; ra[17] = c2;
  h1p[d * 2]     = make_float4(dv * h[0], dv * h[1], dv * h[2], dv * h[3]);
  h1p[d * 2 + 1] = make_float4(dv * h[4], dv, 0.f, 0.f);
}

__global__ __launch_bounds__(256)
void k_vv_hop(const float4* __restrict__ hinp,
              const int* __restrict__ rowstart, const int* __restrict__ cnt,
              const int* __restrict__ payload, float4* __restrict__ houtp) {
  int d = blockIdx.x * 256 + threadIdx.x;
  if (d >= NVV) return;
  int rs = rowstart[d], c = cnt[d];
  float h[5] = {0,0,0,0,0};
  for (int j = 0; j < c; j++) {
    int s = payload[rs + j] & 0xFFFFF;
    float4 x0 = hinp[s * 2], x1 = hinp[s * 2 + 1];
    float wsc = x1.y;
    h[0] += wsc * x0.x; h[1] += wsc * x0.y; h[2] += wsc * x0.z; h[3] += wsc * x0.w;
    h[4] += wsc * x1.x;
  }
  float dv = hinp[d * 2 + 1].y;
  houtp[d * 2]     = make_float4(dv * h[0], dv * h[1], dv * h[2], dv * h[3]);
  houtp[d * 2 + 1] = make_float4(dv * h[4], dv, 0.f, 0.f);
}

// gx16[v] = bf16( x@(W1_root+W12_0) + sum_r mean_r@W1_rel[r] + sum_k h_k@W12[k] + b )
__global__ __launch_bounds__(256)
void k_combine_gx(const float4* __restrict__ xp,
                  const float* __restrict__ relall,
                  const float4* __restrict__ h1p, const float4* __restrict__ h2p,
                  const float4* __restrict__ h3p,
                  const float* __restrict__ W1_rel, const float* __restrict__ W1_root,
                  const float* __restrict__ b1,
                  const float* __restrict__ W12, const float* __restrict__ b12,
                  unsigned short* __restrict__ gx16) {
  __shared__ float Ws[7 * 320];
  __shared__ float bs[64];
  int tid = threadIdx.x;
  for (int i = tid; i < 320; i += 256) {
    Ws[i]        = W1_root[i] + W12[i];
    Ws[320 + i]  = W1_rel[i];
    Ws[640 + i]  = W1_rel[320 + i];
    Ws[960 + i]  = W1_rel[640 + i];
    Ws[1280 + i] = W12[320 + i];
    Ws[1600 + i] = W12[640 + i];
    Ws[1920 + i] = W12[960 + i];
  }
  if (tid < 64) bs[tid] = b1[tid] + b12[tid];
  __syncthreads();
  int v = blockIdx.x * 4 + (tid >> 6);
  if (v >= NVV) return;
  int f = tid & 63;
  float in[35];
  {
    float4 x0 = xp[v * 2], x1 = xp[v * 2 + 1];
    in[0] = x0.x; in[1] = x0.y; in[2] = x0.z; in[3] = x0.w; in[4] = x1.x;
  }
  const float* ra = relall + v * 18;
#pragma unroll
  for (int r = 0; r < 3; r++) {
    float inv = 1.0f / fmaxf(ra[15 + r], 1.0f);
#pragma unroll
    for (int j = 0; j < DIN; j++) in[5 + r * 5 + j] = ra[r * 5 + j] * inv;
  }
  {
    float4 a = h1p[v * 2], b = h1p[v * 2 + 1];
    in[20] = a.x; in[21] = a.y; in[22] = a.z; in[23] = a.w; in[24] = b.x;
    a = h2p[v * 2]; b = h2p[v * 2 + 1];
    in[25] = a.x; in[26] = a.y; in[27] = a.z; in[28] = a.w; in[29] = b.x;
    a = h3p[v * 2]; b = h3p[v * 2 + 1];
    in[30] = a.x; in[31] = a.y; in[32] = a.z; in[33] = a.w; in[34] = b.x;
  }
  float acc = bs[f];
#pragma unroll
  for (int t = 0; t < 35; t++) acc += in[t] * Ws[t * 64 + f];
  gx16[v * 64 + f] = f2bf(acc);
}

// ================= 64-dim CSR aggregation (wave per dst, lane=feature) =================

// h-graph over bf16 gx: weighted sum + plain sum in one pass
__global__ __launch_bounds__(256)
void k_agg_h64(const unsigned short* __restrict__ X16,
               const int* __restrict__ rowstart, const int* __restrict__ cnt,
               const int2* __restrict__ eh,
               float* __restrict__ outw, float* __restrict__ outu) {
  int wid = blockIdx.x * 4 + (threadIdx.x >> 6);
  if (wid >= NSV) return;
  int lane = threadIdx.x & 63;
  int rs = rowstart[wid], c = cnt[wid];
  float aw = 0.f, au = 0.f;
  for (int j = 0; j < c; j++) {
    int2 p = eh[rs + j];                  // wave-broadcast 8B
    float v = bf2f(X16[p.x * 64 + lane]); // coalesced 128B line
    au += v; aw += __int_as_float(p.y) * v;
  }
  outw[wid * 64 + lane] = aw;
  outu[wid * 64 + lane] = au;
}

// plain sum over bf16 matrix
__global__ __launch_bounds__(256)
void k_agg64b(const unsigned short* __restrict__ X16,
              const int* __restrict__ rowstart, const int* __restrict__ cnt,
              const int* __restrict__ srcs, float* __restrict__ out, int n) {
  int wid = blockIdx.x * 4 + (threadIdx.x >> 6);
  if (wid >= n) return;
  int lane = threadIdx.x & 63;
  int rs = rowstart[wid], c = cnt[wid];
  float a = 0.f;
  for (int j = 0; j < c; j++) {
    int s = srcs[rs + j];
    a += bf2f(X16[s * 64 + lane]);
  }
  out[wid * 64 + lane] = a;
}

// plain sum over f32 matrix (ss graph)
__global__ __launch_bounds__(256)
void k_agg64(const float* __restrict__ X,
             const int* __restrict__ rowstart, const int* __restrict__ cnt,
             const int* __restrict__ srcs, float* __restrict__ out, int n) {
  int wid = blockIdx.x * 4 + (threadIdx.x >> 6);
  if (wid >= n) return;
  int lane = threadIdx.x & 63;
  int rs = rowstart[wid], c = cnt[wid];
  float a = 0.f;
  for (int j = 0; j < c; j++) {
    int s = srcs[rs + j];
    a += X[s * 64 + lane];
  }
  out[wid * 64 + lane] = a;
}

// sym-normalized hop (f32)
__global__ __launch_bounds__(256)
void k_tag64(const float* __restrict__ X,
             const int* __restrict__ rowstart, const int* __restrict__ cnt,
             const int* __restrict__ srcs, const float* __restrict__ dinv,
             float* __restrict__ out, int n) {
  int wid = blockIdx.x * 4 + (threadIdx.x >> 6);
  if (wid >= n) return;
  int lane = threadIdx.x & 63;
  int rs = rowstart[wid], c = cnt[wid];
  float a = 0.f;
  for (int j = 0; j < c; j++) {
    int s = srcs[rs + j];
    a += dinv[s] * X[s * 64 + lane];
  }
  out[wid * 64 + lane] = dinv[wid] * a;
}

// ---------------- Fused node matmul ----------------

__global__ __launch_bounds__(256)
void k_node_mm(const float* __restrict__ A, const int* __restrict__ cntA,
               const float* __restrict__ WA,
               const float* __restrict__ B, int DB,
               const float* __restrict__ WB,
               const float* __restrict__ bias,
               float* __restrict__ out, int n, int dorelu, int accum) {
  __shared__ float WAs[64 * 64];
  __shared__ float WBs[64 * 64];
  __shared__ float bs[64];
  __shared__ float as[64 * 68];
  const int tid = threadIdx.x;
  {
    const float4* w4 = (const float4*)WA;
    float4* s4 = (float4*)WAs;
    for (int i = tid; i < 1024; i += 256) s4[i] = w4[i];
    if (B) {
      const float4* wb4 = (const float4*)WB;
      float4* sb4 = (float4*)WBs;
      int nb = DB * 16;
      for (int i = tid; i < nb; i += 256) sb4[i] = wb4[i];
    }
    if (tid < 64) bs[tid] = bias ? bias[tid] : 0.0f;
  }
  const int gb = blockIdx.x * 64;
  for (int i = tid; i < 1024; i += 256) {
    int nl = i >> 4, k4 = i & 15;
    int g = gb + nl;
    float4 v = make_float4(0.f, 0.f, 0.f, 0.f);
    if (g < n) {
      v = ((const float4*)A)[g * 16 + k4];
      if (cntA) {
        float sc = 1.0f / fmaxf((float)cntA[g], 1.0f);
        v.x *= sc; v.y *= sc; v.z *= sc; v.w *= sc;
      }
    }
    *(float4*)(&as[nl * 68 + k4 * 4]) = v;
  }
  __syncthreads();
  const int lane = tid & 63;
  const int fq = lane & 15, nq = lane >> 4;
  const int f0 = fq * 4;
  const int nl0 = (tid >> 6) * 16 + nq * 4;
  float acc[4][4];
#pragma unroll
  for (int j = 0; j < 4; j++)
#pragma unroll
    for (int jj = 0; jj < 4; jj++) acc[j][jj] = 0.f;
#pragma unroll 4
  for (int k = 0; k < 64; k++) {
    float4 w = *(const float4*)(&WAs[k * 64 + f0]);
#pragma unroll
    for (int j = 0; j < 4; j++) {
      float a = as[(nl0 + j) * 68 + k];
      acc[j][0] += a * w.x; acc[j][1] += a * w.y; acc[j][2] += a * w.z; acc[j][3] += a * w.w;
    }
  }
  if (B) {
    __syncthreads();
    if (DB == 64) {
      for (int i = tid; i < 1024; i += 256) {
        int nl = i >> 4, k4 = i & 15;
        int g = gb + nl;
        float4 v = make_float4(0.f, 0.f, 0.f, 0.f);
        if (g < n) v = ((const float4*)B)[g * 16 + k4];
        *(float4*)(&as[nl * 68 + k4 * 4]) = v;
      }
    } else {
      for (int i = tid; i < 64 * DB; i += 256) {
        int nl = i / DB, k = i - nl * DB;
        int g = gb + nl;
        as[nl * 68 + k] = (g < n) ? B[g * DB + k] : 0.f;
      }
    }
    __syncthreads();
    for (int k = 0; k < DB; k++) {
      float4 w = *(const float4*)(&WBs[k * 64 + f0]);
#pragma unroll
      for (int j = 0; j < 4; j++) {
        float a = as[(nl0 + j) * 68 + k];
        acc[j][0] += a * w.x; acc[j][1] += a * w.y; acc[j][2] += a * w.z; acc[j][3] += a * w.w;
      }
    }
  }
#pragma unroll
  for (int j = 0; j < 4; j++) {
    int g = gb + nl0 + j;
    if (g < n) {
#pragma unroll
      for (int jj = 0; jj < 4; jj++) {
        int f = f0 + jj;
        float v = acc[j][jj] + bs[f];
        if (accum) v += out[g * 64 + f];
        if (dorelu) v = fmaxf(v, 0.f);
        out[g * 64 + f] = v;
      }
    }
  }
}

// ---------------- Final projection ----------------

__global__ void k_final(const float* __restrict__ X, const float* __restrict__ Wl,
                        const float* __restrict__ bl, float* __restrict__ out) {
  __shared__ float Ws[64 * 8];
  __shared__ float bsh[8];
  int tid = threadIdx.x;
  for (int i = tid; i < 512; i += 256) Ws[i] = Wl[i];
  if (tid < 8) bsh[tid] = bl[tid];
  __syncthreads();
  int gid = blockIdx.x * 256 + tid;
  if (gid >= NSV * 8) return;
  int v = gid >> 3, f = gid & 7;
  float acc = bsh[f];
  const float* xr = X + v * 64;
#pragma unroll 8
  for (int k = 0; k < 64; k++) acc += xr[k] * Ws[k * 8 + f];
  out[gid] = acc;
}

// ---------------- Host ----------------

extern "C" void kernel_launch(void* const* d_in, const int* in_sizes, int n_in,
                              void* d_out, int out_size, void* d_ws, size_t ws_size,
                              hipStream_t stream) {
  const float* game_x  = (const float*)d_in[0];
  const float* state_x = (const float*)d_in[1];
  const int*   ei_vv   = (const int*)d_in[2];
  const int*   et_vv   = (const int*)d_in[3];
  const int*   ei_h    = (const int*)d_in[4];
  const float* ew_h    = (const float*)d_in[5];
  const int*   ei_in   = (const int*)d_in[6];
  const int*   ei_ss   = (const int*)d_in[7];
  const float* W1_rel  = (const float*)d_in[8];
  const float* W1_root = (const float*)d_in[9];
  const float* b1      = (const float*)d_in[10];
  const float* W12     = (const float*)d_in[11];
  const float* b12     = (const float*)d_in[12];
  const float* W2      = (const float*)d_in[13];
  const float* b2      = (const float*)d_in[14];
  const float* W3_rel  = (const float*)d_in[15];
  const float* W3_root = (const float*)d_in[16];
  const float* b3      = (const float*)d_in[17];
  const float* W32_l   = (const float*)d_in[18];
  const float* W32_r   = (const float*)d_in[19];
  const float* b32     = (const float*)d_in[20];
  const float* W4_l    = (const float*)d_in[21];
  const float* W4_r    = (const float*)d_in[22];
  const float* b4      = (const float*)d_in[23];
  const float* W42_l   = (const float*)d_in[24];
  const float* W42_r   = (const float*)d_in[25];
  const float* b42     = (const float*)d_in[26];
  const float* W5_l    = (const float*)d_in[27];
  const float* W5_r    = (const float*)d_in[28];
  const float* b5      = (const float*)d_in[29];
  const float* Wl      = (const float*)d_in[30];
  const float* bl      = (const float*)d_in[31];

  // Workspace (4B slots). Max touched: 22,904,000 slots = 91.6 MiB.
  float* ws = (float*)d_ws;
  // --- Phase A block [0, 6.91M) ---
  float4* x_pad = (float4*)(ws + 0);           // [NVV][8]
  float4* h1p   = (float4*)(ws + 800000);
  float4* h2p   = (float4*)(ws + 1600000);
  float4* h3p   = (float4*)(ws + 2400000);
  float*  relall = ws + 3200000;               // [NVV][18]
  int*   payload_vv = (int*)(ws + 5000000);    // 1.6M
  int*   rs_vv   = (int*)(ws + 6600000);
  int*   cur_vv  = (int*)(ws + 6700000);
  int*   cnt_vv  = (int*)(ws + 6800000);
  int*   bsum_vv = (int*)(ws + 6900000);
  int*   bscan_vv= (int*)(ws + 6901024);
  // --- CSR h/in/ss block, overlays phase A after combine_gx [0, 3.73M) ---
  int2*  eh      = (int2*)(ws + 0);            // 1.6M slots (0.8M int2)
  int*   rs_h    = (int*)(ws + 1600000);
  int*   cur_h   = (int*)(ws + 1650000);
  int*   cnt_h   = (int*)(ws + 1700000);
  int*   bsum_h  = (int*)(ws + 1750000);
  int*   bscan_h = (int*)(ws + 1751024);
  int*   srcs_in = (int*)(ws + 1760000);       // 0.8M
  int*   rs_in   = (int*)(ws + 2560000);
  int*   cur_in  = (int*)(ws + 2610000);
  int*   cnt_in  = (int*)(ws + 2660000);
  int*   bsum_in = (int*)(ws + 2710000);
  int*   bscan_in= (int*)(ws + 2711024);
  int*   srcs_ss = (int*)(ws + 2720000);       // 0.8M
  int*   rs_ss   = (int*)(ws + 3520000);
  int*   cur_ss  = (int*)(ws + 3570000);
  int*   cnt_ss  = (int*)(ws + 3620000);
  int*   bsum_ss = (int*)(ws + 3670000);
  int*   bscan_ss= (int*)(ws + 3671024);
  float* dinvS   = ws + 3680000;               // 50K
  // --- big matrices ---
  float* S1 = ws + 6904000;                      // 3.2M
  unsigned short* gx16 = (unsigned short*)(ws + 10104000);  // 3.2M slots (bf16)
  float* S2 = ws + 10104000;                     // overlays gx16 (dead after gathers)
  float* aggHw = ws + 13304000;                  // 3.2M; -> t1 -> aggSS
  float* aggHu = ws + 16504000;                  // 3.2M; -> t2
  float* aggIN = ws + 19704000;                  // 3.2M; -> t3
  float* t1 = aggHw; float* t2 = aggHu; float* t3 = aggIN; float* aggSS = aggHw;

  const int* src_vv = ei_vv;  const int* dst_vv = ei_vv + E_VV;
  const int* src_h  = ei_h;   const int* dst_h  = ei_h + E_H;
  const int* src_in = ei_in;  const int* dst_in = ei_in + E_IN;
  const int* src_ss = ei_ss;  const int* dst_ss = ei_ss + E_SS;

  auto nblk = [](long long n) { return dim3((unsigned)((n + 255) / 256)); };
  const int GVV = (NVV + 1023) / 1024;
  const int GS  = (NSV + 1023) / 1024;
  const int NB64 = (NSV + 3) / 4;
  const int NB   = (NSV + 63) / 64;

  // ---- Phase A: CSR-vv + fused 5-dim aggregation ----
  hipMemsetAsync(cnt_vv, 0, NVV * sizeof(int), stream);
  k_count<<<nblk(E_VV), 256, 0, stream>>>(dst_vv, cnt_vv, E_VV);
  k_scan_bsum<<<GVV, 256, 0, stream>>>(cnt_vv, bsum_vv, NVV);
  k_scan_carry<<<1, 256, 0, stream>>>(bsum_vv, bscan_vv, GVV);
  k_scan_write<<<GVV, 256, 0, stream>>>(cnt_vv, bscan_vv, rs_vv, cur_vv, NVV);
  k_prep_x<<<nblk(NVV), 256, 0, stream>>>(game_x, cnt_vv, x_pad);
  k_fill_vv<<<nblk(E_VV), 256, 0, stream>>>(src_vv, dst_vv, et_vv, cur_vv, payload_vv);
  k_vv_pass1<<<nblk(NVV), 256, 0, stream>>>(x_pad, rs_vv, cnt_vv, payload_vv, relall, h1p);
  k_vv_hop<<<nblk(NVV), 256, 0, stream>>>(h1p, rs_vv, cnt_vv, payload_vv, h2p);
  k_vv_hop<<<nblk(NVV), 256, 0, stream>>>(h2p, rs_vv, cnt_vv, payload_vv, h3p);
  k_combine_gx<<<dim3((NVV + 3) / 4), 256, 0, stream>>>(x_pad, relall, h1p, h2p, h3p,
                                                        W1_rel, W1_root, b1, W12, b12, gx16);

  // ---- Phase B: CSR h/in/ss (region free post-combine), 64-dim bf16 gathers ----
  hipMemsetAsync(cnt_h, 0, NSV * sizeof(int), stream);
  hipMemsetAsync(cnt_in, 0, NSV * sizeof(int), stream);
  hipMemsetAsync(cnt_ss, 0, NSV * sizeof(int), stream);
  k_count<<<nblk(E_H), 256, 0, stream>>>(dst_h, cnt_h, E_H);
  k_count<<<nblk(E_IN), 256, 0, stream>>>(dst_in, cnt_in, E_IN);
  k_count<<<nblk(E_SS), 256, 0, stream>>>(dst_ss, cnt_ss, E_SS);
  k_scan_bsum<<<GS, 256, 0, stream>>>(cnt_h, bsum_h, NSV);
  k_scan_carry<<<1, 256, 0, stream>>>(bsum_h, bscan_h, GS);
  k_scan_write<<<GS, 256, 0, stream>>>(cnt_h, bscan_h, rs_h, cur_h, NSV);
  k_scan_bsum<<<GS, 256, 0, stream>>>(cnt_in, bsum_in, NSV);
  k_scan_carry<<<1, 256, 0, stream>>>(bsum_in, bscan_in, GS);
  k_scan_write<<<GS, 256, 0, stream>>>(cnt_in, bscan_in, rs_in, cur_in, NSV);
  k_scan_bsum<<<GS, 256, 0, stream>>>(cnt_ss, bsum_ss, NSV);
  k_scan_carry<<<1, 256, 0, stream>>>(bsum_ss, bscan_ss, GS);
  k_scan_write<<<GS, 256, 0, stream>>>(cnt_ss, bscan_ss, rs_ss, cur_ss, NSV);
  k_fill_h<<<nblk(E_H), 256, 0, stream>>>(src_h, dst_h, ew_h, cur_h, eh);
  k_fill<<<nblk(E_IN), 256, 0, stream>>>(src_in, dst_in, cur_in, srcs_in, E_IN);
  k_fill<<<nblk(E_SS), 256, 0, stream>>>(src_ss, dst_ss, cur_ss, srcs_ss, E_SS);
  k_rsqrt_deg<<<nblk(NSV), 256, 0, stream>>>(cnt_ss, dinvS, NSV);
  k_agg_h64<<<NB64, 256, 0, stream>>>(gx16, rs_h, cnt_h, eh, aggHw, aggHu);
  k_agg64b<<<NB64, 256, 0, stream>>>(gx16, rs_in, cnt_in, srcs_in, aggIN, NSV);

  // ---- Phase C: graph_conv + 3x SAGE ----
  k_node_mm<<<NB, 256, 0, stream>>>(aggHw, nullptr, W3_rel, state_x, 5, W3_root, b3, S1, NSV, 1, 0);
  k_node_mm<<<NB, 256, 0, stream>>>(aggHu, cnt_h,   W32_l, S1, 64, W32_r, b32, S2, NSV, 1, 0);
  k_node_mm<<<NB, 256, 0, stream>>>(aggIN, cnt_in,  W4_l,  S2, 64, W4_r,  b4,  S1, NSV, 1, 0);
  k_node_mm<<<NB, 256, 0, stream>>>(aggIN, cnt_in,  W42_l, S1, 64, W42_r, b42, S2, NSV, 1, 0);

  // ---- Phase D: TAG on s-s ----
  k_tag64<<<NB64, 256, 0, stream>>>(S2, rs_ss, cnt_ss, srcs_ss, dinvS, t1, NSV);
  k_tag64<<<NB64, 256, 0, stream>>>(t1, rs_ss, cnt_ss, srcs_ss, dinvS, t2, NSV);
  k_tag64<<<NB64, 256, 0, stream>>>(t2, rs_ss, cnt_ss, srcs_ss, dinvS, t3, NSV);
  k_node_mm<<<NB, 256, 0, stream>>>(S2, nullptr, W2,        t1, 64, W2 + 4096,  b2,      S1, NSV, 0, 0);
  k_node_mm<<<NB, 256, 0, stream>>>(t2, nullptr, W2 + 8192, t3, 64, W2 + 12288, nullptr, S1, NSV, 1, 1);

  // ---- Phase E: SAGE on s-s ----
  k_agg64<<<NB64, 256, 0, stream>>>(S1, rs_ss, cnt_ss, srcs_ss, aggSS, NSV);
  k_node_mm<<<NB, 256, 0, stream>>>(aggSS, cnt_ss, W5_l, S1, 64, W5_r, b5, S2, NSV, 1, 0);

  // ---- Final projection ----
  k_final<<<nblk(NSV * 8), 256, 0, stream>>>(S2, Wl, bl, (float*)d_out);
}

// Round 5
// 1301.164 us; speedup vs baseline: 2.6184x; 1.0241x over previous
//
#include <hip/hip_runtime.h>

#define NVV 100000
#define NSV 50000
#define E_VV 1600000
#define E_H  800000
#define E_IN 800000
#define E_SS 800000
#define DIN 5
#define NROWS 250000          // concatenated count/rowstart space: vv|h|in|ss
#define H_ROW 100000
#define IN_ROW 150000
#define SS_ROW 200000
#define POS_H  E_VV
#define POS_IN (E_VV + E_H)
#define POS_SS (E_VV + E_H + E_IN)
#define NBUK 196              // vv buckets: dst >> 9
#define BSHIFT 9
#define T1 4096               // edges per stage-1 block

__device__ __forceinline__ unsigned short f2bf(float x) {
  unsigned b = __float_as_uint(x);
  return (unsigned short)((b + 0x7FFFu + ((b >> 16) & 1u)) >> 16);
}
__device__ __forceinline__ float bf2f(unsigned short u) {
  return __uint_as_float(((unsigned)u) << 16);
}

// ====================== unified CSR build ======================

__global__ void k_count_all(const int* __restrict__ d_vv, const int* __restrict__ d_h,
                            const int* __restrict__ d_in, const int* __restrict__ d_ss,
                            int* __restrict__ cnt) {
  int g = blockIdx.x * 256 + threadIdx.x;
  if (g < E_VV) atomicAdd(&cnt[d_vv[g]], 1);
  else if (g < POS_IN) atomicAdd(&cnt[H_ROW + d_h[g - POS_H]], 1);
  else if (g < POS_SS) atomicAdd(&cnt[IN_ROW + d_in[g - POS_IN]], 1);
  else if (g < POS_SS + E_SS) atomicAdd(&cnt[SS_ROW + d_ss[g - POS_SS]], 1);
}

__global__ void k_scan_bsum(const int* __restrict__ cnt, int* __restrict__ bsum, int n) {
  int tid = threadIdx.x, b = blockIdx.x;
  int base = b * 1024 + tid * 4;
  int s = 0;
#pragma unroll
  for (int i = 0; i < 4; i++) { int idx = base + i; if (idx < n) s += cnt[idx]; }
  __shared__ int sd[256];
  sd[tid] = s; __syncthreads();
  for (int off = 128; off > 0; off >>= 1) {
    if (tid < off) sd[tid] += sd[tid + off];
    __syncthreads();
  }
  if (tid == 0) bsum[b] = sd[0];
}

__global__ void k_scan_carry(const int* __restrict__ bsum, int* __restrict__ bscan, int g) {
  int tid = threadIdx.x;
  __shared__ int sd[256];
  int my = (tid < g) ? bsum[tid] : 0;
  sd[tid] = my; __syncthreads();
  for (int off = 1; off < 256; off <<= 1) {
    int t = (tid >= off) ? sd[tid - off] : 0;
    __syncthreads();
    sd[tid] += t;
    __syncthreads();
  }
  if (tid < g) bscan[tid] = sd[tid] - my;
}

__global__ void k_scan_write(const int* __restrict__ cnt, const int* __restrict__ bscan,
                             int* __restrict__ rowstart, int* __restrict__ cursor, int n) {
  int tid = threadIdx.x, b = blockIdx.x;
  int base = b * 1024 + tid * 4;
  int v[4]; int s = 0;
#pragma unroll
  for (int i = 0; i < 4; i++) { int idx = base + i; v[i] = (idx < n) ? cnt[idx] : 0; s += v[i]; }
  __shared__ int sd[256];
  sd[tid] = s; __syncthreads();
  for (int off = 1; off < 256; off <<= 1) {
    int t = (tid >= off) ? sd[tid - off] : 0;
    __syncthreads();
    sd[tid] += t;
    __syncthreads();
  }
  int run = bscan[b] + sd[tid] - s;
#pragma unroll
  for (int i = 0; i < 4; i++) {
    int idx = base + i;
    if (idx < n) { rowstart[idx] = run; cursor[idx] = run; run += v[i]; }
  }
}

__global__ void k_binit(const int* __restrict__ rs, int* __restrict__ cur_b) {
  int b = threadIdx.x;
  if (b < NBUK) cur_b[b] = rs[b << BSHIFT];
}

// Stage 1: bucket-grouped binning of vv edges with coalesced run writes.
// temp entry: [dstloc:9][et:2][src:17]
__global__ __launch_bounds__(256)
void k_fill_vv_s1(const int* __restrict__ src, const int* __restrict__ dst,
                  const int* __restrict__ et,
                  int* __restrict__ cur_b, unsigned* __restrict__ temp) {
  __shared__ int hist[NBUK], lbase[NBUK], run[NBUK], gb[NBUK];
  __shared__ int sc[256];
  __shared__ unsigned stage[T1];
  __shared__ int gpos[T1];
  const int tid = threadIdx.x;
  const int base = blockIdx.x * T1;
  const int nvalid = min(T1, E_VV - base);
  for (int i = tid; i < NBUK; i += 256) { hist[i] = 0; run[i] = 0; }
  __syncthreads();
  int dv[16]; unsigned pk[16];
#pragma unroll
  for (int k = 0; k < 16; k++) {
    int e = base + k * 256 + tid;
    if (e < E_VV) {
      int d = dst[e];
      dv[k] = d;
      pk[k] = (unsigned)(((d & 511) << 19) | (et[e] << 17) | src[e]);
      atomicAdd(&hist[d >> BSHIFT], 1);
    } else dv[k] = -1;
  }
  __syncthreads();
  int my = (tid < NBUK) ? hist[tid] : 0;
  sc[tid] = my; __syncthreads();
  for (int off = 1; off < 256; off <<= 1) {
    int t = (tid >= off) ? sc[tid - off] : 0;
    __syncthreads();
    sc[tid] += t;
    __syncthreads();
  }
  if (tid < NBUK) {
    lbase[tid] = sc[tid] - my;
    gb[tid] = my ? atomicAdd(&cur_b[tid], my) : 0;
  }
  __syncthreads();
#pragma unroll
  for (int k = 0; k < 16; k++) {
    if (dv[k] >= 0) {
      int b = dv[k] >> BSHIFT;
      int loc = atomicAdd(&run[b], 1);
      int li = lbase[b] + loc;
      stage[li] = pk[k];
      gpos[li] = gb[b] + loc;
    }
  }
  __syncthreads();
  for (int i = tid; i < nvalid; i += 256) temp[gpos[i]] = stage[i];
}

// Stage 2: one WG per bucket; LDS per-dst cursors; scatter confined to ~128KB window.
__global__ __launch_bounds__(256)
void k_fill_vv_s2(const unsigned* __restrict__ temp, const int* __restrict__ rs,
                  unsigned* __restrict__ payload) {
  __shared__ int cur[1 << BSHIFT];
  const int b = blockIdx.x, tid = threadIdx.x;
  const int d0 = b << BSHIFT;
  for (int d = tid; d < (1 << BSHIFT); d += 256) {
    int gd = d0 + d;
    cur[d] = (gd < NVV) ? rs[gd] : 0;
  }
  __syncthreads();
  const int gstart = rs[d0];
  const int gend = (b == NBUK - 1) ? E_VV : rs[d0 + (1 << BSHIFT)];
  for (int i = gstart + tid; i < gend; i += 256) {
    unsigned en = temp[i];
    int pos = atomicAdd(&cur[en >> 19], 1);
    payload[pos] = en & 0x7FFFFu;   // [et:2][src:17]
  }
}

// Fused fill for h / in / ss
__global__ void k_fill_hss(const int* __restrict__ s_h, const int* __restrict__ d_h,
                           const float* __restrict__ ew,
                           const int* __restrict__ s_in, const int* __restrict__ d_in,
                           const int* __restrict__ s_ss, const int* __restrict__ d_ss,
                           int* __restrict__ cur, int2* __restrict__ eh,
                           int* __restrict__ srcs_in, int* __restrict__ srcs_ss) {
  int g = blockIdx.x * 256 + threadIdx.x;
  if (g < E_H) {
    int p = atomicAdd(&cur[H_ROW + d_h[g]], 1);
    eh[p - POS_H] = make_int2(s_h[g], __float_as_int(ew[g]));
  } else if (g < E_H + E_IN) {
    int e = g - E_H;
    int p = atomicAdd(&cur[IN_ROW + d_in[e]], 1);
    srcs_in[p - POS_IN] = s_in[e];
  } else if (g < E_H + E_IN + E_SS) {
    int e = g - E_H - E_IN;
    int p = atomicAdd(&cur[SS_ROW + d_ss[e]], 1);
    srcs_ss[p - POS_SS] = s_ss[e];
  }
}

__global__ void k_rsqrt_deg(const int* __restrict__ deg, float* __restrict__ dinv, int n) {
  int i = blockIdx.x * 256 + threadIdx.x;
  if (i >= n) return;
  float d = (float)deg[i];
  dinv[i] = d > 0.f ? rsqrtf(d) : 0.f;
}

// ====================== Phase A: v-graph (5-dim, padded rows) ======================

__global__ void k_prep_x(const float* __restrict__ x, const int* __restrict__ cnt,
                         float4* __restrict__ xp) {
  int v = blockIdx.x * 256 + threadIdx.x;
  if (v >= NVV) return;
  float d = (float)cnt[v];
  float di = d > 0.f ? rsqrtf(d) : 0.f;
  const float* xr = x + v * 5;
  xp[v * 2]     = make_float4(xr[0], xr[1], xr[2], xr[3]);
  xp[v * 2 + 1] = make_float4(xr[4], di, 0.f, 0.f);
}

__global__ __launch_bounds__(256)
void k_vv_pass1(const float4* __restrict__ xp,
                const int* __restrict__ rowstart, const int* __restrict__ cnt,
                const unsigned* __restrict__ payload,
                float* __restrict__ relall, float4* __restrict__ h1p) {
  int d = blockIdx.x * 256 + threadIdx.x;
  if (d >= NVV) return;
  int rs = rowstart[d], c = cnt[d];
  float a0[5] = {0,0,0,0,0}, a1[5] = {0,0,0,0,0}, a2[5] = {0,0,0,0,0}, h[5] = {0,0,0,0,0};
  float c0 = 0.f, c1 = 0.f, c2 = 0.f;
  for (int j = 0; j < c; j++) {
    unsigned p = payload[rs + j];
    int s = p & 0x1FFFF, r = p >> 17;
    float4 x0 = xp[s * 2], x1 = xp[s * 2 + 1];
    float xs[5] = {x0.x, x0.y, x0.z, x0.w, x1.x};
    float wsc = x1.y;
    float m0 = (r == 0) ? 1.f : 0.f, m1 = (r == 1) ? 1.f : 0.f, m2 = (r == 2) ? 1.f : 0.f;
    c0 += m0; c1 += m1; c2 += m2;
#pragma unroll
    for (int k = 0; k < 5; k++) {
      h[k] += wsc * xs[k];
      a0[k] += m0 * xs[k]; a1[k] += m1 * xs[k]; a2[k] += m2 * xs[k];
    }
  }
  float dv = xp[d * 2 + 1].y;
  float* ra = relall + d * 18;
#pragma unroll
  for (int k = 0; k < 5; k++) { ra[k] = a0[k]; ra[5 + k] = a1[k]; ra[10 + k] = a2[k]; }
  ra[15] = c0; ra[16] = c1; ra[17] = c2;
  h1p[d * 2]     = make_float4(dv * h[0], dv * h[1], dv * h[2], dv * h[3]);
  h1p[d * 2 + 1] = make_float4(dv * h[4], dv, 0.f, 0.f);
}

__global__ __launch_bounds__(256)
void k_vv_hop(const float4* __restrict__ hinp,
              const int* __restrict__ rowstart, const int* __restrict__ cnt,
              const unsigned* __restrict__ payload, float4* __restrict__ houtp) {
  int d = blockIdx.x * 256 + threadIdx.x;
  if (d >= NVV) return;
  int rs = rowstart[d], c = cnt[d];
  float h[5] = {0,0,0,0,0};
  for (int j = 0; j < c; j++) {
    int s = payload[rs + j] & 0x1FFFF;
    float4 x0 = hinp[s * 2], x1 = hinp[s * 2 + 1];
    float wsc = x1.y;
    h[0] += wsc * x0.x; h[1] += wsc * x0.y; h[2] += wsc * x0.z; h[3] += wsc * x0.w;
    h[4] += wsc * x1.x;
  }
  float dv = hinp[d * 2 + 1].y;
  houtp[d * 2]     = make_float4(dv * h[0], dv * h[1], dv * h[2], dv * h[3]);
  houtp[d * 2 + 1] = make_float4(dv * h[4], dv, 0.f, 0.f);
}

__global__ __launch_bounds__(256)
void k_combine_gx(const float4* __restrict__ xp,
                  const float* __restrict__ relall,
                  const float4* __restrict__ h1p, const float4* __restrict__ h2p,
                  const float4* __restrict__ h3p,
                  const float* __restrict__ W1_rel, const float* __restrict__ W1_root,
                  const float* __restrict__ b1,
                  const float* __restrict__ W12, const float* __restrict__ b12,
                  unsigned short* __restrict__ gx16) {
  __shared__ float Ws[7 * 320];
  __shared__ float bs[64];
  int tid = threadIdx.x;
  for (int i = tid; i < 320; i += 256) {
    Ws[i]        = W1_root[i] + W12[i];
    Ws[320 + i]  = W1_rel[i];
    Ws[640 + i]  = W1_rel[320 + i];
    Ws[960 + i]  = W1_rel[640 + i];
    Ws[1280 + i] = W12[320 + i];
    Ws[1600 + i] = W12[640 + i];
    Ws[1920 + i] = W12[960 + i];
  }
  if (tid < 64) bs[tid] = b1[tid] + b12[tid];
  __syncthreads();
  int v = blockIdx.x * 4 + (tid >> 6);
  if (v >= NVV) return;
  int f = tid & 63;
  float in[35];
  {
    float4 x0 = xp[v * 2], x1 = xp[v * 2 + 1];
    in[0] = x0.x; in[1] = x0.y; in[2] = x0.z; in[3] = x0.w; in[4] = x1.x;
  }
  const float* ra = relall + v * 18;
#pragma unroll
  for (int r = 0; r < 3; r++) {
    float inv = 1.0f / fmaxf(ra[15 + r], 1.0f);
#pragma unroll
    for (int j = 0; j < DIN; j++) in[5 + r * 5 + j] = ra[r * 5 + j] * inv;
  }
  {
    float4 a = h1p[v * 2], b = h1p[v * 2 + 1];
    in[20] = a.x; in[21] = a.y; in[22] = a.z; in[23] = a.w; in[24] = b.x;
    a = h2p[v * 2]; b = h2p[v * 2 + 1];
    in[25] = a.x; in[26] = a.y; in[27] = a.z; in[28] = a.w; in[29] = b.x;
    a = h3p[v * 2]; b = h3p[v * 2 + 1];
    in[30] = a.x; in[31] = a.y; in[32] = a.z; in[33] = a.w; in[34] = b.x;
  }
  float acc = bs[f];
#pragma unroll
  for (int t = 0; t < 35; t++) acc += in[t] * Ws[t * 64 + f];
  gx16[v * 64 + f] = f2bf(acc);
}

// ================= 64-dim CSR gathers (wave per dst, lane=feature) =================

__global__ __launch_bounds__(256)
void k_agg_h64(const unsigned short* __restrict__ X16,
               const int* __restrict__ rowstart, const int* __restrict__ cnt,
               const int2* __restrict__ eh, int posoff,
               float* __restrict__ outw, float* __restrict__ outu) {
  int wid = blockIdx.x * 4 + (threadIdx.x >> 6);
  if (wid >= NSV) return;
  int lane = threadIdx.x & 63;
  int rs = rowstart[wid] - posoff, c = cnt[wid];
  float aw = 0.f, au = 0.f;
  for (int j = 0; j < c; j++) {
    int2 p = eh[rs + j];
    float v = bf2f(X16[p.x * 64 + lane]);
    au += v; aw += __int_as_float(p.y) * v;
  }
  outw[wid * 64 + lane] = aw;
  outu[wid * 64 + lane] = au;
}

__global__ __launch_bounds__(256)
void k_agg64b(const unsigned short* __restrict__ X16,
              const int* __restrict__ rowstart, const int* __restrict__ cnt,
              const int* __restrict__ srcs, int posoff, float* __restrict__ out, int n) {
  int wid = blockIdx.x * 4 + (threadIdx.x >> 6);
  if (wid >= n) return;
  int lane = threadIdx.x & 63;
  int rs = rowstart[wid] - posoff, c = cnt[wid];
  float a = 0.f;
  for (int j = 0; j < c; j++) {
    int s = srcs[rs + j];
    a += bf2f(X16[s * 64 + lane]);
  }
  out[wid * 64 + lane] = a;
}

__global__ __launch_bounds__(256)
void k_tag64b(const unsigned short* __restrict__ X16,
              const int* __restrict__ rowstart, const int* __restrict__ cnt,
              const int* __restrict__ srcs, int posoff, const float* __restrict__ dinv,
              unsigned short* __restrict__ out16, int n) {
  int wid = blockIdx.x * 4 + (threadIdx.x >> 6);
  if (wid >= n) return;
  int lane = threadIdx.x & 63;
  int rs = rowstart[wid] - posoff, c = cnt[wid];
  float a = 0.f;
  for (int j = 0; j < c; j++) {
    int s = srcs[rs + j];
    a += dinv[s] * bf2f(X16[s * 64 + lane]);
  }
  out16[wid * 64 + lane] = f2bf(dinv[wid] * a);
}

// ---------------- Fused node matmul ----------------
// out = [relu]( [out +] A'@WA + B@WB + bias ), A' = A/max(cnt,1); A/B f32 or bf16.

__global__ __launch_bounds__(256)
void k_node_mm(const void* __restrict__ Av, int a16f, const int* __restrict__ cntA,
               const float* __restrict__ WA,
               const void* __restrict__ Bv, int DB, int b16f,
               const float* __restrict__ WB,
               const float* __restrict__ bias,
               float* __restrict__ out, unsigned short* __restrict__ out16,
               int n, int dorelu, int accum) {
  __shared__ float WAs[64 * 64];
  __shared__ float WBs[64 * 64];
  __shared__ float bs[64];
  __shared__ float as[64 * 68];
  const int tid = threadIdx.x;
  {
    const float4* w4 = (const float4*)WA;
    float4* s4 = (float4*)WAs;
    for (int i = tid; i < 1024; i += 256) s4[i] = w4[i];
    if (Bv) {
      const float4* wb4 = (const float4*)WB;
      float4* sb4 = (float4*)WBs;
      int nb = DB * 16;
      for (int i = tid; i < nb; i += 256) sb4[i] = wb4[i];
    }
    if (tid < 64) bs[tid] = bias ? bias[tid] : 0.0f;
  }
  const int gb = blockIdx.x * 64;
  for (int i = tid; i < 1024; i += 256) {
    int nl = i >> 4, k4 = i & 15;
    int g = gb + nl;
    float4 v = make_float4(0.f, 0.f, 0.f, 0.f);
    if (g < n) {
      if (a16f) {
        uint2 u = ((const uint2*)((const unsigned short*)Av + (size_t)g * 64))[k4];
        v.x = bf2f((unsigned short)(u.x & 0xFFFF));
        v.y = bf2f((unsigned short)(u.x >> 16));
        v.z = bf2f((unsigned short)(u.y & 0xFFFF));
        v.w = bf2f((unsigned short)(u.y >> 16));
      } else {
        v = ((const float4*)Av)[g * 16 + k4];
      }
      if (cntA) {
        float sc = 1.0f / fmaxf((float)cntA[g], 1.0f);
        v.x *= sc; v.y *= sc; v.z *= sc; v.w *= sc;
      }
    }
    *(float4*)(&as[nl * 68 + k4 * 4]) = v;
  }
  __syncthreads();
  const int lane = tid & 63;
  const int fq = lane & 15, nq = lane >> 4;
  const int f0 = fq * 4;
  const int nl0 = (tid >> 6) * 16 + nq * 4;
  float acc[4][4];
#pragma unroll
  for (int j = 0; j < 4; j++)
#pragma unroll
    for (int jj = 0; jj < 4; jj++) acc[j][jj] = 0.f;
#pragma unroll 4
  for (int k = 0; k < 64; k++) {
    float4 w = *(const float4*)(&WAs[k * 64 + f0]);
#pragma unroll
    for (int j = 0; j < 4; j++) {
      float a = as[(nl0 + j) * 68 + k];
      acc[j][0] += a * w.x; acc[j][1] += a * w.y; acc[j][2] += a * w.z; acc[j][3] += a * w.w;
    }
  }
  if (Bv) {
    __syncthreads();
    if (DB == 64) {
      for (int i = tid; i < 1024; i += 256) {
        int nl = i >> 4, k4 = i & 15;
        int g = gb + nl;
        float4 v = make_float4(0.f, 0.f, 0.f, 0.f);
        if (g < n) {
          if (b16f) {
            uint2 u = ((const uint2*)((const unsigned short*)Bv + (size_t)g * 64))[k4];
            v.x = bf2f((unsigned short)(u.x & 0xFFFF));
            v.y = bf2f((unsigned short)(u.x >> 16));
            v.z = bf2f((unsigned short)(u.y & 0xFFFF));
            v.w = bf2f((unsigned short)(u.y >> 16));
          } else {
            v = ((const float4*)Bv)[g * 16 + k4];
          }
        }
        *(float4*)(&as[nl * 68 + k4 * 4]) = v;
      }
    } else {
      const float* Bf = (const float*)Bv;
      for (int i = tid; i < 64 * DB; i += 256) {
        int nl = i / DB, k = i - nl * DB;
        int g = gb + nl;
        as[nl * 68 + k] = (g < n) ? Bf[g * DB + k] : 0.f;
      }
    }
    __syncthreads();
    for (int k = 0; k < DB; k++) {
      float4 w = *(const float4*)(&WBs[k * 64 + f0]);
#pragma unroll
      for (int j = 0; j < 4; j++) {
        float a = as[(nl0 + j) * 68 + k];
        acc[j][0] += a * w.x; acc[j][1] += a * w.y; acc[j][2] += a * w.z; acc[j][3] += a * w.w;
      }
    }
  }
#pragma unroll
  for (int j = 0; j < 4; j++) {
    int g = gb + nl0 + j;
    if (g < n) {
#pragma unroll
      for (int jj = 0; jj < 4; jj++) {
        int f = f0 + jj;
        float v = acc[j][jj] + bs[f];
        if (accum) v += out[g * 64 + f];
        if (dorelu) v = fmaxf(v, 0.f);
        out[g * 64 + f] = v;
        if (out16) out16[g * 64 + f] = f2bf(v);
      }
    }
  }
}

// ---------------- Final projection ----------------

__global__ void k_final(const float* __restrict__ X, const float* __restrict__ Wl,
                        const float* __restrict__ bl, float* __restrict__ out) {
  __shared__ float Ws[64 * 8];
  __shared__ float bsh[8];
  int tid = threadIdx.x;
  for (int i = tid; i < 512; i += 256) Ws[i] = Wl[i];
  if (tid < 8) bsh[tid] = bl[tid];
  __syncthreads();
  int gid = blockIdx.x * 256 + tid;
  if (gid >= NSV * 8) return;
  int v = gid >> 3, f = gid & 7;
  float acc = bsh[f];
  const float* xr = X + v * 64;
#pragma unroll 8
  for (int k = 0; k < 64; k++) acc += xr[k] * Ws[k * 8 + f];
  out[gid] = acc;
}

// ---------------- Host ----------------

extern "C" void kernel_launch(void* const* d_in, const int* in_sizes, int n_in,
                              void* d_out, int out_size, void* d_ws, size_t ws_size,
                              hipStream_t stream) {
  const float* game_x  = (const float*)d_in[0];
  const float* state_x = (const float*)d_in[1];
  const int*   ei_vv   = (const int*)d_in[2];
  const int*   et_vv   = (const int*)d_in[3];
  const int*   ei_h    = (const int*)d_in[4];
  const float* ew_h    = (const float*)d_in[5];
  const int*   ei_in   = (const int*)d_in[6];
  const int*   ei_ss   = (const int*)d_in[7];
  const float* W1_rel  = (const float*)d_in[8];
  const float* W1_root = (const float*)d_in[9];
  const float* b1      = (const float*)d_in[10];
  const float* W12     = (const float*)d_in[11];
  const float* b12     = (const float*)d_in[12];
  const float* W2      = (const float*)d_in[13];
  const float* b2      = (const float*)d_in[14];
  const float* W3_rel  = (const float*)d_in[15];
  const float* W3_root = (const float*)d_in[16];
  const float* b3      = (const float*)d_in[17];
  const float* W32_l   = (const float*)d_in[18];
  const float* W32_r   = (const float*)d_in[19];
  const float* b32     = (const float*)d_in[20];
  const float* W4_l    = (const float*)d_in[21];
  const float* W4_r    = (const float*)d_in[22];
  const float* b4      = (const float*)d_in[23];
  const float* W42_l   = (const float*)d_in[24];
  const float* W42_r   = (const float*)d_in[25];
  const float* b42     = (const float*)d_in[26];
  const float* W5_l    = (const float*)d_in[27];
  const float* W5_r    = (const float*)d_in[28];
  const float* b5      = (const float*)d_in[29];
  const float* Wl      = (const float*)d_in[30];
  const float* bl      = (const float*)d_in[31];

  // Workspace (4B slots), 25.9M slots = 103.6 MiB (within round-1-proven budget).
  float* ws = (float*)d_ws;
  int*   cnt_all = (int*)(ws + 0);              // 250K
  int*   rs_all  = (int*)(ws + 250000);         // 250K
  int*   cur_all = (int*)(ws + 500000);         // 250K
  int*   bsum    = (int*)(ws + 750000);         // 256
  int*   bscan   = (int*)(ws + 750256);         // 256
  int*   cur_b   = (int*)(ws + 750512);         // 256
  int*   srcs_ss = (int*)(ws + 760000);         // 0.8M  (lives through phase E)
  float4* x_pad  = (float4*)(ws + 1600000);     // 800K
  float4* h1p    = (float4*)(ws + 2400000);
  float4* h2p    = (float4*)(ws + 3200000);
  float4* h3p    = (float4*)(ws + 4000000);
  float* relall  = ws + 4800000;                // 1.8M -> ends 6.6M
  float* dinvS   = ws + 6600000;                // 50K
  unsigned short* gx16 = (unsigned short*)(ws + 6700000);  // [NVV][64] bf16 = 3.2M SLOTS -> ends 9.9M
  unsigned* temp_vv    = (unsigned*)(ws + 6700000);        // 1.6M, overlays gx16 front (dead before combine)
  float* aggHw = ws + 9900000;                  // 3.2M
  float* aggHu = ws + 13100000;                 // 3.2M
  float* aggIN = ws + 16300000;                 // 3.2M
  float* S1    = ws + 19500000;                 // 3.2M
  float* S2    = ws + 22700000;                 // 3.2M -> ends 25.9M
  // overlays (aliases verified dead-before-write):
  unsigned short* S2b = (unsigned short*)aggHw;              // [9.9M,11.5M) C4 shadow; aggHw dead after MM-C1
  float*          aggSS = aggHw + 1600000;                   // [11.5M,14.7M) phase E; S2b+t1b dead by then
  unsigned short* t1b = (unsigned short*)aggHu;              // [13.1M,14.7M); aggHu dead after MM-C2
  unsigned short* t2b = (unsigned short*)(aggHu + 1600000);  // [14.7M,16.3M)
  unsigned short* t3b = (unsigned short*)aggIN;              // [16.3M,17.9M); aggIN dead after MM-C4
  unsigned short* S1b = (unsigned short*)(aggIN + 1600000);  // [17.9M,19.5M) D2 shadow
  unsigned* payload_vv = (unsigned*)S1;                      // [19.5M,21.1M); dead before MM-C1 writes S1
  int2*     eh         = (int2*)S2;                          // [22.7M,24.3M); dead before MM-C2 writes S2
  int*      srcs_in    = (int*)(S2 + 1600000);               // [24.3M,25.1M)

  const int* src_vv = ei_vv;  const int* dst_vv = ei_vv + E_VV;
  const int* src_h  = ei_h;   const int* dst_h  = ei_h + E_H;
  const int* src_in = ei_in;  const int* dst_in = ei_in + E_IN;
  const int* src_ss = ei_ss;  const int* dst_ss = ei_ss + E_SS;

  auto nblk = [](long long n) { return dim3((unsigned)((n + 255) / 256)); };
  const int GALL = (NROWS + 1023) / 1024;   // 245
  const int NB64 = (NSV + 3) / 4;
  const int NB   = (NSV + 63) / 64;

  int* cnt_h  = cnt_all + H_ROW;
  int* cnt_in = cnt_all + IN_ROW;
  int* cnt_ss = cnt_all + SS_ROW;
  int* rs_h   = rs_all + H_ROW;
  int* rs_in  = rs_all + IN_ROW;
  int* rs_ss  = rs_all + SS_ROW;

  // ---- unified CSR build ----
  hipMemsetAsync(cnt_all, 0, NROWS * sizeof(int), stream);
  k_count_all<<<nblk((long long)POS_SS + E_SS), 256, 0, stream>>>(dst_vv, dst_h, dst_in, dst_ss, cnt_all);
  k_scan_bsum<<<GALL, 256, 0, stream>>>(cnt_all, bsum, NROWS);
  k_scan_carry<<<1, 256, 0, stream>>>(bsum, bscan, GALL);
  k_scan_write<<<GALL, 256, 0, stream>>>(cnt_all, bscan, rs_all, cur_all, NROWS);
  k_binit<<<1, 256, 0, stream>>>(rs_all, cur_b);
  k_prep_x<<<nblk(NVV), 256, 0, stream>>>(game_x, cnt_all, x_pad);
  k_fill_vv_s1<<<(E_VV + T1 - 1) / T1, 256, 0, stream>>>(src_vv, dst_vv, et_vv, cur_b, temp_vv);
  k_fill_vv_s2<<<NBUK, 256, 0, stream>>>(temp_vv, rs_all, payload_vv);
  k_fill_hss<<<nblk((long long)E_H + E_IN + E_SS), 256, 0, stream>>>(
      src_h, dst_h, ew_h, src_in, dst_in, src_ss, dst_ss, cur_all, eh, srcs_in, srcs_ss);
  k_rsqrt_deg<<<nblk(NSV), 256, 0, stream>>>(cnt_ss, dinvS, NSV);

  // ---- Phase A: v-graph 5-dim ----
  k_vv_pass1<<<nblk(NVV), 256, 0, stream>>>(x_pad, rs_all, cnt_all, payload_vv, relall, h1p);
  k_vv_hop<<<nblk(NVV), 256, 0, stream>>>(h1p, rs_all, cnt_all, payload_vv, h2p);
  k_vv_hop<<<nblk(NVV), 256, 0, stream>>>(h2p, rs_all, cnt_all, payload_vv, h3p);
  k_combine_gx<<<dim3((NVV + 3) / 4), 256, 0, stream>>>(x_pad, relall, h1p, h2p, h3p,
                                                        W1_rel, W1_root, b1, W12, b12, gx16);

  // ---- Phase B: 64-dim bf16 gathers ----
  k_agg_h64<<<NB64, 256, 0, stream>>>(gx16, rs_h, cnt_h, eh, POS_H, aggHw, aggHu);
  k_agg64b<<<NB64, 256, 0, stream>>>(gx16, rs_in, cnt_in, srcs_in, POS_IN, aggIN, NSV);

  // ---- Phase C: graph_conv + 3x SAGE ----
  k_node_mm<<<NB, 256, 0, stream>>>(aggHw, 0, nullptr, W3_rel, state_x, 5, 0, W3_root, b3, S1, nullptr, NSV, 1, 0);
  k_node_mm<<<NB, 256, 0, stream>>>(aggHu, 0, cnt_h,   W32_l, S1, 64, 0, W32_r, b32, S2, nullptr, NSV, 1, 0);
  k_node_mm<<<NB, 256, 0, stream>>>(aggIN, 0, cnt_in,  W4_l,  S2, 64, 0, W4_r,  b4,  S1, nullptr, NSV, 1, 0);
  k_node_mm<<<NB, 256, 0, stream>>>(aggIN, 0, cnt_in,  W42_l, S1, 64, 0, W42_r, b42, S2, S2b,     NSV, 1, 0);

  // ---- Phase D: TAG on s-s (bf16 hops) ----
  k_tag64b<<<NB64, 256, 0, stream>>>(S2b, rs_ss, cnt_ss, srcs_ss, POS_SS, dinvS, t1b, NSV);
  k_tag64b<<<NB64, 256, 0, stream>>>(t1b, rs_ss, cnt_ss, srcs_ss, POS_SS, dinvS, t2b, NSV);
  k_tag64b<<<NB64, 256, 0, stream>>>(t2b, rs_ss, cnt_ss, srcs_ss, POS_SS, dinvS, t3b, NSV);
  k_node_mm<<<NB, 256, 0, stream>>>(S2, 0, nullptr, W2,        t1b, 64, 1, W2 + 4096,  b2,      S1, nullptr, NSV, 0, 0);
  k_node_mm<<<NB, 256, 0, stream>>>(t2b, 1, nullptr, W2 + 8192, t3b, 64, 1, W2 + 12288, nullptr, S1, S1b,    NSV, 1, 1);

  // ---- Phase E: SAGE on s-s ----
  k_agg64b<<<NB64, 256, 0, stream>>>(S1b, rs_ss, cnt_ss, srcs_ss, POS_SS, aggSS, NSV);
  k_node_mm<<<NB, 256, 0, stream>>>(aggSS, 0, cnt_ss, W5_l, S1, 64, 0, W5_r, b5, S2, nullptr, NSV, 1, 0);

  // ---- Final projection ----
  k_final<<<nblk(NSV * 8), 256, 0, stream>>>(S2, Wl, bl, (float*)d_out);
}

// Round 6
// 1203.383 us; speedup vs baseline: 2.8311x; 1.0813x over previous
//
#include <hip/hip_runtime.h>

#define NVV 100000
#define NSV 50000
#define E_VV 1600000
#define E_H  800000
#define E_IN 800000
#define E_SS 800000
#define DIN 5
#define NROWS 250000          // concatenated count/rowstart space: vv|h|in|ss
#define H_ROW 100000
#define IN_ROW 150000
#define SS_ROW 200000
#define POS_H  E_VV
#define POS_IN (E_VV + E_H)
#define POS_SS (E_VV + E_H + E_IN)
#define NBUK 196              // vv buckets: dst >> 9
#define NBUKS 98              // NSV-graph buckets: dst >> 9
#define BSHIFT 9
#define T1 4096               // edges per stage-1 block

__device__ __forceinline__ unsigned short f2bf(float x) {
  unsigned b = __float_as_uint(x);
  return (unsigned short)((b + 0x7FFFu + ((b >> 16) & 1u)) >> 16);
}
__device__ __forceinline__ float bf2f(unsigned short u) {
  return __uint_as_float(((unsigned)u) << 16);
}

// ====================== unified CSR build ======================

__global__ void k_count_all(const int* __restrict__ d_vv, const int* __restrict__ d_h,
                            const int* __restrict__ d_in, const int* __restrict__ d_ss,
                            int* __restrict__ cnt) {
  int g = blockIdx.x * 256 + threadIdx.x;
  if (g < E_VV) atomicAdd(&cnt[d_vv[g]], 1);
  else if (g < POS_IN) atomicAdd(&cnt[H_ROW + d_h[g - POS_H]], 1);
  else if (g < POS_SS) atomicAdd(&cnt[IN_ROW + d_in[g - POS_IN]], 1);
  else if (g < POS_SS + E_SS) atomicAdd(&cnt[SS_ROW + d_ss[g - POS_SS]], 1);
}

__global__ void k_scan_bsum(const int* __restrict__ cnt, int* __restrict__ bsum, int n) {
  int tid = threadIdx.x, b = blockIdx.x;
  int base = b * 1024 + tid * 4;
  int s = 0;
#pragma unroll
  for (int i = 0; i < 4; i++) { int idx = base + i; if (idx < n) s += cnt[idx]; }
  __shared__ int sd[256];
  sd[tid] = s; __syncthreads();
  for (int off = 128; off > 0; off >>= 1) {
    if (tid < off) sd[tid] += sd[tid + off];
    __syncthreads();
  }
  if (tid == 0) bsum[b] = sd[0];
}

__global__ void k_scan_carry(const int* __restrict__ bsum, int* __restrict__ bscan, int g) {
  int tid = threadIdx.x;
  __shared__ int sd[256];
  int my = (tid < g) ? bsum[tid] : 0;
  sd[tid] = my; __syncthreads();
  for (int off = 1; off < 256; off <<= 1) {
    int t = (tid >= off) ? sd[tid - off] : 0;
    __syncthreads();
    sd[tid] += t;
    __syncthreads();
  }
  if (tid < g) bscan[tid] = sd[tid] - my;
}

__global__ void k_scan_write(const int* __restrict__ cnt, const int* __restrict__ bscan,
                             int* __restrict__ rowstart, int n) {
  int tid = threadIdx.x, b = blockIdx.x;
  int base = b * 1024 + tid * 4;
  int v[4]; int s = 0;
#pragma unroll
  for (int i = 0; i < 4; i++) { int idx = base + i; v[i] = (idx < n) ? cnt[idx] : 0; s += v[i]; }
  __shared__ int sd[256];
  sd[tid] = s; __syncthreads();
  for (int off = 1; off < 256; off <<= 1) {
    int t = (tid >= off) ? sd[tid - off] : 0;
    __syncthreads();
    sd[tid] += t;
    __syncthreads();
  }
  int run = bscan[b] + sd[tid] - s;
#pragma unroll
  for (int i = 0; i < 4; i++) {
    int idx = base + i;
    if (idx < n) { rowstart[idx] = run; run += v[i]; }
  }
}

// init all bucket cursors: vv global-pos; h/in/ss graph-local
__global__ void k_binit_all(const int* __restrict__ rs, int* __restrict__ cb_vv,
                            int* __restrict__ cb_h, int* __restrict__ cb_in,
                            int* __restrict__ cb_ss) {
  int t = threadIdx.x;
  if (t < NBUK) cb_vv[t] = rs[t << BSHIFT];
  if (t < NBUKS) {
    cb_h[t]  = rs[H_ROW  + (t << BSHIFT)] - POS_H;
    cb_in[t] = rs[IN_ROW + (t << BSHIFT)] - POS_IN;
    cb_ss[t] = rs[SS_ROW + (t << BSHIFT)] - POS_SS;
  }
}

// ---- vv two-stage fill (entry: [dstloc:9][et:2][src:17]) ----
__global__ __launch_bounds__(256)
void k_fill_vv_s1(const int* __restrict__ src, const int* __restrict__ dst,
                  const int* __restrict__ et,
                  int* __restrict__ cur_b, unsigned* __restrict__ temp) {
  __shared__ int hist[NBUK], lbase[NBUK], run[NBUK], gb[NBUK];
  __shared__ int sc[256];
  __shared__ unsigned stage[T1];
  __shared__ int gpos[T1];
  const int tid = threadIdx.x;
  const int base = blockIdx.x * T1;
  const int nvalid = min(T1, E_VV - base);
  for (int i = tid; i < NBUK; i += 256) { hist[i] = 0; run[i] = 0; }
  __syncthreads();
  int dv[16]; unsigned pk[16];
#pragma unroll
  for (int k = 0; k < 16; k++) {
    int e = base + k * 256 + tid;
    if (e < E_VV) {
      int d = dst[e];
      dv[k] = d;
      pk[k] = (unsigned)(((d & 511) << 19) | (et[e] << 17) | src[e]);
      atomicAdd(&hist[d >> BSHIFT], 1);
    } else dv[k] = -1;
  }
  __syncthreads();
  int my = (tid < NBUK) ? hist[tid] : 0;
  sc[tid] = my; __syncthreads();
  for (int off = 1; off < 256; off <<= 1) {
    int t = (tid >= off) ? sc[tid - off] : 0;
    __syncthreads();
    sc[tid] += t;
    __syncthreads();
  }
  if (tid < NBUK) {
    lbase[tid] = sc[tid] - my;
    gb[tid] = my ? atomicAdd(&cur_b[tid], my) : 0;
  }
  __syncthreads();
#pragma unroll
  for (int k = 0; k < 16; k++) {
    if (dv[k] >= 0) {
      int b = dv[k] >> BSHIFT;
      int loc = atomicAdd(&run[b], 1);
      int li = lbase[b] + loc;
      stage[li] = pk[k];
      gpos[li] = gb[b] + loc;
    }
  }
  __syncthreads();
  for (int i = tid; i < nvalid; i += 256) temp[gpos[i]] = stage[i];
}

__global__ __launch_bounds__(256)
void k_fill_vv_s2(const unsigned* __restrict__ temp, const int* __restrict__ rs,
                  unsigned* __restrict__ payload) {
  __shared__ int cur[1 << BSHIFT];
  const int b = blockIdx.x, tid = threadIdx.x;
  const int d0 = b << BSHIFT;
  for (int d = tid; d < (1 << BSHIFT); d += 256) {
    int gd = d0 + d;
    cur[d] = (gd < NVV) ? rs[gd] : 0;
  }
  __syncthreads();
  const int gstart = rs[d0];
  const int gend = (b == NBUK - 1) ? E_VV : rs[d0 + (1 << BSHIFT)];
  for (int i = gstart + tid; i < gend; i += 256) {
    unsigned en = temp[i];
    int pos = atomicAdd(&cur[en >> 19], 1);
    payload[pos] = en & 0x7FFFFu;   // [et:2][src:17]
  }
}

// ---- generic NSV-graph two-stage fill (entry: [dstloc:9][src:17]) ----
__global__ __launch_bounds__(256)
void k_fill_s1(const int* __restrict__ src, const int* __restrict__ dst, int ne,
               int* __restrict__ cur_b, unsigned* __restrict__ temp) {
  __shared__ int hist[NBUKS], lbase[NBUKS], run[NBUKS], gb[NBUKS];
  __shared__ int sc[256];
  __shared__ unsigned stage[T1];
  __shared__ int gpos[T1];
  const int tid = threadIdx.x;
  const int base = blockIdx.x * T1;
  const int nvalid = min(T1, ne - base);
  for (int i = tid; i < NBUKS; i += 256) { hist[i] = 0; run[i] = 0; }
  __syncthreads();
  int dv[16]; unsigned pk[16];
#pragma unroll
  for (int k = 0; k < 16; k++) {
    int e = base + k * 256 + tid;
    if (e < ne) {
      int d = dst[e];
      dv[k] = d;
      pk[k] = (unsigned)(((d & 511) << 17) | src[e]);
      atomicAdd(&hist[d >> BSHIFT], 1);
    } else dv[k] = -1;
  }
  __syncthreads();
  int my = (tid < NBUKS) ? hist[tid] : 0;
  sc[tid] = my; __syncthreads();
  for (int off = 1; off < 256; off <<= 1) {
    int t = (tid >= off) ? sc[tid - off] : 0;
    __syncthreads();
    sc[tid] += t;
    __syncthreads();
  }
  if (tid < NBUKS) {
    lbase[tid] = sc[tid] - my;
    gb[tid] = my ? atomicAdd(&cur_b[tid], my) : 0;
  }
  __syncthreads();
#pragma unroll
  for (int k = 0; k < 16; k++) {
    if (dv[k] >= 0) {
      int b = dv[k] >> BSHIFT;
      int loc = atomicAdd(&run[b], 1);
      int li = lbase[b] + loc;
      stage[li] = pk[k];
      gpos[li] = gb[b] + loc;
    }
  }
  __syncthreads();
  for (int i = tid; i < nvalid; i += 256) temp[gpos[i]] = stage[i];
}

__global__ __launch_bounds__(256)
void k_fill_s2(const unsigned* __restrict__ temp, const int* __restrict__ rs_all,
               int row0, int posoff, int nloc, int* __restrict__ payload) {
  __shared__ int cur[1 << BSHIFT];
  const int b = blockIdx.x, tid = threadIdx.x;
  const int d0 = b << BSHIFT;
  for (int d = tid; d < (1 << BSHIFT); d += 256) {
    int gd = d0 + d;
    cur[d] = (gd < NSV) ? rs_all[row0 + gd] - posoff : 0;
  }
  __syncthreads();
  const int gstart = rs_all[row0 + d0] - posoff;
  const int gend = (b == NBUKS - 1) ? nloc : rs_all[row0 + d0 + (1 << BSHIFT)] - posoff;
  for (int i = gstart + tid; i < gend; i += 256) {
    unsigned en = temp[i];
    int pos = atomicAdd(&cur[en >> 17], 1);
    payload[pos] = (int)(en & 0x1FFFFu);
  }
}

// ---- h-graph two-stage fill (uint2: {[dstloc:9][src:17], weight bits}) ----
__global__ __launch_bounds__(256)
void k_fill_h_s1(const int* __restrict__ src, const int* __restrict__ dst,
                 const float* __restrict__ ew,
                 int* __restrict__ cur_b, uint2* __restrict__ temp) {
  __shared__ int hist[NBUKS], lbase[NBUKS], run[NBUKS], gb[NBUKS];
  __shared__ int sc[256];
  __shared__ uint2 stage[T1];
  __shared__ int gpos[T1];
  const int tid = threadIdx.x;
  const int base = blockIdx.x * T1;
  const int nvalid = min(T1, E_H - base);
  for (int i = tid; i < NBUKS; i += 256) { hist[i] = 0; run[i] = 0; }
  __syncthreads();
  int dv[16]; uint2 pk[16];
#pragma unroll
  for (int k = 0; k < 16; k++) {
    int e = base + k * 256 + tid;
    if (e < E_H) {
      int d = dst[e];
      dv[k] = d;
      pk[k] = make_uint2((unsigned)(((d & 511) << 17) | src[e]), (unsigned)__float_as_int(ew[e]));
      atomicAdd(&hist[d >> BSHIFT], 1);
    } else dv[k] = -1;
  }
  __syncthreads();
  int my = (tid < NBUKS) ? hist[tid] : 0;
  sc[tid] = my; __syncthreads();
  for (int off = 1; off < 256; off <<= 1) {
    int t = (tid >= off) ? sc[tid - off] : 0;
    __syncthreads();
    sc[tid] += t;
    __syncthreads();
  }
  if (tid < NBUKS) {
    lbase[tid] = sc[tid] - my;
    gb[tid] = my ? atomicAdd(&cur_b[tid], my) : 0;
  }
  __syncthreads();
#pragma unroll
  for (int k = 0; k < 16; k++) {
    if (dv[k] >= 0) {
      int b = dv[k] >> BSHIFT;
      int loc = atomicAdd(&run[b], 1);
      int li = lbase[b] + loc;
      stage[li] = pk[k];
      gpos[li] = gb[b] + loc;
    }
  }
  __syncthreads();
  for (int i = tid; i < nvalid; i += 256) temp[gpos[i]] = stage[i];
}

__global__ __launch_bounds__(256)
void k_fill_h_s2(const uint2* __restrict__ temp, const int* __restrict__ rs_all,
                 int2* __restrict__ eh) {
  __shared__ int cur[1 << BSHIFT];
  const int b = blockIdx.x, tid = threadIdx.x;
  const int d0 = b << BSHIFT;
  for (int d = tid; d < (1 << BSHIFT); d += 256) {
    int gd = d0 + d;
    cur[d] = (gd < NSV) ? rs_all[H_ROW + gd] - POS_H : 0;
  }
  __syncthreads();
  const int gstart = rs_all[H_ROW + d0] - POS_H;
  const int gend = (b == NBUKS - 1) ? E_H : rs_all[H_ROW + d0 + (1 << BSHIFT)] - POS_H;
  for (int i = gstart + tid; i < gend; i += 256) {
    uint2 en = temp[i];
    int pos = atomicAdd(&cur[en.x >> 17], 1);
    eh[pos] = make_int2((int)(en.x & 0x1FFFFu), (int)en.y);
  }
}

__global__ void k_rsqrt_deg(const int* __restrict__ deg, float* __restrict__ dinv, int n) {
  int i = blockIdx.x * 256 + threadIdx.x;
  if (i >= n) return;
  float d = (float)deg[i];
  dinv[i] = d > 0.f ? rsqrtf(d) : 0.f;
}

// ====================== Phase A: v-graph (5-dim, padded rows) ======================

__global__ void k_prep_x(const float* __restrict__ x, const int* __restrict__ cnt,
                         float4* __restrict__ xp) {
  int v = blockIdx.x * 256 + threadIdx.x;
  if (v >= NVV) return;
  float d = (float)cnt[v];
  float di = d > 0.f ? rsqrtf(d) : 0.f;
  const float* xr = x + v * 5;
  xp[v * 2]     = make_float4(xr[0], xr[1], xr[2], xr[3]);
  xp[v * 2 + 1] = make_float4(xr[4], di, 0.f, 0.f);
}

__global__ __launch_bounds__(256)
void k_vv_pass1(const float4* __restrict__ xp,
                const int* __restrict__ rowstart, const int* __restrict__ cnt,
                const unsigned* __restrict__ payload,
                float* __restrict__ relall, float4* __restrict__ h1p) {
  int d = blockIdx.x * 256 + threadIdx.x;
  if (d >= NVV) return;
  int rs = rowstart[d], c = cnt[d];
  float a0[5] = {0,0,0,0,0}, a1[5] = {0,0,0,0,0}, a2[5] = {0,0,0,0,0}, h[5] = {0,0,0,0,0};
  float c0 = 0.f, c1 = 0.f, c2 = 0.f;
  for (int j = 0; j < c; j++) {
    unsigned p = payload[rs + j];
    int s = p & 0x1FFFF, r = p >> 17;
    float4 x0 = xp[s * 2], x1 = xp[s * 2 + 1];
    float xs[5] = {x0.x, x0.y, x0.z, x0.w, x1.x};
    float wsc = x1.y;
    float m0 = (r == 0) ? 1.f : 0.f, m1 = (r == 1) ? 1.f : 0.f, m2 = (r == 2) ? 1.f : 0.f;
    c0 += m0; c1 += m1; c2 += m2;
#pragma unroll
    for (int k = 0; k < 5; k++) {
      h[k] += wsc * xs[k];
      a0[k] += m0 * xs[k]; a1[k] += m1 * xs[k]; a2[k] += m2 * xs[k];
    }
  }
  float dv = xp[d * 2 + 1].y;
  float* ra = relall + d * 18;
#pragma unroll
  for (int k = 0; k < 5; k++) { ra[k] = a0[k]; ra[5 + k] = a1[k]; ra[10 + k] = a2[k]; }
  ra[15] = c0; ra[16] = c1; ra[17] = c2;
  h1p[d * 2]     = make_float4(dv * h[0], dv * h[1], dv * h[2], dv * h[3]);
  h1p[d * 2 + 1] = make_float4(dv * h[4], dv, 0.f, 0.f);
}

__global__ __launch_bounds__(256)
void k_vv_hop(const float4* __restrict__ hinp,
              const int* __restrict__ rowstart, const int* __restrict__ cnt,
              const unsigned* __restrict__ payload, float4* __restrict__ houtp) {
  int d = blockIdx.x * 256 + threadIdx.x;
  if (d >= NVV) return;
  int rs = rowstart[d], c = cnt[d];
  float h[5] = {0,0,0,0,0};
  for (int j = 0; j < c; j++) {
    int s = payload[rs + j] & 0x1FFFF;
    float4 x0 = hinp[s * 2], x1 = hinp[s * 2 + 1];
    float wsc = x1.y;
    h[0] += wsc * x0.x; h[1] += wsc * x0.y; h[2] += wsc * x0.z; h[3] += wsc * x0.w;
    h[4] += wsc * x1.x;
  }
  float dv = hinp[d * 2 + 1].y;
  houtp[d * 2]     = make_float4(dv * h[0], dv * h[1], dv * h[2], dv * h[3]);
  houtp[d * 2 + 1] = make_float4(dv * h[4], dv, 0.f, 0.f);
}

__global__ __launch_bounds__(256)
void k_combine_gx(const float4* __restrict__ xp,
                  const float* __restrict__ relall,
                  const float4* __restrict__ h1p, const float4* __restrict__ h2p,
                  const float4* __restrict__ h3p,
                  const float* __restrict__ W1_rel, const float* __restrict__ W1_root,
                  const float* __restrict__ b1,
                  const float* __restrict__ W12, const float* __restrict__ b12,
                  unsigned short* __restrict__ gx16) {
  __shared__ float Ws[7 * 320];
  __shared__ float bs[64];
  int tid = threadIdx.x;
  for (int i = tid; i < 320; i += 256) {
    Ws[i]        = W1_root[i] + W12[i];
    Ws[320 + i]  = W1_rel[i];
    Ws[640 + i]  = W1_rel[320 + i];
    Ws[960 + i]  = W1_rel[640 + i];
    Ws[1280 + i] = W12[320 + i];
    Ws[1600 + i] = W12[640 + i];
    Ws[1920 + i] = W12[960 + i];
  }
  if (tid < 64) bs[tid] = b1[tid] + b12[tid];
  __syncthreads();
  int v = blockIdx.x * 4 + (tid >> 6);
  if (v >= NVV) return;
  int f = tid & 63;
  float in[35];
  {
    float4 x0 = xp[v * 2], x1 = xp[v * 2 + 1];
    in[0] = x0.x; in[1] = x0.y; in[2] = x0.z; in[3] = x0.w; in[4] = x1.x;
  }
  const float* ra = relall + v * 18;
#pragma unroll
  for (int r = 0; r < 3; r++) {
    float inv = 1.0f / fmaxf(ra[15 + r], 1.0f);
#pragma unroll
    for (int j = 0; j < DIN; j++) in[5 + r * 5 + j] = ra[r * 5 + j] * inv;
  }
  {
    float4 a = h1p[v * 2], b = h1p[v * 2 + 1];
    in[20] = a.x; in[21] = a.y; in[22] = a.z; in[23] = a.w; in[24] = b.x;
    a = h2p[v * 2]; b = h2p[v * 2 + 1];
    in[25] = a.x; in[26] = a.y; in[27] = a.z; in[28] = a.w; in[29] = b.x;
    a = h3p[v * 2]; b = h3p[v * 2 + 1];
    in[30] = a.x; in[31] = a.y; in[32] = a.z; in[33] = a.w; in[34] = b.x;
  }
  float acc = bs[f];
#pragma unroll
  for (int t = 0; t < 35; t++) acc += in[t] * Ws[t * 64 + f];
  gx16[v * 64 + f] = f2bf(acc);
}

// ================= 64-dim CSR gathers (wave per dst, lane=feature) =================

__global__ __launch_bounds__(256)
void k_agg_h64(const unsigned short* __restrict__ X16,
               const int* __restrict__ rowstart, const int* __restrict__ cnt,
               const int2* __restrict__ eh, int posoff,
               float* __restrict__ outw, float* __restrict__ outu) {
  int wid = blockIdx.x * 4 + (threadIdx.x >> 6);
  if (wid >= NSV) return;
  int lane = threadIdx.x & 63;
  int rs = rowstart[wid] - posoff, c = cnt[wid];
  float aw = 0.f, au = 0.f;
  for (int j = 0; j < c; j++) {
    int2 p = eh[rs + j];
    float v = bf2f(X16[p.x * 64 + lane]);
    au += v; aw += __int_as_float(p.y) * v;
  }
  outw[wid * 64 + lane] = aw;
  outu[wid * 64 + lane] = au;
}

__global__ __launch_bounds__(256)
void k_agg64b(const unsigned short* __restrict__ X16,
              const int* __restrict__ rowstart, const int* __restrict__ cnt,
              const int* __restrict__ srcs, int posoff, float* __restrict__ out, int n) {
  int wid = blockIdx.x * 4 + (threadIdx.x >> 6);
  if (wid >= n) return;
  int lane = threadIdx.x & 63;
  int rs = rowstart[wid] - posoff, c = cnt[wid];
  float a = 0.f;
  for (int j = 0; j < c; j++) {
    int s = srcs[rs + j];
    a += bf2f(X16[s * 64 + lane]);
  }
  out[wid * 64 + lane] = a;
}

__global__ __launch_bounds__(256)
void k_tag64b(const unsigned short* __restrict__ X16,
              const int* __restrict__ rowstart, const int* __restrict__ cnt,
              const int* __restrict__ srcs, int posoff, const float* __restrict__ dinv,
              unsigned short* __restrict__ out16, int n) {
  int wid = blockIdx.x * 4 + (threadIdx.x >> 6);
  if (wid >= n) return;
  int lane = threadIdx.x & 63;
  int rs = rowstart[wid] - posoff, c = cnt[wid];
  float a = 0.f;
  for (int j = 0; j < c; j++) {
    int s = srcs[rs + j];
    a += dinv[s] * bf2f(X16[s * 64 + lane]);
  }
  out16[wid * 64 + lane] = f2bf(dinv[wid] * a);
}

// ---------------- Fused node matmul ----------------
// out = [relu]( [out +] A'@WA + B@WB + bias ), A' = A/max(cnt,1); A/B f32 or bf16.

__global__ __launch_bounds__(256)
void k_node_mm(const void* __restrict__ Av, int a16f, const int* __restrict__ cntA,
               const float* __restrict__ WA,
               const void* __restrict__ Bv, int DB, int b16f,
               const float* __restrict__ WB,
               const float* __restrict__ bias,
               float* __restrict__ out, unsigned short* __restrict__ out16,
               int n, int dorelu, int accum) {
  __shared__ float WAs[64 * 64];
  __shared__ float WBs[64 * 64];
  __shared__ float bs[64];
  __shared__ float as[64 * 68];
  const int tid = threadIdx.x;
  {
    const float4* w4 = (const float4*)WA;
    float4* s4 = (float4*)WAs;
    for (int i = tid; i < 1024; i += 256) s4[i] = w4[i];
    if (Bv) {
      const float4* wb4 = (const float4*)WB;
      float4* sb4 = (float4*)WBs;
      int nb = DB * 16;
      for (int i = tid; i < nb; i += 256) sb4[i] = wb4[i];
    }
    if (tid < 64) bs[tid] = bias ? bias[tid] : 0.0f;
  }
  const int gb = blockIdx.x * 64;
  for (int i = tid; i < 1024; i += 256) {
    int nl = i >> 4, k4 = i & 15;
    int g = gb + nl;
    float4 v = make_float4(0.f, 0.f, 0.f, 0.f);
    if (g < n) {
      if (a16f) {
        uint2 u = ((const uint2*)((const unsigned short*)Av + (size_t)g * 64))[k4];
        v.x = bf2f((unsigned short)(u.x & 0xFFFF));
        v.y = bf2f((unsigned short)(u.x >> 16));
        v.z = bf2f((unsigned short)(u.y & 0xFFFF));
        v.w = bf2f((unsigned short)(u.y >> 16));
      } else {
        v = ((const float4*)Av)[g * 16 + k4];
      }
      if (cntA) {
        float sc = 1.0f / fmaxf((float)cntA[g], 1.0f);
        v.x *= sc; v.y *= sc; v.z *= sc; v.w *= sc;
      }
    }
    *(float4*)(&as[nl * 68 + k4 * 4]) = v;
  }
  __syncthreads();
  const int lane = tid & 63;
  const int fq = lane & 15, nq = lane >> 4;
  const int f0 = fq * 4;
  const int nl0 = (tid >> 6) * 16 + nq * 4;
  float acc[4][4];
#pragma unroll
  for (int j = 0; j < 4; j++)
#pragma unroll
    for (int jj = 0; jj < 4; jj++) acc[j][jj] = 0.f;
#pragma unroll 4
  for (int k = 0; k < 64; k++) {
    float4 w = *(const float4*)(&WAs[k * 64 + f0]);
#pragma unroll
    for (int j = 0; j < 4; j++) {
      float a = as[(nl0 + j) * 68 + k];
      acc[j][0] += a * w.x; acc[j][1] += a * w.y; acc[j][2] += a * w.z; acc[j][3] += a * w.w;
    }
  }
  if (Bv) {
    __syncthreads();
    if (DB == 64) {
      for (int i = tid; i < 1024; i += 256) {
        int nl = i >> 4, k4 = i & 15;
        int g = gb + nl;
        float4 v = make_float4(0.f, 0.f, 0.f, 0.f);
        if (g < n) {
          if (b16f) {
            uint2 u = ((const uint2*)((const unsigned short*)Bv + (size_t)g * 64))[k4];
            v.x = bf2f((unsigned short)(u.x & 0xFFFF));
            v.y = bf2f((unsigned short)(u.x >> 16));
            v.z = bf2f((unsigned short)(u.y & 0xFFFF));
            v.w = bf2f((unsigned short)(u.y >> 16));
          } else {
            v = ((const float4*)Bv)[g * 16 + k4];
          }
        }
        *(float4*)(&as[nl * 68 + k4 * 4]) = v;
      }
    } else {
      const float* Bf = (const float*)Bv;
      for (int i = tid; i < 64 * DB; i += 256) {
        int nl = i / DB, k = i - nl * DB;
        int g = gb + nl;
        as[nl * 68 + k] = (g < n) ? Bf[g * DB + k] : 0.f;
      }
    }
    __syncthreads();
    for (int k = 0; k < DB; k++) {
      float4 w = *(const float4*)(&WBs[k * 64 + f0]);
#pragma unroll
      for (int j = 0; j < 4; j++) {
        float a = as[(nl0 + j) * 68 + k];
        acc[j][0] += a * w.x; acc[j][1] += a * w.y; acc[j][2] += a * w.z; acc[j][3] += a * w.w;
      }
    }
  }
#pragma unroll
  for (int j = 0; j < 4; j++) {
    int g = gb + nl0 + j;
    if (g < n) {
#pragma unroll
      for (int jj = 0; jj < 4; jj++) {
        int f = f0 + jj;
        float v = acc[j][jj] + bs[f];
        if (accum) v += out[g * 64 + f];
        if (dorelu) v = fmaxf(v, 0.f);
        out[g * 64 + f] = v;
        if (out16) out16[g * 64 + f] = f2bf(v);
      }
    }
  }
}

// ---------------- Final projection ----------------

__global__ void k_final(const float* __restrict__ X, const float* __restrict__ Wl,
                        const float* __restrict__ bl, float* __restrict__ out) {
  __shared__ float Ws[64 * 8];
  __shared__ float bsh[8];
  int tid = threadIdx.x;
  for (int i = tid; i < 512; i += 256) Ws[i] = Wl[i];
  if (tid < 8) bsh[tid] = bl[tid];
  __syncthreads();
  int gid = blockIdx.x * 256 + tid;
  if (gid >= NSV * 8) return;
  int v = gid >> 3, f = gid & 7;
  float acc = bsh[f];
  const float* xr = X + v * 64;
#pragma unroll 8
  for (int k = 0; k < 64; k++) acc += xr[k] * Ws[k * 8 + f];
  out[gid] = acc;
}

// ---------------- Host ----------------

extern "C" void kernel_launch(void* const* d_in, const int* in_sizes, int n_in,
                              void* d_out, int out_size, void* d_ws, size_t ws_size,
                              hipStream_t stream) {
  const float* game_x  = (const float*)d_in[0];
  const float* state_x = (const float*)d_in[1];
  const int*   ei_vv   = (const int*)d_in[2];
  const int*   et_vv   = (const int*)d_in[3];
  const int*   ei_h    = (const int*)d_in[4];
  const float* ew_h    = (const float*)d_in[5];
  const int*   ei_in   = (const int*)d_in[6];
  const int*   ei_ss   = (const int*)d_in[7];
  const float* W1_rel  = (const float*)d_in[8];
  const float* W1_root = (const float*)d_in[9];
  const float* b1      = (const float*)d_in[10];
  const float* W12     = (const float*)d_in[11];
  const float* b12     = (const float*)d_in[12];
  const float* W2      = (const float*)d_in[13];
  const float* b2      = (const float*)d_in[14];
  const float* W3_rel  = (const float*)d_in[15];
  const float* W3_root = (const float*)d_in[16];
  const float* b3      = (const float*)d_in[17];
  const float* W32_l   = (const float*)d_in[18];
  const float* W32_r   = (const float*)d_in[19];
  const float* b32     = (const float*)d_in[20];
  const float* W4_l    = (const float*)d_in[21];
  const float* W4_r    = (const float*)d_in[22];
  const float* b4      = (const float*)d_in[23];
  const float* W42_l   = (const float*)d_in[24];
  const float* W42_r   = (const float*)d_in[25];
  const float* b42     = (const float*)d_in[26];
  const float* W5_l    = (const float*)d_in[27];
  const float* W5_r    = (const float*)d_in[28];
  const float* b5      = (const float*)d_in[29];
  const float* Wl      = (const float*)d_in[30];
  const float* bl      = (const float*)d_in[31];

  // Workspace (4B slots), 25.9M slots = 103.6 MiB.
  float* ws = (float*)d_ws;
  int*   cnt_all = (int*)(ws + 0);              // 250K
  int*   rs_all  = (int*)(ws + 250000);         // 250K
  int*   bsum    = (int*)(ws + 500000);         // 256
  int*   bscan   = (int*)(ws + 500256);         // 256
  int*   cb_vv   = (int*)(ws + 500512);         // 256
  int*   cb_h    = (int*)(ws + 500768);         // 128
  int*   cb_in   = (int*)(ws + 500896);         // 128
  int*   cb_ss   = (int*)(ws + 501024);         // 128
  int*   srcs_ss = (int*)(ws + 760000);         // 0.8M  (lives through phase E)
  float4* x_pad  = (float4*)(ws + 1600000);     // 800K
  float4* h1p    = (float4*)(ws + 2400000);
  float4* h2p    = (float4*)(ws + 3200000);
  float4* h3p    = (float4*)(ws + 4000000);
  float* relall  = ws + 4800000;                // 1.8M -> ends 6.6M
  float* dinvS   = ws + 6600000;                // 50K
  unsigned short* gx16 = (unsigned short*)(ws + 6700000);  // [NVV][64] bf16 = 3.2M slots -> 9.9M
  unsigned* temp_vv    = (unsigned*)(ws + 6700000);        // 1.6M, overlays gx16 front (dead before combine)
  float* aggHw = ws + 9900000;                  // 3.2M
  float* aggHu = ws + 13100000;                 // 3.2M
  float* aggIN = ws + 16300000;                 // 3.2M
  float* S1    = ws + 19500000;                 // 3.2M
  float* S2    = ws + 22700000;                 // 3.2M -> ends 25.9M
  // fill temps overlay agg regions (dead until phase B):
  uint2*    temp_h  = (uint2*)aggHw;                         // [9.9M,11.5M)
  unsigned* temp_in = (unsigned*)(aggHw + 1600000);          // [11.5M,12.3M)
  unsigned* temp_ss = (unsigned*)(aggHw + 2400000);          // [12.3M,13.1M)
  // other overlays (aliases verified dead-before-write):
  unsigned short* S2b = (unsigned short*)aggHw;              // C4 shadow; aggHw dead after MM-C1
  float*          aggSS = aggHw + 1600000;                   // phase E; S2b/t1b dead by then
  unsigned short* t1b = (unsigned short*)aggHu;              // aggHu dead after MM-C2
  unsigned short* t2b = (unsigned short*)(aggHu + 1600000);
  unsigned short* t3b = (unsigned short*)aggIN;              // aggIN dead after MM-C4
  unsigned short* S1b = (unsigned short*)(aggIN + 1600000);  // D2 shadow
  unsigned* payload_vv = (unsigned*)S1;                      // dead before MM-C1 writes S1
  int2*     eh         = (int2*)S2;                          // dead before MM-C2 writes S2
  int*      srcs_in    = (int*)(S2 + 1600000);

  const int* src_vv = ei_vv;  const int* dst_vv = ei_vv + E_VV;
  const int* src_h  = ei_h;   const int* dst_h  = ei_h + E_H;
  const int* src_in = ei_in;  const int* dst_in = ei_in + E_IN;
  const int* src_ss = ei_ss;  const int* dst_ss = ei_ss + E_SS;

  auto nblk = [](long long n) { return dim3((unsigned)((n + 255) / 256)); };
  const int GALL = (NROWS + 1023) / 1024;   // 245
  const int NB64 = (NSV + 3) / 4;
  const int NB   = (NSV + 63) / 64;
  const int G1VV = (E_VV + T1 - 1) / T1;    // 391
  const int G1S  = (E_H + T1 - 1) / T1;     // 196

  int* cnt_h  = cnt_all + H_ROW;
  int* cnt_in = cnt_all + IN_ROW;
  int* cnt_ss = cnt_all + SS_ROW;
  int* rs_h   = rs_all + H_ROW;
  int* rs_in  = rs_all + IN_ROW;
  int* rs_ss  = rs_all + SS_ROW;

  // ---- unified CSR build: count -> scan -> two-stage binned fills ----
  hipMemsetAsync(cnt_all, 0, NROWS * sizeof(int), stream);
  k_count_all<<<nblk((long long)POS_SS + E_SS), 256, 0, stream>>>(dst_vv, dst_h, dst_in, dst_ss, cnt_all);
  k_scan_bsum<<<GALL, 256, 0, stream>>>(cnt_all, bsum, NROWS);
  k_scan_carry<<<1, 256, 0, stream>>>(bsum, bscan, GALL);
  k_scan_write<<<GALL, 256, 0, stream>>>(cnt_all, bscan, rs_all, NROWS);
  k_binit_all<<<1, 256, 0, stream>>>(rs_all, cb_vv, cb_h, cb_in, cb_ss);
  k_prep_x<<<nblk(NVV), 256, 0, stream>>>(game_x, cnt_all, x_pad);
  k_fill_vv_s1<<<G1VV, 256, 0, stream>>>(src_vv, dst_vv, et_vv, cb_vv, temp_vv);
  k_fill_vv_s2<<<NBUK, 256, 0, stream>>>(temp_vv, rs_all, payload_vv);
  k_fill_h_s1<<<G1S, 256, 0, stream>>>(src_h, dst_h, ew_h, cb_h, temp_h);
  k_fill_s1<<<G1S, 256, 0, stream>>>(src_in, dst_in, E_IN, cb_in, temp_in);
  k_fill_s1<<<G1S, 256, 0, stream>>>(src_ss, dst_ss, E_SS, cb_ss, temp_ss);
  k_fill_h_s2<<<NBUKS, 256, 0, stream>>>(temp_h, rs_all, eh);
  k_fill_s2<<<NBUKS, 256, 0, stream>>>(temp_in, rs_all, IN_ROW, POS_IN, E_IN, srcs_in);
  k_fill_s2<<<NBUKS, 256, 0, stream>>>(temp_ss, rs_all, SS_ROW, POS_SS, E_SS, srcs_ss);
  k_rsqrt_deg<<<nblk(NSV), 256, 0, stream>>>(cnt_ss, dinvS, NSV);

  // ---- Phase A: v-graph 5-dim ----
  k_vv_pass1<<<nblk(NVV), 256, 0, stream>>>(x_pad, rs_all, cnt_all, payload_vv, relall, h1p);
  k_vv_hop<<<nblk(NVV), 256, 0, stream>>>(h1p, rs_all, cnt_all, payload_vv, h2p);
  k_vv_hop<<<nblk(NVV), 256, 0, stream>>>(h2p, rs_all, cnt_all, payload_vv, h3p);
  k_combine_gx<<<dim3((NVV + 3) / 4), 256, 0, stream>>>(x_pad, relall, h1p, h2p, h3p,
                                                        W1_rel, W1_root, b1, W12, b12, gx16);

  // ---- Phase B: 64-dim bf16 gathers ----
  k_agg_h64<<<NB64, 256, 0, stream>>>(gx16, rs_h, cnt_h, eh, POS_H, aggHw, aggHu);
  k_agg64b<<<NB64, 256, 0, stream>>>(gx16, rs_in, cnt_in, srcs_in, POS_IN, aggIN, NSV);

  // ---- Phase C: graph_conv + 3x SAGE ----
  k_node_mm<<<NB, 256, 0, stream>>>(aggHw, 0, nullptr, W3_rel, state_x, 5, 0, W3_root, b3, S1, nullptr, NSV, 1, 0);
  k_node_mm<<<NB, 256, 0, stream>>>(aggHu, 0, cnt_h,   W32_l, S1, 64, 0, W32_r, b32, S2, nullptr, NSV, 1, 0);
  k_node_mm<<<NB, 256, 0, stream>>>(aggIN, 0, cnt_in,  W4_l,  S2, 64, 0, W4_r,  b4,  S1, nullptr, NSV, 1, 0);
  k_node_mm<<<NB, 256, 0, stream>>>(aggIN, 0, cnt_in,  W42_l, S1, 64, 0, W42_r, b42, S2, S2b,     NSV, 1, 0);

  // ---- Phase D: TAG on s-s (bf16 hops) ----
  k_tag64b<<<NB64, 256, 0, stream>>>(S2b, rs_ss, cnt_ss, srcs_ss, POS_SS, dinvS, t1b, NSV);
  k_tag64b<<<NB64, 256, 0, stream>>>(t1b, rs_ss, cnt_ss, srcs_ss, POS_SS, dinvS, t2b, NSV);
  k_tag64b<<<NB64, 256, 0, stream>>>(t2b, rs_ss, cnt_ss, srcs_ss, POS_SS, dinvS, t3b, NSV);
  k_node_mm<<<NB, 256, 0, stream>>>(S2, 0, nullptr, W2,        t1b, 64, 1, W2 + 4096,  b2,      S1, nullptr, NSV, 0, 0);
  k_node_mm<<<NB, 256, 0, stream>>>(t2b, 1, nullptr, W2 + 8192, t3b, 64, 1, W2 + 12288, nullptr, S1, S1b,    NSV, 1, 1);

  // ---- Phase E: SAGE on s-s ----
  k_agg64b<<<NB64, 256, 0, stream>>>(S1b, rs_ss, cnt_ss, srcs_ss, POS_SS, aggSS, NSV);
  k_node_mm<<<NB, 256, 0, stream>>>(aggSS, 0, cnt_ss, W5_l, S1, 64, 0, W5_r, b5, S2, nullptr, NSV, 1, 0);

  // ---- Final projection ----
  k_final<<<nblk(NSV * 8), 256, 0, stream>>>(S2, Wl, bl, (float*)d_out);
}

// Round 7
// 1080.358 us; speedup vs baseline: 3.1535x; 1.1139x over previous
//
#include <hip/hip_runtime.h>

#define NVV 100000
#define NSV 50000
#define E_VV 1600000
#define E_H  800000
#define E_IN 800000
#define E_SS 800000
#define ETOT 4000000
#define DIN 5
#define H_ROW 100000          // concatenated cnt/rs space: vv|h|in|ss
#define IN_ROW 150000
#define SS_ROW 200000
#define NROWS 250000
#define POS_H  E_VV
#define POS_IN (E_VV + E_H)
#define POS_SS (E_VV + E_H + E_IN)
#define NBUK 196              // vv buckets (dst >> 9)
#define NBUKS 98              // NSV-graph buckets
#define NBTOT 490             // vv|h|in|ss bucket space
#define BUK_H  196
#define BUK_IN 294
#define BUK_SS 392
#define BSHIFT 9
#define T1 4096               // edges per fill-stage-1 block
#define TC 16384              // edges per bucket-count block

__device__ __forceinline__ unsigned short f2bf(float x) {
  unsigned b = __float_as_uint(x);
  return (unsigned short)((b + 0x7FFFu + ((b >> 16) & 1u)) >> 16);
}
__device__ __forceinline__ float bf2f(unsigned short u) {
  return __uint_as_float(((unsigned)u) << 16);
}

// ====================== CSR build: bucket counts -> bases -> binned fills ======================

__global__ __launch_bounds__(256)
void k_bucket_count(const int* __restrict__ d_vv, const int* __restrict__ d_h,
                    const int* __restrict__ d_in, const int* __restrict__ d_ss,
                    int* __restrict__ bcnt) {
  __shared__ int h[NBTOT];
  const int tid = threadIdx.x;
  for (int i = tid; i < NBTOT; i += 256) h[i] = 0;
  __syncthreads();
  const int base = blockIdx.x * TC;
#pragma unroll 4
  for (int k = 0; k < TC / 256; k++) {
    int e = base + k * 256 + tid;
    int bi = -1;
    if (e < E_VV) bi = d_vv[e] >> BSHIFT;
    else if (e < POS_IN) bi = BUK_H + (d_h[e - POS_H] >> BSHIFT);
    else if (e < POS_SS) bi = BUK_IN + (d_in[e - POS_IN] >> BSHIFT);
    else if (e < ETOT) bi = BUK_SS + (d_ss[e - POS_SS] >> BSHIFT);
    if (bi >= 0) atomicAdd(&h[bi], 1);
  }
  __syncthreads();
  for (int i = tid; i < NBTOT; i += 256) if (h[i]) atomicAdd(&bcnt[i], h[i]);
}

// segmented exclusive scan of 490 bucket counts -> graph-local bucket bases + s1 cursors
__global__ __launch_bounds__(512)
void k_bucket_scan(const int* __restrict__ bcnt, int* __restrict__ bbase, int* __restrict__ cb) {
  __shared__ int sd[512];
  int t = threadIdx.x;
  int v = (t < NBTOT) ? bcnt[t] : 0;
  sd[t] = v; __syncthreads();
  for (int off = 1; off < 512; off <<= 1) {
    int x = (t >= off) ? sd[t - off] : 0;
    __syncthreads();
    sd[t] += x;
    __syncthreads();
  }
  int segstart = (t < BUK_H) ? 0 : (t < BUK_IN) ? BUK_H : (t < BUK_SS) ? BUK_IN : BUK_SS;
  int excl = ((t > 0) ? sd[t - 1] : 0) - ((segstart > 0) ? sd[segstart - 1] : 0);
  if (t < NBTOT) { bbase[t] = excl; cb[t] = excl; }
}

// ---- stage 1: bucket-grouped binning, coalesced run writes ----
// vv entry: [dstloc:9][et:2][src:17]
__global__ __launch_bounds__(256)
void k_fill_vv_s1(const int* __restrict__ src, const int* __restrict__ dst,
                  const int* __restrict__ et,
                  int* __restrict__ cur_b, unsigned* __restrict__ temp) {
  __shared__ int hist[NBUK], lbase[NBUK], run[NBUK], gb[NBUK];
  __shared__ int sc[256];
  __shared__ unsigned stage[T1];
  __shared__ int gpos[T1];
  const int tid = threadIdx.x;
  const int base = blockIdx.x * T1;
  const int nvalid = min(T1, E_VV - base);
  for (int i = tid; i < NBUK; i += 256) { hist[i] = 0; run[i] = 0; }
  __syncthreads();
  int dv[16]; unsigned pk[16];
#pragma unroll
  for (int k = 0; k < 16; k++) {
    int e = base + k * 256 + tid;
    if (e < E_VV) {
      int d = dst[e];
      dv[k] = d;
      pk[k] = (unsigned)(((d & 511) << 19) | (et[e] << 17) | src[e]);
      atomicAdd(&hist[d >> BSHIFT], 1);
    } else dv[k] = -1;
  }
  __syncthreads();
  int my = (tid < NBUK) ? hist[tid] : 0;
  sc[tid] = my; __syncthreads();
  for (int off = 1; off < 256; off <<= 1) {
    int t = (tid >= off) ? sc[tid - off] : 0;
    __syncthreads();
    sc[tid] += t;
    __syncthreads();
  }
  if (tid < NBUK) {
    lbase[tid] = sc[tid] - my;
    gb[tid] = my ? atomicAdd(&cur_b[tid], my) : 0;
  }
  __syncthreads();
#pragma unroll
  for (int k = 0; k < 16; k++) {
    if (dv[k] >= 0) {
      int b = dv[k] >> BSHIFT;
      int loc = atomicAdd(&run[b], 1);
      int li = lbase[b] + loc;
      stage[li] = pk[k];
      gpos[li] = gb[b] + loc;
    }
  }
  __syncthreads();
  for (int i = tid; i < nvalid; i += 256) temp[gpos[i]] = stage[i];
}

// generic NSV-graph entry: [dstloc:9][src:17]
__global__ __launch_bounds__(256)
void k_fill_s1(const int* __restrict__ src, const int* __restrict__ dst, int ne,
               int* __restrict__ cur_b, unsigned* __restrict__ temp) {
  __shared__ int hist[NBUKS], lbase[NBUKS], run[NBUKS], gb[NBUKS];
  __shared__ int sc[256];
  __shared__ unsigned stage[T1];
  __shared__ int gpos[T1];
  const int tid = threadIdx.x;
  const int base = blockIdx.x * T1;
  const int nvalid = min(T1, ne - base);
  for (int i = tid; i < NBUKS; i += 256) { hist[i] = 0; run[i] = 0; }
  __syncthreads();
  int dv[16]; unsigned pk[16];
#pragma unroll
  for (int k = 0; k < 16; k++) {
    int e = base + k * 256 + tid;
    if (e < ne) {
      int d = dst[e];
      dv[k] = d;
      pk[k] = (unsigned)(((d & 511) << 17) | src[e]);
      atomicAdd(&hist[d >> BSHIFT], 1);
    } else dv[k] = -1;
  }
  __syncthreads();
  int my = (tid < NBUKS) ? hist[tid] : 0;
  sc[tid] = my; __syncthreads();
  for (int off = 1; off < 256; off <<= 1) {
    int t = (tid >= off) ? sc[tid - off] : 0;
    __syncthreads();
    sc[tid] += t;
    __syncthreads();
  }
  if (tid < NBUKS) {
    lbase[tid] = sc[tid] - my;
    gb[tid] = my ? atomicAdd(&cur_b[tid], my) : 0;
  }
  __syncthreads();
#pragma unroll
  for (int k = 0; k < 16; k++) {
    if (dv[k] >= 0) {
      int b = dv[k] >> BSHIFT;
      int loc = atomicAdd(&run[b], 1);
      int li = lbase[b] + loc;
      stage[li] = pk[k];
      gpos[li] = gb[b] + loc;
    }
  }
  __syncthreads();
  for (int i = tid; i < nvalid; i += 256) temp[gpos[i]] = stage[i];
}

// h-graph: uint2 {[dstloc:9][src:17], weight bits}
__global__ __launch_bounds__(256)
void k_fill_h_s1(const int* __restrict__ src, const int* __restrict__ dst,
                 const float* __restrict__ ew,
                 int* __restrict__ cur_b, uint2* __restrict__ temp) {
  __shared__ int hist[NBUKS], lbase[NBUKS], run[NBUKS], gb[NBUKS];
  __shared__ int sc[256];
  __shared__ uint2 stage[T1];
  __shared__ int gpos[T1];
  const int tid = threadIdx.x;
  const int base = blockIdx.x * T1;
  const int nvalid = min(T1, E_H - base);
  for (int i = tid; i < NBUKS; i += 256) { hist[i] = 0; run[i] = 0; }
  __syncthreads();
  int dv[16]; uint2 pk[16];
#pragma unroll
  for (int k = 0; k < 16; k++) {
    int e = base + k * 256 + tid;
    if (e < E_H) {
      int d = dst[e];
      dv[k] = d;
      pk[k] = make_uint2((unsigned)(((d & 511) << 17) | src[e]), (unsigned)__float_as_int(ew[e]));
      atomicAdd(&hist[d >> BSHIFT], 1);
    } else dv[k] = -1;
  }
  __syncthreads();
  int my = (tid < NBUKS) ? hist[tid] : 0;
  sc[tid] = my; __syncthreads();
  for (int off = 1; off < 256; off <<= 1) {
    int t = (tid >= off) ? sc[tid - off] : 0;
    __syncthreads();
    sc[tid] += t;
    __syncthreads();
  }
  if (tid < NBUKS) {
    lbase[tid] = sc[tid] - my;
    gb[tid] = my ? atomicAdd(&cur_b[tid], my) : 0;
  }
  __syncthreads();
#pragma unroll
  for (int k = 0; k < 16; k++) {
    if (dv[k] >= 0) {
      int b = dv[k] >> BSHIFT;
      int loc = atomicAdd(&run[b], 1);
      int li = lbase[b] + loc;
      stage[li] = pk[k];
      gpos[li] = gb[b] + loc;
    }
  }
  __syncthreads();
  for (int i = tid; i < nvalid; i += 256) temp[gpos[i]] = stage[i];
}

// ---- stage 2: per-bucket LDS count + scan -> cnt/rs coalesced; then in-window scatter ----

__global__ __launch_bounds__(256)
void k_fill_vv_s2(const unsigned* __restrict__ temp, const int* __restrict__ bbase,
                  unsigned* __restrict__ payload, int* __restrict__ rs, int* __restrict__ cnt) {
  __shared__ int lcnt[512], lpos[512];
  __shared__ int sc[256];
  const int b = blockIdx.x, tid = threadIdx.x;
  const int d0 = b << BSHIFT;
  lcnt[tid] = 0; lcnt[tid + 256] = 0;
  __syncthreads();
  const int gstart = bbase[b];
  const int gend = (b == NBUK - 1) ? E_VV : bbase[b + 1];
  for (int i = gstart + tid; i < gend; i += 256) atomicAdd(&lcnt[temp[i] >> 19], 1);
  __syncthreads();
  int c0 = lcnt[2 * tid], c1 = lcnt[2 * tid + 1];
  int ps = c0 + c1;
  sc[tid] = ps; __syncthreads();
  for (int off = 1; off < 256; off <<= 1) {
    int x = (tid >= off) ? sc[tid - off] : 0;
    __syncthreads();
    sc[tid] += x;
    __syncthreads();
  }
  int basep = gstart + sc[tid] - ps;
  lpos[2 * tid] = basep;
  lpos[2 * tid + 1] = basep + c0;
  __syncthreads();
  for (int d = tid; d < 512; d += 256) {
    int gd = d0 + d;
    if (gd < NVV) { rs[gd] = lpos[d]; cnt[gd] = lcnt[d]; }
  }
  __syncthreads();
  for (int i = gstart + tid; i < gend; i += 256) {
    unsigned en = temp[i];
    int pos = atomicAdd(&lpos[en >> 19], 1);
    payload[pos] = en & 0x7FFFFu;   // [et:2][src:17]
  }
}

__global__ __launch_bounds__(256)
void k_fill_s2(const unsigned* __restrict__ temp, const int* __restrict__ bbase, int buk0,
               int nloc, int* __restrict__ payload, int* __restrict__ rs, int* __restrict__ cnt) {
  __shared__ int lcnt[512], lpos[512];
  __shared__ int sc[256];
  const int b = blockIdx.x, tid = threadIdx.x;
  const int d0 = b << BSHIFT;
  lcnt[tid] = 0; lcnt[tid + 256] = 0;
  __syncthreads();
  const int gstart = bbase[buk0 + b];
  const int gend = (b == NBUKS - 1) ? nloc : bbase[buk0 + b + 1];
  for (int i = gstart + tid; i < gend; i += 256) atomicAdd(&lcnt[temp[i] >> 17], 1);
  __syncthreads();
  int c0 = lcnt[2 * tid], c1 = lcnt[2 * tid + 1];
  int ps = c0 + c1;
  sc[tid] = ps; __syncthreads();
  for (int off = 1; off < 256; off <<= 1) {
    int x = (tid >= off) ? sc[tid - off] : 0;
    __syncthreads();
    sc[tid] += x;
    __syncthreads();
  }
  int basep = gstart + sc[tid] - ps;
  lpos[2 * tid] = basep;
  lpos[2 * tid + 1] = basep + c0;
  __syncthreads();
  for (int d = tid; d < 512; d += 256) {
    int gd = d0 + d;
    if (gd < NSV) { rs[gd] = lpos[d]; cnt[gd] = lcnt[d]; }
  }
  __syncthreads();
  for (int i = gstart + tid; i < gend; i += 256) {
    unsigned en = temp[i];
    int pos = atomicAdd(&lpos[en >> 17], 1);
    payload[pos] = (int)(en & 0x1FFFFu);
  }
}

__global__ __launch_bounds__(256)
void k_fill_h_s2(const uint2* __restrict__ temp, const int* __restrict__ bbase,
                 int2* __restrict__ eh, int* __restrict__ rs, int* __restrict__ cnt) {
  __shared__ int lcnt[512], lpos[512];
  __shared__ int sc[256];
  const int b = blockIdx.x, tid = threadIdx.x;
  const int d0 = b << BSHIFT;
  lcnt[tid] = 0; lcnt[tid + 256] = 0;
  __syncthreads();
  const int gstart = bbase[BUK_H + b];
  const int gend = (b == NBUKS - 1) ? E_H : bbase[BUK_H + b + 1];
  for (int i = gstart + tid; i < gend; i += 256) atomicAdd(&lcnt[temp[i].x >> 17], 1);
  __syncthreads();
  int c0 = lcnt[2 * tid], c1 = lcnt[2 * tid + 1];
  int ps = c0 + c1;
  sc[tid] = ps; __syncthreads();
  for (int off = 1; off < 256; off <<= 1) {
    int x = (tid >= off) ? sc[tid - off] : 0;
    __syncthreads();
    sc[tid] += x;
    __syncthreads();
  }
  int basep = gstart + sc[tid] - ps;
  lpos[2 * tid] = basep;
  lpos[2 * tid + 1] = basep + c0;
  __syncthreads();
  for (int d = tid; d < 512; d += 256) {
    int gd = d0 + d;
    if (gd < NSV) { rs[gd] = lpos[d]; cnt[gd] = lcnt[d]; }
  }
  __syncthreads();
  for (int i = gstart + tid; i < gend; i += 256) {
    uint2 en = temp[i];
    int pos = atomicAdd(&lpos[en.x >> 17], 1);
    eh[pos] = make_int2((int)(en.x & 0x1FFFFu), (int)en.y);
  }
}

__global__ void k_rsqrt_deg(const int* __restrict__ deg, float* __restrict__ dinv, int n) {
  int i = blockIdx.x * 256 + threadIdx.x;
  if (i >= n) return;
  float d = (float)deg[i];
  dinv[i] = d > 0.f ? rsqrtf(d) : 0.f;
}

// ====================== Phase A: v-graph (5-dim, padded rows) ======================

__global__ void k_prep_x(const float* __restrict__ x, const int* __restrict__ cnt,
                         float4* __restrict__ xp) {
  int v = blockIdx.x * 256 + threadIdx.x;
  if (v >= NVV) return;
  float d = (float)cnt[v];
  float di = d > 0.f ? rsqrtf(d) : 0.f;
  const float* xr = x + v * 5;
  xp[v * 2]     = make_float4(xr[0], xr[1], xr[2], xr[3]);
  xp[v * 2 + 1] = make_float4(xr[4], di, 0.f, 0.f);
}

__global__ __launch_bounds__(256)
void k_vv_pass1(const float4* __restrict__ xp,
                const int* __restrict__ rowstart, const int* __restrict__ cnt,
                const unsigned* __restrict__ payload,
                float* __restrict__ relall, float4* __restrict__ h1p) {
  int d = blockIdx.x * 256 + threadIdx.x;
  if (d >= NVV) return;
  int rs = rowstart[d], c = cnt[d];
  float a0[5] = {0,0,0,0,0}, a1[5] = {0,0,0,0,0}, a2[5] = {0,0,0,0,0}, h[5] = {0,0,0,0,0};
  float c0 = 0.f, c1 = 0.f, c2 = 0.f;
  for (int j = 0; j < c; j++) {
    unsigned p = payload[rs + j];
    int s = p & 0x1FFFF, r = p >> 17;
    float4 x0 = xp[s * 2], x1 = xp[s * 2 + 1];
    float xs[5] = {x0.x, x0.y, x0.z, x0.w, x1.x};
    float wsc = x1.y;
    float m0 = (r == 0) ? 1.f : 0.f, m1 = (r == 1) ? 1.f : 0.f, m2 = (r == 2) ? 1.f : 0.f;
    c0 += m0; c1 += m1; c2 += m2;
#pragma unroll
    for (int k = 0; k < 5; k++) {
      h[k] += wsc * xs[k];
      a0[k] += m0 * xs[k]; a1[k] += m1 * xs[k]; a2[k] += m2 * xs[k];
    }
  }
  float dv = xp[d * 2 + 1].y;
  float* ra = relall + d * 18;
#pragma unroll
  for (int k = 0; k < 5; k++) { ra[k] = a0[k]; ra[5 + k] = a1[k]; ra[10 + k] = a2[k]; }
  ra[15] = c0; ra[16] = c1; ra[17] = c2;
  h1p[d * 2]     = make_float4(dv * h[0], dv * h[1], dv * h[2], dv * h[3]);
  h1p[d * 2 + 1] = make_float4(dv * h[4], dv, 0.f, 0.f);
}

__global__ __launch_bounds__(256)
void k_vv_hop(const float4* __restrict__ hinp,
              const int* __restrict__ rowstart, const int* __restrict__ cnt,
              const unsigned* __restrict__ payload, float4* __restrict__ houtp) {
  int d = blockIdx.x * 256 + threadIdx.x;
  if (d >= NVV) return;
  int rs = rowstart[d], c = cnt[d];
  float h[5] = {0,0,0,0,0};
  for (int j = 0; j < c; j++) {
    int s = payload[rs + j] & 0x1FFFF;
    float4 x0 = hinp[s * 2], x1 = hinp[s * 2 + 1];
    float wsc = x1.y;
    h[0] += wsc * x0.x; h[1] += wsc * x0.y; h[2] += wsc * x0.z; h[3] += wsc * x0.w;
    h[4] += wsc * x1.x;
  }
  float dv = hinp[d * 2 + 1].y;
  houtp[d * 2]     = make_float4(dv * h[0], dv * h[1], dv * h[2], dv * h[3]);
  houtp[d * 2 + 1] = make_float4(dv * h[4], dv, 0.f, 0.f);
}

__global__ __launch_bounds__(256)
void k_combine_gx(const float4* __restrict__ xp,
                  const float* __restrict__ relall,
                  const float4* __restrict__ h1p, const float4* __restrict__ h2p,
                  const float4* __restrict__ h3p,
                  const float* __restrict__ W1_rel, const float* __restrict__ W1_root,
                  const float* __restrict__ b1,
                  const float* __restrict__ W12, const float* __restrict__ b12,
                  unsigned short* __restrict__ gx16) {
  __shared__ float Ws[7 * 320];
  __shared__ float bs[64];
  int tid = threadIdx.x;
  for (int i = tid; i < 320; i += 256) {
    Ws[i]        = W1_root[i] + W12[i];
    Ws[320 + i]  = W1_rel[i];
    Ws[640 + i]  = W1_rel[320 + i];
    Ws[960 + i]  = W1_rel[640 + i];
    Ws[1280 + i] = W12[320 + i];
    Ws[1600 + i] = W12[640 + i];
    Ws[1920 + i] = W12[960 + i];
  }
  if (tid < 64) bs[tid] = b1[tid] + b12[tid];
  __syncthreads();
  int v = blockIdx.x * 4 + (tid >> 6);
  if (v >= NVV) return;
  int f = tid & 63;
  float in[35];
  {
    float4 x0 = xp[v * 2], x1 = xp[v * 2 + 1];
    in[0] = x0.x; in[1] = x0.y; in[2] = x0.z; in[3] = x0.w; in[4] = x1.x;
  }
  const float* ra = relall + v * 18;
#pragma unroll
  for (int r = 0; r < 3; r++) {
    float inv = 1.0f / fmaxf(ra[15 + r], 1.0f);
#pragma unroll
    for (int j = 0; j < DIN; j++) in[5 + r * 5 + j] = ra[r * 5 + j] * inv;
  }
  {
    float4 a = h1p[v * 2], b = h1p[v * 2 + 1];
    in[20] = a.x; in[21] = a.y; in[22] = a.z; in[23] = a.w; in[24] = b.x;
    a = h2p[v * 2]; b = h2p[v * 2 + 1];
    in[25] = a.x; in[26] = a.y; in[27] = a.z; in[28] = a.w; in[29] = b.x;
    a = h3p[v * 2]; b = h3p[v * 2 + 1];
    in[30] = a.x; in[31] = a.y; in[32] = a.z; in[33] = a.w; in[34] = b.x;
  }
  float acc = bs[f];
#pragma unroll
  for (int t = 0; t < 35; t++) acc += in[t] * Ws[t * 64 + f];
  gx16[v * 64 + f] = f2bf(acc);
}

// ================= 64-dim CSR gathers (wave per dst, lane=feature) =================

__global__ __launch_bounds__(256)
void k_agg_h64(const unsigned short* __restrict__ X16,
               const int* __restrict__ rowstart, const int* __restrict__ cnt,
               const int2* __restrict__ eh,
               float* __restrict__ outw, float* __restrict__ outu) {
  int wid = blockIdx.x * 4 + (threadIdx.x >> 6);
  if (wid >= NSV) return;
  int lane = threadIdx.x & 63;
  int rs = rowstart[wid], c = cnt[wid];
  float aw = 0.f, au = 0.f;
  for (int j = 0; j < c; j++) {
    int2 p = eh[rs + j];
    float v = bf2f(X16[p.x * 64 + lane]);
    au += v; aw += __int_as_float(p.y) * v;
  }
  outw[wid * 64 + lane] = aw;
  outu[wid * 64 + lane] = au;
}

__global__ __launch_bounds__(256)
void k_agg64b(const unsigned short* __restrict__ X16,
              const int* __restrict__ rowstart, const int* __restrict__ cnt,
              const int* __restrict__ srcs, float* __restrict__ out, int n) {
  int wid = blockIdx.x * 4 + (threadIdx.x >> 6);
  if (wid >= n) return;
  int lane = threadIdx.x & 63;
  int rs = rowstart[wid], c = cnt[wid];
  float a = 0.f;
  for (int j = 0; j < c; j++) {
    int s = srcs[rs + j];
    a += bf2f(X16[s * 64 + lane]);
  }
  out[wid * 64 + lane] = a;
}

__global__ __launch_bounds__(256)
void k_tag64b(const unsigned short* __restrict__ X16,
              const int* __restrict__ rowstart, const int* __restrict__ cnt,
              const int* __restrict__ srcs, const float* __restrict__ dinv,
              unsigned short* __restrict__ out16, int n) {
  int wid = blockIdx.x * 4 + (threadIdx.x >> 6);
  if (wid >= n) return;
  int lane = threadIdx.x & 63;
  int rs = rowstart[wid], c = cnt[wid];
  float a = 0.f;
  for (int j = 0; j < c; j++) {
    int s = srcs[rs + j];
    a += dinv[s] * bf2f(X16[s * 64 + lane]);
  }
  out16[wid * 64 + lane] = f2bf(dinv[wid] * a);
}

// ---------------- Fused node matmul ----------------
// out = [relu]( [out +] A'@WA + B@WB + bias ), A' = A/max(cnt,1); A/B f32 or bf16.

__global__ __launch_bounds__(256)
void k_node_mm(const void* __restrict__ Av, int a16f, const int* __restrict__ cntA,
               const float* __restrict__ WA,
               const void* __restrict__ Bv, int DB, int b16f,
               const float* __restrict__ WB,
               const float* __restrict__ bias,
               float* __restrict__ out, unsigned short* __restrict__ out16,
               int n, int dorelu, int accum) {
  __shared__ float WAs[64 * 64];
  __shared__ float WBs[64 * 64];
  __shared__ float bs[64];
  __shared__ float as[64 * 68];
  const int tid = threadIdx.x;
  {
    const float4* w4 = (const float4*)WA;
    float4* s4 = (float4*)WAs;
    for (int i = tid; i < 1024; i += 256) s4[i] = w4[i];
    if (Bv) {
      const float4* wb4 = (const float4*)WB;
      float4* sb4 = (float4*)WBs;
      int nb = DB * 16;
      for (int i = tid; i < nb; i += 256) sb4[i] = wb4[i];
    }
    if (tid < 64) bs[tid] = bias ? bias[tid] : 0.0f;
  }
  const int gb = blockIdx.x * 64;
  for (int i = tid; i < 1024; i += 256) {
    int nl = i >> 4, k4 = i & 15;
    int g = gb + nl;
    float4 v = make_float4(0.f, 0.f, 0.f, 0.f);
    if (g < n) {
      if (a16f) {
        uint2 u = ((const uint2*)((const unsigned short*)Av + (size_t)g * 64))[k4];
        v.x = bf2f((unsigned short)(u.x & 0xFFFF));
        v.y = bf2f((unsigned short)(u.x >> 16));
        v.z = bf2f((unsigned short)(u.y & 0xFFFF));
        v.w = bf2f((unsigned short)(u.y >> 16));
      } else {
        v = ((const float4*)Av)[g * 16 + k4];
      }
      if (cntA) {
        float sc = 1.0f / fmaxf((float)cntA[g], 1.0f);
        v.x *= sc; v.y *= sc; v.z *= sc; v.w *= sc;
      }
    }
    *(float4*)(&as[nl * 68 + k4 * 4]) = v;
  }
  __syncthreads();
  const int lane = tid & 63;
  const int fq = lane & 15, nq = lane >> 4;
  const int f0 = fq * 4;
  const int nl0 = (tid >> 6) * 16 + nq * 4;
  float acc[4][4];
#pragma unroll
  for (int j = 0; j < 4; j++)
#pragma unroll
    for (int jj = 0; jj < 4; jj++) acc[j][jj] = 0.f;
#pragma unroll 4
  for (int k = 0; k < 64; k++) {
    float4 w = *(const float4*)(&WAs[k * 64 + f0]);
#pragma unroll
    for (int j = 0; j < 4; j++) {
      float a = as[(nl0 + j) * 68 + k];
      acc[j][0] += a * w.x; acc[j][1] += a * w.y; acc[j][2] += a * w.z; acc[j][3] += a * w.w;
    }
  }
  if (Bv) {
    __syncthreads();
    if (DB == 64) {
      for (int i = tid; i < 1024; i += 256) {
        int nl = i >> 4, k4 = i & 15;
        int g = gb + nl;
        float4 v = make_float4(0.f, 0.f, 0.f, 0.f);
        if (g < n) {
          if (b16f) {
            uint2 u = ((const uint2*)((const unsigned short*)Bv + (size_t)g * 64))[k4];
            v.x = bf2f((unsigned short)(u.x & 0xFFFF));
            v.y = bf2f((unsigned short)(u.x >> 16));
            v.z = bf2f((unsigned short)(u.y & 0xFFFF));
            v.w = bf2f((unsigned short)(u.y >> 16));
          } else {
            v = ((const float4*)Bv)[g * 16 + k4];
          }
        }
        *(float4*)(&as[nl * 68 + k4 * 4]) = v;
      }
    } else {
      const float* Bf = (const float*)Bv;
      for (int i = tid; i < 64 * DB; i += 256) {
        int nl = i / DB, k = i - nl * DB;
        int g = gb + nl;
        as[nl * 68 + k] = (g < n) ? Bf[g * DB + k] : 0.f;
      }
    }
    __syncthreads();
    for (int k = 0; k < DB; k++) {
      float4 w = *(const float4*)(&WBs[k * 64 + f0]);
#pragma unroll
      for (int j = 0; j < 4; j++) {
        float a = as[(nl0 + j) * 68 + k];
        acc[j][0] += a * w.x; acc[j][1] += a * w.y; acc[j][2] += a * w.z; acc[j][3] += a * w.w;
      }
    }
  }
#pragma unroll
  for (int j = 0; j < 4; j++) {
    int g = gb + nl0 + j;
    if (g < n) {
#pragma unroll
      for (int jj = 0; jj < 4; jj++) {
        int f = f0 + jj;
        float v = acc[j][jj] + bs[f];
        if (accum) v += out[g * 64 + f];
        if (dorelu) v = fmaxf(v, 0.f);
        out[g * 64 + f] = v;
        if (out16) out16[g * 64 + f] = f2bf(v);
      }
    }
  }
}

// ---------------- Final projection ----------------

__global__ void k_final(const float* __restrict__ X, const float* __restrict__ Wl,
                        const float* __restrict__ bl, float* __restrict__ out) {
  __shared__ float Ws[64 * 8];
  __shared__ float bsh[8];
  int tid = threadIdx.x;
  for (int i = tid; i < 512; i += 256) Ws[i] = Wl[i];
  if (tid < 8) bsh[tid] = bl[tid];
  __syncthreads();
  int gid = blockIdx.x * 256 + tid;
  if (gid >= NSV * 8) return;
  int v = gid >> 3, f = gid & 7;
  float acc = bsh[f];
  const float* xr = X + v * 64;
#pragma unroll 8
  for (int k = 0; k < 64; k++) acc += xr[k] * Ws[k * 8 + f];
  out[gid] = acc;
}

// ---------------- Host ----------------

extern "C" void kernel_launch(void* const* d_in, const int* in_sizes, int n_in,
                              void* d_out, int out_size, void* d_ws, size_t ws_size,
                              hipStream_t stream) {
  const float* game_x  = (const float*)d_in[0];
  const float* state_x = (const float*)d_in[1];
  const int*   ei_vv   = (const int*)d_in[2];
  const int*   et_vv   = (const int*)d_in[3];
  const int*   ei_h    = (const int*)d_in[4];
  const float* ew_h    = (const float*)d_in[5];
  const int*   ei_in   = (const int*)d_in[6];
  const int*   ei_ss   = (const int*)d_in[7];
  const float* W1_rel  = (const float*)d_in[8];
  const float* W1_root = (const float*)d_in[9];
  const float* b1      = (const float*)d_in[10];
  const float* W12     = (const float*)d_in[11];
  const float* b12     = (const float*)d_in[12];
  const float* W2      = (const float*)d_in[13];
  const float* b2      = (const float*)d_in[14];
  const float* W3_rel  = (const float*)d_in[15];
  const float* W3_root = (const float*)d_in[16];
  const float* b3      = (const float*)d_in[17];
  const float* W32_l   = (const float*)d_in[18];
  const float* W32_r   = (const float*)d_in[19];
  const float* b32     = (const float*)d_in[20];
  const float* W4_l    = (const float*)d_in[21];
  const float* W4_r    = (const float*)d_in[22];
  const float* b4      = (const float*)d_in[23];
  const float* W42_l   = (const float*)d_in[24];
  const float* W42_r   = (const float*)d_in[25];
  const float* b42     = (const float*)d_in[26];
  const float* W5_l    = (const float*)d_in[27];
  const float* W5_r    = (const float*)d_in[28];
  const float* b5      = (const float*)d_in[29];
  const float* Wl      = (const float*)d_in[30];
  const float* bl      = (const float*)d_in[31];

  // Workspace (4B slots), 25.9M slots = 103.6 MiB.
  float* ws = (float*)d_ws;
  int*   cnt_all = (int*)(ws + 0);              // 250K (vv|h|in|ss)
  int*   rs_all  = (int*)(ws + 250000);         // 250K (graph-local values)
  int*   bcnt    = (int*)(ws + 500000);         // 512
  int*   bbase   = (int*)(ws + 500512);         // 512
  int*   cb      = (int*)(ws + 501024);         // 512
  int*   srcs_ss = (int*)(ws + 760000);         // 0.8M  (lives through phase E)
  float4* x_pad  = (float4*)(ws + 1600000);     // 800K
  float4* h1p    = (float4*)(ws + 2400000);
  float4* h2p    = (float4*)(ws + 3200000);
  float4* h3p    = (float4*)(ws + 4000000);
  float* relall  = ws + 4800000;                // 1.8M -> ends 6.6M
  float* dinvS   = ws + 6600000;                // 50K
  unsigned short* gx16 = (unsigned short*)(ws + 6700000);  // [NVV][64] bf16 = 3.2M slots -> 9.9M
  unsigned* temp_vv    = (unsigned*)(ws + 6700000);        // 1.6M, overlays gx16 front (dead before combine)
  float* aggHw = ws + 9900000;                  // 3.2M
  float* aggHu = ws + 13100000;                 // 3.2M
  float* aggIN = ws + 16300000;                 // 3.2M
  float* S1    = ws + 19500000;                 // 3.2M
  float* S2    = ws + 22700000;                 // 3.2M -> ends 25.9M
  // fill temps overlay agg regions (dead until phase B):
  uint2*    temp_h  = (uint2*)aggHw;                         // [9.9M,11.5M)
  unsigned* temp_in = (unsigned*)(aggHw + 1600000);          // [11.5M,12.3M)
  unsigned* temp_ss = (unsigned*)(aggHw + 2400000);          // [12.3M,13.1M)
  // other overlays (aliases verified dead-before-write):
  unsigned short* S2b = (unsigned short*)aggHw;              // C4 shadow; aggHw dead after MM-C1
  float*          aggSS = aggHw + 1600000;                   // phase E; S2b/t1b dead by then
  unsigned short* t1b = (unsigned short*)aggHu;              // aggHu dead after MM-C2
  unsigned short* t2b = (unsigned short*)(aggHu + 1600000);
  unsigned short* t3b = (unsigned short*)aggIN;              // aggIN dead after MM-C4
  unsigned short* S1b = (unsigned short*)(aggIN + 1600000);  // D2 shadow
  unsigned* payload_vv = (unsigned*)S1;                      // dead before MM-C1 writes S1
  int2*     eh         = (int2*)S2;                          // dead before MM-C2 writes S2
  int*      srcs_in    = (int*)(S2 + 1600000);

  const int* src_vv = ei_vv;  const int* dst_vv = ei_vv + E_VV;
  const int* src_h  = ei_h;   const int* dst_h  = ei_h + E_H;
  const int* src_in = ei_in;  const int* dst_in = ei_in + E_IN;
  const int* src_ss = ei_ss;  const int* dst_ss = ei_ss + E_SS;

  auto nblk = [](long long n) { return dim3((unsigned)((n + 255) / 256)); };
  const int NB64 = (NSV + 3) / 4;
  const int NB   = (NSV + 63) / 64;
  const int G1VV = (E_VV + T1 - 1) / T1;    // 391
  const int G1S  = (E_H + T1 - 1) / T1;     // 196
  const int GC   = (ETOT + TC - 1) / TC;    // 245

  int* cnt_h  = cnt_all + H_ROW;
  int* cnt_in = cnt_all + IN_ROW;
  int* cnt_ss = cnt_all + SS_ROW;
  int* rs_vv  = rs_all;
  int* rs_h   = rs_all + H_ROW;
  int* rs_in  = rs_all + IN_ROW;
  int* rs_ss  = rs_all + SS_ROW;

  // ---- CSR build: bucket count -> bucket scan -> two-stage binned fills (no per-dst atomics) ----
  hipMemsetAsync(bcnt, 0, NBTOT * sizeof(int), stream);
  k_bucket_count<<<GC, 256, 0, stream>>>(dst_vv, dst_h, dst_in, dst_ss, bcnt);
  k_bucket_scan<<<1, 512, 0, stream>>>(bcnt, bbase, cb);
  k_fill_vv_s1<<<G1VV, 256, 0, stream>>>(src_vv, dst_vv, et_vv, cb, temp_vv);
  k_fill_h_s1<<<G1S, 256, 0, stream>>>(src_h, dst_h, ew_h, cb + BUK_H, temp_h);
  k_fill_s1<<<G1S, 256, 0, stream>>>(src_in, dst_in, E_IN, cb + BUK_IN, temp_in);
  k_fill_s1<<<G1S, 256, 0, stream>>>(src_ss, dst_ss, E_SS, cb + BUK_SS, temp_ss);
  k_fill_vv_s2<<<NBUK, 256, 0, stream>>>(temp_vv, bbase, payload_vv, rs_vv, cnt_all);
  k_fill_h_s2<<<NBUKS, 256, 0, stream>>>(temp_h, bbase, eh, rs_h, cnt_h);
  k_fill_s2<<<NBUKS, 256, 0, stream>>>(temp_in, bbase, BUK_IN, E_IN, srcs_in, rs_in, cnt_in);
  k_fill_s2<<<NBUKS, 256, 0, stream>>>(temp_ss, bbase, BUK_SS, E_SS, srcs_ss, rs_ss, cnt_ss);
  k_prep_x<<<nblk(NVV), 256, 0, stream>>>(game_x, cnt_all, x_pad);
  k_rsqrt_deg<<<nblk(NSV), 256, 0, stream>>>(cnt_ss, dinvS, NSV);

  // ---- Phase A: v-graph 5-dim ----
  k_vv_pass1<<<nblk(NVV), 256, 0, stream>>>(x_pad, rs_vv, cnt_all, payload_vv, relall, h1p);
  k_vv_hop<<<nblk(NVV), 256, 0, stream>>>(h1p, rs_vv, cnt_all, payload_vv, h2p);
  k_vv_hop<<<nblk(NVV), 256, 0, stream>>>(h2p, rs_vv, cnt_all, payload_vv, h3p);
  k_combine_gx<<<dim3((NVV + 3) / 4), 256, 0, stream>>>(x_pad, relall, h1p, h2p, h3p,
                                                        W1_rel, W1_root, b1, W12, b12, gx16);

  // ---- Phase B: 64-dim bf16 gathers ----
  k_agg_h64<<<NB64, 256, 0, stream>>>(gx16, rs_h, cnt_h, eh, aggHw, aggHu);
  k_agg64b<<<NB64, 256, 0, stream>>>(gx16, rs_in, cnt_in, srcs_in, aggIN, NSV);

  // ---- Phase C: graph_conv + 3x SAGE ----
  k_node_mm<<<NB, 256, 0, stream>>>(aggHw, 0, nullptr, W3_rel, state_x, 5, 0, W3_root, b3, S1, nullptr, NSV, 1, 0);
  k_node_mm<<<NB, 256, 0, stream>>>(aggHu, 0, cnt_h,   W32_l, S1, 64, 0, W32_r, b32, S2, nullptr, NSV, 1, 0);
  k_node_mm<<<NB, 256, 0, stream>>>(aggIN, 0, cnt_in,  W4_l,  S2, 64, 0, W4_r,  b4,  S1, nullptr, NSV, 1, 0);
  k_node_mm<<<NB, 256, 0, stream>>>(aggIN, 0, cnt_in,  W42_l, S1, 64, 0, W42_r, b42, S2, S2b,     NSV, 1, 0);

  // ---- Phase D: TAG on s-s (bf16 hops) ----
  k_tag64b<<<NB64, 256, 0, stream>>>(S2b, rs_ss, cnt_ss, srcs_ss, dinvS, t1b, NSV);
  k_tag64b<<<NB64, 256, 0, stream>>>(t1b, rs_ss, cnt_ss, srcs_ss, dinvS, t2b, NSV);
  k_tag64b<<<NB64, 256, 0, stream>>>(t2b, rs_ss, cnt_ss, srcs_ss, dinvS, t3b, NSV);
  k_node_mm<<<NB, 256, 0, stream>>>(S2, 0, nullptr, W2,        t1b, 64, 1, W2 + 4096,  b2,      S1, nullptr, NSV, 0, 0);
  k_node_mm<<<NB, 256, 0, stream>>>(t2b, 1, nullptr, W2 + 8192, t3b, 64, 1, W2 + 12288, nullptr, S1, S1b,    NSV, 1, 1);

  // ---- Phase E: SAGE on s-s ----
  k_agg64b<<<NB64, 256, 0, stream>>>(S1b, rs_ss, cnt_ss, srcs_ss, aggSS, NSV);
  k_node_mm<<<NB, 256, 0, stream>>>(aggSS, 0, cnt_ss, W5_l, S1, 64, 0, W5_r, b5, S2, nullptr, NSV, 1, 0);

  // ---- Final projection ----
  k_final<<<nblk(NSV * 8), 256, 0, stream>>>(S2, Wl, bl, (float*)d_out);
}

// Round 8
// 830.113 us; speedup vs baseline: 4.1042x; 1.3015x over previous
//
#include <hip/hip_runtime.h>

#define NVV 100000
#define NSV 50000
#define E_VV 1600000
#define E_H  800000
#define E_IN 800000
#define E_SS 800000
#define ETOT 4000000
#define DIN 5
#define H_ROW 100000          // concatenated cnt/rs space: vv|h|in|ss
#define IN_ROW 150000
#define SS_ROW 200000
#define NROWS 250000
#define POS_H  E_VV
#define POS_IN (E_VV + E_H)
#define POS_SS (E_VV + E_H + E_IN)
#define NBUK 196              // vv buckets (dst >> 9)
#define NBUKS 98              // NSV-graph buckets
#define NBTOT 490             // vv|h|in|ss bucket space
#define BUK_H  196
#define BUK_IN 294
#define BUK_SS 392
#define BSHIFT 9
#define T1 4096               // edges per fill-stage-1 block
#define TC 16384              // edges per bucket-count block

__device__ __forceinline__ unsigned short f2bf(float x) {
  unsigned b = __float_as_uint(x);
  return (unsigned short)((b + 0x7FFFu + ((b >> 16) & 1u)) >> 16);
}
__device__ __forceinline__ float bf2f(unsigned short u) {
  return __uint_as_float(((unsigned)u) << 16);
}

// ====================== CSR build: bucket counts -> bases -> binned fills ======================

__global__ __launch_bounds__(256)
void k_bucket_count(const int* __restrict__ d_vv, const int* __restrict__ d_h,
                    const int* __restrict__ d_in, const int* __restrict__ d_ss,
                    int* __restrict__ bcnt) {
  __shared__ int h[NBTOT];
  const int tid = threadIdx.x;
  for (int i = tid; i < NBTOT; i += 256) h[i] = 0;
  __syncthreads();
  const int base = blockIdx.x * TC;
#pragma unroll 4
  for (int k = 0; k < TC / 256; k++) {
    int e = base + k * 256 + tid;
    int bi = -1;
    if (e < E_VV) bi = d_vv[e] >> BSHIFT;
    else if (e < POS_IN) bi = BUK_H + (d_h[e - POS_H] >> BSHIFT);
    else if (e < POS_SS) bi = BUK_IN + (d_in[e - POS_IN] >> BSHIFT);
    else if (e < ETOT) bi = BUK_SS + (d_ss[e - POS_SS] >> BSHIFT);
    if (bi >= 0) atomicAdd(&h[bi], 1);
  }
  __syncthreads();
  for (int i = tid; i < NBTOT; i += 256) if (h[i]) atomicAdd(&bcnt[i], h[i]);
}

// segmented exclusive scan of 490 bucket counts -> graph-local bucket bases + s1 cursors
__global__ __launch_bounds__(512)
void k_bucket_scan(const int* __restrict__ bcnt, int* __restrict__ bbase, int* __restrict__ cb) {
  __shared__ int sd[512];
  int t = threadIdx.x;
  int v = (t < NBTOT) ? bcnt[t] : 0;
  sd[t] = v; __syncthreads();
  for (int off = 1; off < 512; off <<= 1) {
    int x = (t >= off) ? sd[t - off] : 0;
    __syncthreads();
    sd[t] += x;
    __syncthreads();
  }
  int segstart = (t < BUK_H) ? 0 : (t < BUK_IN) ? BUK_H : (t < BUK_SS) ? BUK_IN : BUK_SS;
  int excl = ((t > 0) ? sd[t - 1] : 0) - ((segstart > 0) ? sd[segstart - 1] : 0);
  if (t < NBTOT) { bbase[t] = excl; cb[t] = excl; }
}

// ---- stage 1: bucket-grouped binning, coalesced run writes ----
// vv entry: [dstloc:9][et:2][src:17]
__global__ __launch_bounds__(256)
void k_fill_vv_s1(const int* __restrict__ src, const int* __restrict__ dst,
                  const int* __restrict__ et,
                  int* __restrict__ cur_b, unsigned* __restrict__ temp) {
  __shared__ int hist[NBUK], lbase[NBUK], run[NBUK], gb[NBUK];
  __shared__ int sc[256];
  __shared__ unsigned stage[T1];
  __shared__ int gpos[T1];
  const int tid = threadIdx.x;
  const int base = blockIdx.x * T1;
  const int nvalid = min(T1, E_VV - base);
  for (int i = tid; i < NBUK; i += 256) { hist[i] = 0; run[i] = 0; }
  __syncthreads();
  int dv[16]; unsigned pk[16];
#pragma unroll
  for (int k = 0; k < 16; k++) {
    int e = base + k * 256 + tid;
    if (e < E_VV) {
      int d = dst[e];
      dv[k] = d;
      pk[k] = (unsigned)(((d & 511) << 19) | (et[e] << 17) | src[e]);
      atomicAdd(&hist[d >> BSHIFT], 1);
    } else dv[k] = -1;
  }
  __syncthreads();
  int my = (tid < NBUK) ? hist[tid] : 0;
  sc[tid] = my; __syncthreads();
  for (int off = 1; off < 256; off <<= 1) {
    int t = (tid >= off) ? sc[tid - off] : 0;
    __syncthreads();
    sc[tid] += t;
    __syncthreads();
  }
  if (tid < NBUK) {
    lbase[tid] = sc[tid] - my;
    gb[tid] = my ? atomicAdd(&cur_b[tid], my) : 0;
  }
  __syncthreads();
#pragma unroll
  for (int k = 0; k < 16; k++) {
    if (dv[k] >= 0) {
      int b = dv[k] >> BSHIFT;
      int loc = atomicAdd(&run[b], 1);
      int li = lbase[b] + loc;
      stage[li] = pk[k];
      gpos[li] = gb[b] + loc;
    }
  }
  __syncthreads();
  for (int i = tid; i < nvalid; i += 256) temp[gpos[i]] = stage[i];
}

// generic NSV-graph entry: [dstloc:9][src:17]
__global__ __launch_bounds__(256)
void k_fill_s1(const int* __restrict__ src, const int* __restrict__ dst, int ne,
               int* __restrict__ cur_b, unsigned* __restrict__ temp) {
  __shared__ int hist[NBUKS], lbase[NBUKS], run[NBUKS], gb[NBUKS];
  __shared__ int sc[256];
  __shared__ unsigned stage[T1];
  __shared__ int gpos[T1];
  const int tid = threadIdx.x;
  const int base = blockIdx.x * T1;
  const int nvalid = min(T1, ne - base);
  for (int i = tid; i < NBUKS; i += 256) { hist[i] = 0; run[i] = 0; }
  __syncthreads();
  int dv[16]; unsigned pk[16];
#pragma unroll
  for (int k = 0; k < 16; k++) {
    int e = base + k * 256 + tid;
    if (e < ne) {
      int d = dst[e];
      dv[k] = d;
      pk[k] = (unsigned)(((d & 511) << 17) | src[e]);
      atomicAdd(&hist[d >> BSHIFT], 1);
    } else dv[k] = -1;
  }
  __syncthreads();
  int my = (tid < NBUKS) ? hist[tid] : 0;
  sc[tid] = my; __syncthreads();
  for (int off = 1; off < 256; off <<= 1) {
    int t = (tid >= off) ? sc[tid - off] : 0;
    __syncthreads();
    sc[tid] += t;
    __syncthreads();
  }
  if (tid < NBUKS) {
    lbase[tid] = sc[tid] - my;
    gb[tid] = my ? atomicAdd(&cur_b[tid], my) : 0;
  }
  __syncthreads();
#pragma unroll
  for (int k = 0; k < 16; k++) {
    if (dv[k] >= 0) {
      int b = dv[k] >> BSHIFT;
      int loc = atomicAdd(&run[b], 1);
      int li = lbase[b] + loc;
      stage[li] = pk[k];
      gpos[li] = gb[b] + loc;
    }
  }
  __syncthreads();
  for (int i = tid; i < nvalid; i += 256) temp[gpos[i]] = stage[i];
}

// h-graph: uint2 {[dstloc:9][src:17], weight bits}
__global__ __launch_bounds__(256)
void k_fill_h_s1(const int* __restrict__ src, const int* __restrict__ dst,
                 const float* __restrict__ ew,
                 int* __restrict__ cur_b, uint2* __restrict__ temp) {
  __shared__ int hist[NBUKS], lbase[NBUKS], run[NBUKS], gb[NBUKS];
  __shared__ int sc[256];
  __shared__ uint2 stage[T1];
  __shared__ int gpos[T1];
  const int tid = threadIdx.x;
  const int base = blockIdx.x * T1;
  const int nvalid = min(T1, E_H - base);
  for (int i = tid; i < NBUKS; i += 256) { hist[i] = 0; run[i] = 0; }
  __syncthreads();
  int dv[16]; uint2 pk[16];
#pragma unroll
  for (int k = 0; k < 16; k++) {
    int e = base + k * 256 + tid;
    if (e < E_H) {
      int d = dst[e];
      dv[k] = d;
      pk[k] = make_uint2((unsigned)(((d & 511) << 17) | src[e]), (unsigned)__float_as_int(ew[e]));
      atomicAdd(&hist[d >> BSHIFT], 1);
    } else dv[k] = -1;
  }
  __syncthreads();
  int my = (tid < NBUKS) ? hist[tid] : 0;
  sc[tid] = my; __syncthreads();
  for (int off = 1; off < 256; off <<= 1) {
    int t = (tid >= off) ? sc[tid - off] : 0;
    __syncthreads();
    sc[tid] += t;
    __syncthreads();
  }
  if (tid < NBUKS) {
    lbase[tid] = sc[tid] - my;
    gb[tid] = my ? atomicAdd(&cur_b[tid], my) : 0;
  }
  __syncthreads();
#pragma unroll
  for (int k = 0; k < 16; k++) {
    if (dv[k] >= 0) {
      int b = dv[k] >> BSHIFT;
      int loc = atomicAdd(&run[b], 1);
      int li = lbase[b] + loc;
      stage[li] = pk[k];
      gpos[li] = gb[b] + loc;
    }
  }
  __syncthreads();
  for (int i = tid; i < nvalid; i += 256) temp[gpos[i]] = stage[i];
}

// ---- stage 2: per-bucket LDS count + scan -> cnt/rs coalesced; then in-window scatter ----

__global__ __launch_bounds__(256)
void k_fill_vv_s2(const unsigned* __restrict__ temp, const int* __restrict__ bbase,
                  unsigned* __restrict__ payload, int* __restrict__ rs, int* __restrict__ cnt) {
  __shared__ int lcnt[512], lpos[512];
  __shared__ int sc[256];
  const int b = blockIdx.x, tid = threadIdx.x;
  const int d0 = b << BSHIFT;
  lcnt[tid] = 0; lcnt[tid + 256] = 0;
  __syncthreads();
  const int gstart = bbase[b];
  const int gend = (b == NBUK - 1) ? E_VV : bbase[b + 1];
  for (int i = gstart + tid; i < gend; i += 256) atomicAdd(&lcnt[temp[i] >> 19], 1);
  __syncthreads();
  int c0 = lcnt[2 * tid], c1 = lcnt[2 * tid + 1];
  int ps = c0 + c1;
  sc[tid] = ps; __syncthreads();
  for (int off = 1; off < 256; off <<= 1) {
    int x = (tid >= off) ? sc[tid - off] : 0;
    __syncthreads();
    sc[tid] += x;
    __syncthreads();
  }
  int basep = gstart + sc[tid] - ps;
  lpos[2 * tid] = basep;
  lpos[2 * tid + 1] = basep + c0;
  __syncthreads();
  for (int d = tid; d < 512; d += 256) {
    int gd = d0 + d;
    if (gd < NVV) { rs[gd] = lpos[d]; cnt[gd] = lcnt[d]; }
  }
  __syncthreads();
  for (int i = gstart + tid; i < gend; i += 256) {
    unsigned en = temp[i];
    int pos = atomicAdd(&lpos[en >> 19], 1);
    payload[pos] = en & 0x7FFFFu;   // [et:2][src:17]
  }
}

__global__ __launch_bounds__(256)
void k_fill_s2(const unsigned* __restrict__ temp, const int* __restrict__ bbase, int buk0,
               int nloc, int* __restrict__ payload, int* __restrict__ rs, int* __restrict__ cnt) {
  __shared__ int lcnt[512], lpos[512];
  __shared__ int sc[256];
  const int b = blockIdx.x, tid = threadIdx.x;
  const int d0 = b << BSHIFT;
  lcnt[tid] = 0; lcnt[tid + 256] = 0;
  __syncthreads();
  const int gstart = bbase[buk0 + b];
  const int gend = (b == NBUKS - 1) ? nloc : bbase[buk0 + b + 1];
  for (int i = gstart + tid; i < gend; i += 256) atomicAdd(&lcnt[temp[i] >> 17], 1);
  __syncthreads();
  int c0 = lcnt[2 * tid], c1 = lcnt[2 * tid + 1];
  int ps = c0 + c1;
  sc[tid] = ps; __syncthreads();
  for (int off = 1; off < 256; off <<= 1) {
    int x = (tid >= off) ? sc[tid - off] : 0;
    __syncthreads();
    sc[tid] += x;
    __syncthreads();
  }
  int basep = gstart + sc[tid] - ps;
  lpos[2 * tid] = basep;
  lpos[2 * tid + 1] = basep + c0;
  __syncthreads();
  for (int d = tid; d < 512; d += 256) {
    int gd = d0 + d;
    if (gd < NSV) { rs[gd] = lpos[d]; cnt[gd] = lcnt[d]; }
  }
  __syncthreads();
  for (int i = gstart + tid; i < gend; i += 256) {
    unsigned en = temp[i];
    int pos = atomicAdd(&lpos[en >> 17], 1);
    payload[pos] = (int)(en & 0x1FFFFu);
  }
}

__global__ __launch_bounds__(256)
void k_fill_h_s2(const uint2* __restrict__ temp, const int* __restrict__ bbase,
                 int2* __restrict__ eh, int* __restrict__ rs, int* __restrict__ cnt) {
  __shared__ int lcnt[512], lpos[512];
  __shared__ int sc[256];
  const int b = blockIdx.x, tid = threadIdx.x;
  const int d0 = b << BSHIFT;
  lcnt[tid] = 0; lcnt[tid + 256] = 0;
  __syncthreads();
  const int gstart = bbase[BUK_H + b];
  const int gend = (b == NBUKS - 1) ? E_H : bbase[BUK_H + b + 1];
  for (int i = gstart + tid; i < gend; i += 256) atomicAdd(&lcnt[temp[i].x >> 17], 1);
  __syncthreads();
  int c0 = lcnt[2 * tid], c1 = lcnt[2 * tid + 1];
  int ps = c0 + c1;
  sc[tid] = ps; __syncthreads();
  for (int off = 1; off < 256; off <<= 1) {
    int x = (tid >= off) ? sc[tid - off] : 0;
    __syncthreads();
    sc[tid] += x;
    __syncthreads();
  }
  int basep = gstart + sc[tid] - ps;
  lpos[2 * tid] = basep;
  lpos[2 * tid + 1] = basep + c0;
  __syncthreads();
  for (int d = tid; d < 512; d += 256) {
    int gd = d0 + d;
    if (gd < NSV) { rs[gd] = lpos[d]; cnt[gd] = lcnt[d]; }
  }
  __syncthreads();
  for (int i = gstart + tid; i < gend; i += 256) {
    uint2 en = temp[i];
    int pos = atomicAdd(&lpos[en.x >> 17], 1);
    eh[pos] = make_int2((int)(en.x & 0x1FFFFu), (int)en.y);
  }
}

__global__ void k_rsqrt_deg(const int* __restrict__ deg, float* __restrict__ dinv, int n) {
  int i = blockIdx.x * 256 + threadIdx.x;
  if (i >= n) return;
  float d = (float)deg[i];
  dinv[i] = d > 0.f ? rsqrtf(d) : 0.f;
}

// ====================== Phase A: v-graph (5-dim, padded rows) ======================

__global__ void k_prep_x(const float* __restrict__ x, const int* __restrict__ cnt,
                         float4* __restrict__ xp) {
  int v = blockIdx.x * 256 + threadIdx.x;
  if (v >= NVV) return;
  float d = (float)cnt[v];
  float di = d > 0.f ? rsqrtf(d) : 0.f;
  const float* xr = x + v * 5;
  xp[v * 2]     = make_float4(xr[0], xr[1], xr[2], xr[3]);
  xp[v * 2 + 1] = make_float4(xr[4], di, 0.f, 0.f);
}

// 2-way unrolled gather: RGCN rel-sums + TAG hop-1
__global__ __launch_bounds__(256)
void k_vv_pass1(const float4* __restrict__ xp,
                const int* __restrict__ rowstart, const int* __restrict__ cnt,
                const unsigned* __restrict__ payload,
                float* __restrict__ relall, float4* __restrict__ h1p) {
  int d = blockIdx.x * 256 + threadIdx.x;
  if (d >= NVV) return;
  int rs = rowstart[d], c = cnt[d];
  float a0[5] = {0,0,0,0,0}, a1[5] = {0,0,0,0,0}, a2[5] = {0,0,0,0,0}, h[5] = {0,0,0,0,0};
  float c0 = 0.f, c1 = 0.f, c2 = 0.f;
  int j = 0;
  for (; j + 2 <= c; j += 2) {
    unsigned pA = payload[rs + j], pB = payload[rs + j + 1];
    int sA = pA & 0x1FFFF, rA = pA >> 17;
    int sB = pB & 0x1FFFF, rB = pB >> 17;
    float4 xA0 = xp[sA * 2], xA1 = xp[sA * 2 + 1];
    float4 xB0 = xp[sB * 2], xB1 = xp[sB * 2 + 1];
    float xsA[5] = {xA0.x, xA0.y, xA0.z, xA0.w, xA1.x};
    float xsB[5] = {xB0.x, xB0.y, xB0.z, xB0.w, xB1.x};
    float wA = xA1.y, wB = xB1.y;
    float mA0 = (rA == 0) ? 1.f : 0.f, mA1 = (rA == 1) ? 1.f : 0.f, mA2 = (rA == 2) ? 1.f : 0.f;
    float mB0 = (rB == 0) ? 1.f : 0.f, mB1 = (rB == 1) ? 1.f : 0.f, mB2 = (rB == 2) ? 1.f : 0.f;
    c0 += mA0 + mB0; c1 += mA1 + mB1; c2 += mA2 + mB2;
#pragma unroll
    for (int k = 0; k < 5; k++) {
      h[k] += wA * xsA[k] + wB * xsB[k];
      a0[k] += mA0 * xsA[k] + mB0 * xsB[k];
      a1[k] += mA1 * xsA[k] + mB1 * xsB[k];
      a2[k] += mA2 * xsA[k] + mB2 * xsB[k];
    }
  }
  for (; j < c; j++) {
    unsigned p = payload[rs + j];
    int s = p & 0x1FFFF, r = p >> 17;
    float4 x0 = xp[s * 2], x1 = xp[s * 2 + 1];
    float xs[5] = {x0.x, x0.y, x0.z, x0.w, x1.x};
    float wsc = x1.y;
    float m0 = (r == 0) ? 1.f : 0.f, m1 = (r == 1) ? 1.f : 0.f, m2 = (r == 2) ? 1.f : 0.f;
    c0 += m0; c1 += m1; c2 += m2;
#pragma unroll
    for (int k = 0; k < 5; k++) {
      h[k] += wsc * xs[k];
      a0[k] += m0 * xs[k]; a1[k] += m1 * xs[k]; a2[k] += m2 * xs[k];
    }
  }
  float dv = xp[d * 2 + 1].y;
  float* ra = relall + d * 18;
#pragma unroll
  for (int k = 0; k < 5; k++) { ra[k] = a0[k]; ra[5 + k] = a1[k]; ra[10 + k] = a2[k]; }
  ra[15] = c0; ra[16] = c1; ra[17] = c2;
  h1p[d * 2]     = make_float4(dv * h[0], dv * h[1], dv * h[2], dv * h[3]);
  h1p[d * 2 + 1] = make_float4(dv * h[4], dv, 0.f, 0.f);
}

// 4-way unrolled sym-norm 5-dim hop
__global__ __launch_bounds__(256)
void k_vv_hop(const float4* __restrict__ hinp,
              const int* __restrict__ rowstart, const int* __restrict__ cnt,
              const unsigned* __restrict__ payload, float4* __restrict__ houtp) {
  int d = blockIdx.x * 256 + threadIdx.x;
  if (d >= NVV) return;
  int rs = rowstart[d], c = cnt[d];
  float h[5] = {0,0,0,0,0};
  int j = 0;
  for (; j + 4 <= c; j += 4) {
    unsigned p0 = payload[rs + j], p1 = payload[rs + j + 1];
    unsigned p2 = payload[rs + j + 2], p3 = payload[rs + j + 3];
    int s0 = p0 & 0x1FFFF, s1 = p1 & 0x1FFFF, s2 = p2 & 0x1FFFF, s3 = p3 & 0x1FFFF;
    float4 a0 = hinp[s0 * 2], b0 = hinp[s0 * 2 + 1];
    float4 a1 = hinp[s1 * 2], b1 = hinp[s1 * 2 + 1];
    float4 a2 = hinp[s2 * 2], b2 = hinp[s2 * 2 + 1];
    float4 a3 = hinp[s3 * 2], b3 = hinp[s3 * 2 + 1];
    float w0 = b0.y, w1 = b1.y, w2 = b2.y, w3 = b3.y;
    h[0] += w0 * a0.x + w1 * a1.x + w2 * a2.x + w3 * a3.x;
    h[1] += w0 * a0.y + w1 * a1.y + w2 * a2.y + w3 * a3.y;
    h[2] += w0 * a0.z + w1 * a1.z + w2 * a2.z + w3 * a3.z;
    h[3] += w0 * a0.w + w1 * a1.w + w2 * a2.w + w3 * a3.w;
    h[4] += w0 * b0.x + w1 * b1.x + w2 * b2.x + w3 * b3.x;
  }
  for (; j < c; j++) {
    int s = payload[rs + j] & 0x1FFFF;
    float4 x0 = hinp[s * 2], x1 = hinp[s * 2 + 1];
    float wsc = x1.y;
    h[0] += wsc * x0.x; h[1] += wsc * x0.y; h[2] += wsc * x0.z; h[3] += wsc * x0.w;
    h[4] += wsc * x1.x;
  }
  float dv = hinp[d * 2 + 1].y;
  houtp[d * 2]     = make_float4(dv * h[0], dv * h[1], dv * h[2], dv * h[3]);
  houtp[d * 2 + 1] = make_float4(dv * h[4], dv, 0.f, 0.f);
}

__global__ __launch_bounds__(256)
void k_combine_gx(const float4* __restrict__ xp,
                  const float* __restrict__ relall,
                  const float4* __restrict__ h1p, const float4* __restrict__ h2p,
                  const float4* __restrict__ h3p,
                  const float* __restrict__ W1_rel, const float* __restrict__ W1_root,
                  const float* __restrict__ b1,
                  const float* __restrict__ W12, const float* __restrict__ b12,
                  unsigned short* __restrict__ gx16) {
  __shared__ float Ws[7 * 320];
  __shared__ float bs[64];
  int tid = threadIdx.x;
  for (int i = tid; i < 320; i += 256) {
    Ws[i]        = W1_root[i] + W12[i];
    Ws[320 + i]  = W1_rel[i];
    Ws[640 + i]  = W1_rel[320 + i];
    Ws[960 + i]  = W1_rel[640 + i];
    Ws[1280 + i] = W12[320 + i];
    Ws[1600 + i] = W12[640 + i];
    Ws[1920 + i] = W12[960 + i];
  }
  if (tid < 64) bs[tid] = b1[tid] + b12[tid];
  __syncthreads();
  int v = blockIdx.x * 4 + (tid >> 6);
  if (v >= NVV) return;
  int f = tid & 63;
  float in[35];
  {
    float4 x0 = xp[v * 2], x1 = xp[v * 2 + 1];
    in[0] = x0.x; in[1] = x0.y; in[2] = x0.z; in[3] = x0.w; in[4] = x1.x;
  }
  const float* ra = relall + v * 18;
#pragma unroll
  for (int r = 0; r < 3; r++) {
    float inv = 1.0f / fmaxf(ra[15 + r], 1.0f);
#pragma unroll
    for (int j = 0; j < DIN; j++) in[5 + r * 5 + j] = ra[r * 5 + j] * inv;
  }
  {
    float4 a = h1p[v * 2], b = h1p[v * 2 + 1];
    in[20] = a.x; in[21] = a.y; in[22] = a.z; in[23] = a.w; in[24] = b.x;
    a = h2p[v * 2]; b = h2p[v * 2 + 1];
    in[25] = a.x; in[26] = a.y; in[27] = a.z; in[28] = a.w; in[29] = b.x;
    a = h3p[v * 2]; b = h3p[v * 2 + 1];
    in[30] = a.x; in[31] = a.y; in[32] = a.z; in[33] = a.w; in[34] = b.x;
  }
  float acc = bs[f];
#pragma unroll
  for (int t = 0; t < 35; t++) acc += in[t] * Ws[t * 64 + f];
  gx16[v * 64 + f] = f2bf(acc);
}

// ================= 64-dim CSR gathers (wave per dst, lane=feature, 4-way MLP) =================

__global__ __launch_bounds__(256)
void k_agg_h64(const unsigned short* __restrict__ X16,
               const int* __restrict__ rowstart, const int* __restrict__ cnt,
               const int2* __restrict__ eh,
               float* __restrict__ outw, float* __restrict__ outu) {
  int wid = blockIdx.x * 4 + (threadIdx.x >> 6);
  if (wid >= NSV) return;
  int lane = threadIdx.x & 63;
  int rs = rowstart[wid], c = cnt[wid];
  float aw = 0.f, au = 0.f;
  int j = 0;
  for (; j + 4 <= c; j += 4) {
    int2 p0 = eh[rs + j], p1 = eh[rs + j + 1], p2 = eh[rs + j + 2], p3 = eh[rs + j + 3];
    float v0 = bf2f(X16[p0.x * 64 + lane]);
    float v1 = bf2f(X16[p1.x * 64 + lane]);
    float v2 = bf2f(X16[p2.x * 64 + lane]);
    float v3 = bf2f(X16[p3.x * 64 + lane]);
    au += (v0 + v1) + (v2 + v3);
    aw += __int_as_float(p0.y) * v0 + __int_as_float(p1.y) * v1
        + __int_as_float(p2.y) * v2 + __int_as_float(p3.y) * v3;
  }
  for (; j < c; j++) {
    int2 p = eh[rs + j];
    float v = bf2f(X16[p.x * 64 + lane]);
    au += v; aw += __int_as_float(p.y) * v;
  }
  outw[wid * 64 + lane] = aw;
  outu[wid * 64 + lane] = au;
}

__global__ __launch_bounds__(256)
void k_agg64b(const unsigned short* __restrict__ X16,
              const int* __restrict__ rowstart, const int* __restrict__ cnt,
              const int* __restrict__ srcs, float* __restrict__ out, int n) {
  int wid = blockIdx.x * 4 + (threadIdx.x >> 6);
  if (wid >= n) return;
  int lane = threadIdx.x & 63;
  int rs = rowstart[wid], c = cnt[wid];
  float a = 0.f;
  int j = 0;
  for (; j + 4 <= c; j += 4) {
    int s0 = srcs[rs + j], s1 = srcs[rs + j + 1], s2 = srcs[rs + j + 2], s3 = srcs[rs + j + 3];
    float v0 = bf2f(X16[s0 * 64 + lane]);
    float v1 = bf2f(X16[s1 * 64 + lane]);
    float v2 = bf2f(X16[s2 * 64 + lane]);
    float v3 = bf2f(X16[s3 * 64 + lane]);
    a += (v0 + v1) + (v2 + v3);
  }
  for (; j < c; j++) a += bf2f(X16[srcs[rs + j] * 64 + lane]);
  out[wid * 64 + lane] = a;
}

__global__ __launch_bounds__(256)
void k_tag64b(const unsigned short* __restrict__ X16,
              const int* __restrict__ rowstart, const int* __restrict__ cnt,
              const int* __restrict__ srcs, const float* __restrict__ dinv,
              unsigned short* __restrict__ out16, int n) {
  int wid = blockIdx.x * 4 + (threadIdx.x >> 6);
  if (wid >= n) return;
  int lane = threadIdx.x & 63;
  int rs = rowstart[wid], c = cnt[wid];
  float a = 0.f;
  int j = 0;
  for (; j + 4 <= c; j += 4) {
    int s0 = srcs[rs + j], s1 = srcs[rs + j + 1], s2 = srcs[rs + j + 2], s3 = srcs[rs + j + 3];
    float w0 = dinv[s0], w1 = dinv[s1], w2 = dinv[s2], w3 = dinv[s3];
    float v0 = bf2f(X16[s0 * 64 + lane]);
    float v1 = bf2f(X16[s1 * 64 + lane]);
    float v2 = bf2f(X16[s2 * 64 + lane]);
    float v3 = bf2f(X16[s3 * 64 + lane]);
    a += w0 * v0 + w1 * v1 + w2 * v2 + w3 * v3;
  }
  for (; j < c; j++) {
    int s = srcs[rs + j];
    a += dinv[s] * bf2f(X16[s * 64 + lane]);
  }
  out16[wid * 64 + lane] = f2bf(dinv[wid] * a);
}

// ---------------- Fused node matmul ----------------
// out = [relu]( [out +] A'@WA + B@WB + bias ), A' = A/max(cnt,1); A/B f32 or bf16.

__global__ __launch_bounds__(256)
void k_node_mm(const void* __restrict__ Av, int a16f, const int* __restrict__ cntA,
               const float* __restrict__ WA,
               const void* __restrict__ Bv, int DB, int b16f,
               const float* __restrict__ WB,
               const float* __restrict__ bias,
               float* __restrict__ out, unsigned short* __restrict__ out16,
               int n, int dorelu, int accum) {
  __shared__ float WAs[64 * 64];
  __shared__ float WBs[64 * 64];
  __shared__ float bs[64];
  __shared__ float as[64 * 68];
  const int tid = threadIdx.x;
  {
    const float4* w4 = (const float4*)WA;
    float4* s4 = (float4*)WAs;
    for (int i = tid; i < 1024; i += 256) s4[i] = w4[i];
    if (Bv) {
      const float4* wb4 = (const float4*)WB;
      float4* sb4 = (float4*)WBs;
      int nb = DB * 16;
      for (int i = tid; i < nb; i += 256) sb4[i] = wb4[i];
    }
    if (tid < 64) bs[tid] = bias ? bias[tid] : 0.0f;
  }
  const int gb = blockIdx.x * 64;
  for (int i = tid; i < 1024; i += 256) {
    int nl = i >> 4, k4 = i & 15;
    int g = gb + nl;
    float4 v = make_float4(0.f, 0.f, 0.f, 0.f);
    if (g < n) {
      if (a16f) {
        uint2 u = ((const uint2*)((const unsigned short*)Av + (size_t)g * 64))[k4];
        v.x = bf2f((unsigned short)(u.x & 0xFFFF));
        v.y = bf2f((unsigned short)(u.x >> 16));
        v.z = bf2f((unsigned short)(u.y & 0xFFFF));
        v.w = bf2f((unsigned short)(u.y >> 16));
      } else {
        v = ((const float4*)Av)[g * 16 + k4];
      }
      if (cntA) {
        float sc = 1.0f / fmaxf((float)cntA[g], 1.0f);
        v.x *= sc; v.y *= sc; v.z *= sc; v.w *= sc;
      }
    }
    *(float4*)(&as[nl * 68 + k4 * 4]) = v;
  }
  __syncthreads();
  const int lane = tid & 63;
  const int fq = lane & 15, nq = lane >> 4;
  const int f0 = fq * 4;
  const int nl0 = (tid >> 6) * 16 + nq * 4;
  float acc[4][4];
#pragma unroll
  for (int j = 0; j < 4; j++)
#pragma unroll
    for (int jj = 0; jj < 4; jj++) acc[j][jj] = 0.f;
#pragma unroll 4
  for (int k = 0; k < 64; k++) {
    float4 w = *(const float4*)(&WAs[k * 64 + f0]);
#pragma unroll
    for (int j = 0; j < 4; j++) {
      float a = as[(nl0 + j) * 68 + k];
      acc[j][0] += a * w.x; acc[j][1] += a * w.y; acc[j][2] += a * w.z; acc[j][3] += a * w.w;
    }
  }
  if (Bv) {
    __syncthreads();
    if (DB == 64) {
      for (int i = tid; i < 1024; i += 256) {
        int nl = i >> 4, k4 = i & 15;
        int g = gb + nl;
        float4 v = make_float4(0.f, 0.f, 0.f, 0.f);
        if (g < n) {
          if (b16f) {
            uint2 u = ((const uint2*)((const unsigned short*)Bv + (size_t)g * 64))[k4];
            v.x = bf2f((unsigned short)(u.x & 0xFFFF));
            v.y = bf2f((unsigned short)(u.x >> 16));
            v.z = bf2f((unsigned short)(u.y & 0xFFFF));
            v.w = bf2f((unsigned short)(u.y >> 16));
          } else {
            v = ((const float4*)Bv)[g * 16 + k4];
          }
        }
        *(float4*)(&as[nl * 68 + k4 * 4]) = v;
      }
    } else {
      const float* Bf = (const float*)Bv;
      for (int i = tid; i < 64 * DB; i += 256) {
        int nl = i / DB, k = i - nl * DB;
        int g = gb + nl;
        as[nl * 68 + k] = (g < n) ? Bf[g * DB + k] : 0.f;
      }
    }
    __syncthreads();
    for (int k = 0; k < DB; k++) {
      float4 w = *(const float4*)(&WBs[k * 64 + f0]);
#pragma unroll
      for (int j = 0; j < 4; j++) {
        float a = as[(nl0 + j) * 68 + k];
        acc[j][0] += a * w.x; acc[j][1] += a * w.y; acc[j][2] += a * w.z; acc[j][3] += a * w.w;
      }
    }
  }
#pragma unroll
  for (int j = 0; j < 4; j++) {
    int g = gb + nl0 + j;
    if (g < n) {
#pragma unroll
      for (int jj = 0; jj < 4; jj++) {
        int f = f0 + jj;
        float v = acc[j][jj] + bs[f];
        if (accum) v += out[g * 64 + f];
        if (dorelu) v = fmaxf(v, 0.f);
        out[g * 64 + f] = v;
        if (out16) out16[g * 64 + f] = f2bf(v);
      }
    }
  }
}

// ---------------- Final projection ----------------

__global__ void k_final(const float* __restrict__ X, const float* __restrict__ Wl,
                        const float* __restrict__ bl, float* __restrict__ out) {
  __shared__ float Ws[64 * 8];
  __shared__ float bsh[8];
  int tid = threadIdx.x;
  for (int i = tid; i < 512; i += 256) Ws[i] = Wl[i];
  if (tid < 8) bsh[tid] = bl[tid];
  __syncthreads();
  int gid = blockIdx.x * 256 + tid;
  if (gid >= NSV * 8) return;
  int v = gid >> 3, f = gid & 7;
  float acc = bsh[f];
  const float* xr = X + v * 64;
#pragma unroll 8
  for (int k = 0; k < 64; k++) acc += xr[k] * Ws[k * 8 + f];
  out[gid] = acc;
}

// ---------------- Host ----------------

extern "C" void kernel_launch(void* const* d_in, const int* in_sizes, int n_in,
                              void* d_out, int out_size, void* d_ws, size_t ws_size,
                              hipStream_t stream) {
  const float* game_x  = (const float*)d_in[0];
  const float* state_x = (const float*)d_in[1];
  const int*   ei_vv   = (const int*)d_in[2];
  const int*   et_vv   = (const int*)d_in[3];
  const int*   ei_h    = (const int*)d_in[4];
  const float* ew_h    = (const float*)d_in[5];
  const int*   ei_in   = (const int*)d_in[6];
  const int*   ei_ss   = (const int*)d_in[7];
  const float* W1_rel  = (const float*)d_in[8];
  const float* W1_root = (const float*)d_in[9];
  const float* b1      = (const float*)d_in[10];
  const float* W12     = (const float*)d_in[11];
  const float* b12     = (const float*)d_in[12];
  const float* W2      = (const float*)d_in[13];
  const float* b2      = (const float*)d_in[14];
  const float* W3_rel  = (const float*)d_in[15];
  const float* W3_root = (const float*)d_in[16];
  const float* b3      = (const float*)d_in[17];
  const float* W32_l   = (const float*)d_in[18];
  const float* W32_r   = (const float*)d_in[19];
  const float* b32     = (const float*)d_in[20];
  const float* W4_l    = (const float*)d_in[21];
  const float* W4_r    = (const float*)d_in[22];
  const float* b4      = (const float*)d_in[23];
  const float* W42_l   = (const float*)d_in[24];
  const float* W42_r   = (const float*)d_in[25];
  const float* b42     = (const float*)d_in[26];
  const float* W5_l    = (const float*)d_in[27];
  const float* W5_r    = (const float*)d_in[28];
  const float* b5      = (const float*)d_in[29];
  const float* Wl      = (const float*)d_in[30];
  const float* bl      = (const float*)d_in[31];

  // Workspace (4B slots), 25.9M slots = 103.6 MiB.
  float* ws = (float*)d_ws;
  int*   cnt_all = (int*)(ws + 0);              // 250K (vv|h|in|ss)
  int*   rs_all  = (int*)(ws + 250000);         // 250K (graph-local values)
  int*   bcnt    = (int*)(ws + 500000);         // 512
  int*   bbase   = (int*)(ws + 500512);         // 512
  int*   cb      = (int*)(ws + 501024);         // 512
  int*   srcs_ss = (int*)(ws + 760000);         // 0.8M  (lives through phase E)
  float4* x_pad  = (float4*)(ws + 1600000);     // 800K
  float4* h1p    = (float4*)(ws + 2400000);
  float4* h2p    = (float4*)(ws + 3200000);
  float4* h3p    = (float4*)(ws + 4000000);
  float* relall  = ws + 4800000;                // 1.8M -> ends 6.6M
  float* dinvS   = ws + 6600000;                // 50K
  unsigned short* gx16 = (unsigned short*)(ws + 6700000);  // [NVV][64] bf16 = 3.2M slots -> 9.9M
  unsigned* temp_vv    = (unsigned*)(ws + 6700000);        // 1.6M, overlays gx16 front (dead before combine)
  float* aggHw = ws + 9900000;                  // 3.2M
  float* aggHu = ws + 13100000;                 // 3.2M
  float* aggIN = ws + 16300000;                 // 3.2M
  float* S1    = ws + 19500000;                 // 3.2M
  float* S2    = ws + 22700000;                 // 3.2M -> ends 25.9M
  // fill temps overlay agg regions (dead until phase B):
  uint2*    temp_h  = (uint2*)aggHw;                         // [9.9M,11.5M)
  unsigned* temp_in = (unsigned*)(aggHw + 1600000);          // [11.5M,12.3M)
  unsigned* temp_ss = (unsigned*)(aggHw + 2400000);          // [12.3M,13.1M)
  // other overlays (aliases verified dead-before-write):
  unsigned short* S2b = (unsigned short*)aggHw;              // C4 shadow; aggHw dead after MM-C1
  float*          aggSS = aggHw + 1600000;                   // phase E; S2b/t1b dead by then
  unsigned short* t1b = (unsigned short*)aggHu;              // aggHu dead after MM-C2
  unsigned short* t2b = (unsigned short*)(aggHu + 1600000);
  unsigned short* t3b = (unsigned short*)aggIN;              // aggIN dead after MM-C4
  unsigned short* S1b = (unsigned short*)(aggIN + 1600000);  // D2 shadow
  unsigned* payload_vv = (unsigned*)S1;                      // dead before MM-C1 writes S1
  int2*     eh         = (int2*)S2;                          // dead before MM-C2 writes S2
  int*      srcs_in    = (int*)(S2 + 1600000);

  const int* src_vv = ei_vv;  const int* dst_vv = ei_vv + E_VV;
  const int* src_h  = ei_h;   const int* dst_h  = ei_h + E_H;
  const int* src_in = ei_in;  const int* dst_in = ei_in + E_IN;
  const int* src_ss = ei_ss;  const int* dst_ss = ei_ss + E_SS;

  auto nblk = [](long long n) { return dim3((unsigned)((n + 255) / 256)); };
  const int NB64 = (NSV + 3) / 4;
  const int NB   = (NSV + 63) / 64;
  const int G1VV = (E_VV + T1 - 1) / T1;    // 391
  const int G1S  = (E_H + T1 - 1) / T1;     // 196
  const int GC   = (ETOT + TC - 1) / TC;    // 245

  int* cnt_h  = cnt_all + H_ROW;
  int* cnt_in = cnt_all + IN_ROW;
  int* cnt_ss = cnt_all + SS_ROW;
  int* rs_vv  = rs_all;
  int* rs_h   = rs_all + H_ROW;
  int* rs_in  = rs_all + IN_ROW;
  int* rs_ss  = rs_all + SS_ROW;

  // ---- CSR build: bucket count -> bucket scan -> two-stage binned fills (no per-dst atomics) ----
  hipMemsetAsync(bcnt, 0, NBTOT * sizeof(int), stream);
  k_bucket_count<<<GC, 256, 0, stream>>>(dst_vv, dst_h, dst_in, dst_ss, bcnt);
  k_bucket_scan<<<1, 512, 0, stream>>>(bcnt, bbase, cb);
  k_fill_vv_s1<<<G1VV, 256, 0, stream>>>(src_vv, dst_vv, et_vv, cb, temp_vv);
  k_fill_h_s1<<<G1S, 256, 0, stream>>>(src_h, dst_h, ew_h, cb + BUK_H, temp_h);
  k_fill_s1<<<G1S, 256, 0, stream>>>(src_in, dst_in, E_IN, cb + BUK_IN, temp_in);
  k_fill_s1<<<G1S, 256, 0, stream>>>(src_ss, dst_ss, E_SS, cb + BUK_SS, temp_ss);
  k_fill_vv_s2<<<NBUK, 256, 0, stream>>>(temp_vv, bbase, payload_vv, rs_vv, cnt_all);
  k_fill_h_s2<<<NBUKS, 256, 0, stream>>>(temp_h, bbase, eh, rs_h, cnt_h);
  k_fill_s2<<<NBUKS, 256, 0, stream>>>(temp_in, bbase, BUK_IN, E_IN, srcs_in, rs_in, cnt_in);
  k_fill_s2<<<NBUKS, 256, 0, stream>>>(temp_ss, bbase, BUK_SS, E_SS, srcs_ss, rs_ss, cnt_ss);
  k_prep_x<<<nblk(NVV), 256, 0, stream>>>(game_x, cnt_all, x_pad);
  k_rsqrt_deg<<<nblk(NSV), 256, 0, stream>>>(cnt_ss, dinvS, NSV);

  // ---- Phase A: v-graph 5-dim ----
  k_vv_pass1<<<nblk(NVV), 256, 0, stream>>>(x_pad, rs_vv, cnt_all, payload_vv, relall, h1p);
  k_vv_hop<<<nblk(NVV), 256, 0, stream>>>(h1p, rs_vv, cnt_all, payload_vv, h2p);
  k_vv_hop<<<nblk(NVV), 256, 0, stream>>>(h2p, rs_vv, cnt_all, payload_vv, h3p);
  k_combine_gx<<<dim3((NVV + 3) / 4), 256, 0, stream>>>(x_pad, relall, h1p, h2p, h3p,
                                                        W1_rel, W1_root, b1, W12, b12, gx16);

  // ---- Phase B: 64-dim bf16 gathers ----
  k_agg_h64<<<NB64, 256, 0, stream>>>(gx16, rs_h, cnt_h, eh, aggHw, aggHu);
  k_agg64b<<<NB64, 256, 0, stream>>>(gx16, rs_in, cnt_in, srcs_in, aggIN, NSV);

  // ---- Phase C: graph_conv + 3x SAGE ----
  k_node_mm<<<NB, 256, 0, stream>>>(aggHw, 0, nullptr, W3_rel, state_x, 5, 0, W3_root, b3, S1, nullptr, NSV, 1, 0);
  k_node_mm<<<NB, 256, 0, stream>>>(aggHu, 0, cnt_h,   W32_l, S1, 64, 0, W32_r, b32, S2, nullptr, NSV, 1, 0);
  k_node_mm<<<NB, 256, 0, stream>>>(aggIN, 0, cnt_in,  W4_l,  S2, 64, 0, W4_r,  b4,  S1, NSV ? nullptr : nullptr, NSV, 1, 0);
  k_node_mm<<<NB, 256, 0, stream>>>(aggIN, 0, cnt_in,  W42_l, S1, 64, 0, W42_r, b42, S2, S2b,     NSV, 1, 0);

  // ---- Phase D: TAG on s-s (bf16 hops) ----
  k_tag64b<<<NB64, 256, 0, stream>>>(S2b, rs_ss, cnt_ss, srcs_ss, dinvS, t1b, NSV);
  k_tag64b<<<NB64, 256, 0, stream>>>(t1b, rs_ss, cnt_ss, srcs_ss, dinvS, t2b, NSV);
  k_tag64b<<<NB64, 256, 0, stream>>>(t2b, rs_ss, cnt_ss, srcs_ss, dinvS, t3b, NSV);
  k_node_mm<<<NB, 256, 0, stream>>>(S2, 0, nullptr, W2,        t1b, 64, 1, W2 + 4096,  b2,      S1, nullptr, NSV, 0, 0);
  k_node_mm<<<NB, 256, 0, stream>>>(t2b, 1, nullptr, W2 + 8192, t3b, 64, 1, W2 + 12288, nullptr, S1, S1b,    NSV, 1, 1);

  // ---- Phase E: SAGE on s-s ----
  k_agg64b<<<NB64, 256, 0, stream>>>(S1b, rs_ss, cnt_ss, srcs_ss, aggSS, NSV);
  k_node_mm<<<NB, 256, 0, stream>>>(aggSS, 0, cnt_ss, W5_l, S1, 64, 0, W5_r, b5, S2, nullptr, NSV, 1, 0);

  // ---- Final projection ----
  k_final<<<nblk(NSV * 8), 256, 0, stream>>>(S2, Wl, bl, (float*)d_out);
}

// Round 9
// 826.160 us; speedup vs baseline: 4.1238x; 1.0048x over previous
//
#include <hip/hip_runtime.h>

#define NVV 100000
#define NSV 50000
#define E_VV 1600000
#define E_H  800000
#define E_IN 800000
#define E_SS 800000
#define ETOT 4000000
#define DIN 5
#define H_ROW 100000          // concatenated cnt/rs space: vv|h|in|ss
#define IN_ROW 150000
#define SS_ROW 200000
#define NROWS 250000
#define POS_H  E_VV
#define POS_IN (E_VV + E_H)
#define POS_SS (E_VV + E_H + E_IN)
#define NBUK 196              // vv buckets (dst >> 9)
#define NBUKS 98              // NSV-graph buckets
#define NBTOT 490             // vv|h|in|ss bucket space
#define BUK_H  196
#define BUK_IN 294
#define BUK_SS 392
#define BSHIFT 9
#define T1 4096               // edges per fill-stage-1 block
#define TC 16384              // edges per bucket-count block

__device__ __forceinline__ unsigned short f2bf(float x) {
  unsigned b = __float_as_uint(x);
  return (unsigned short)((b + 0x7FFFu + ((b >> 16) & 1u)) >> 16);
}
__device__ __forceinline__ float bf2f(unsigned short u) {
  return __uint_as_float(((unsigned)u) << 16);
}

// ====================== CSR build: bucket counts -> bases -> binned fills ======================

__global__ __launch_bounds__(256)
void k_bucket_count(const int* __restrict__ d_vv, const int* __restrict__ d_h,
                    const int* __restrict__ d_in, const int* __restrict__ d_ss,
                    int* __restrict__ bcnt) {
  __shared__ int h[NBTOT];
  const int tid = threadIdx.x;
  for (int i = tid; i < NBTOT; i += 256) h[i] = 0;
  __syncthreads();
  const int base = blockIdx.x * TC;
#pragma unroll 4
  for (int k = 0; k < TC / 256; k++) {
    int e = base + k * 256 + tid;
    int bi = -1;
    if (e < E_VV) bi = d_vv[e] >> BSHIFT;
    else if (e < POS_IN) bi = BUK_H + (d_h[e - POS_H] >> BSHIFT);
    else if (e < POS_SS) bi = BUK_IN + (d_in[e - POS_IN] >> BSHIFT);
    else if (e < ETOT) bi = BUK_SS + (d_ss[e - POS_SS] >> BSHIFT);
    if (bi >= 0) atomicAdd(&h[bi], 1);
  }
  __syncthreads();
  for (int i = tid; i < NBTOT; i += 256) if (h[i]) atomicAdd(&bcnt[i], h[i]);
}

__global__ __launch_bounds__(512)
void k_bucket_scan(const int* __restrict__ bcnt, int* __restrict__ bbase, int* __restrict__ cb) {
  __shared__ int sd[512];
  int t = threadIdx.x;
  int v = (t < NBTOT) ? bcnt[t] : 0;
  sd[t] = v; __syncthreads();
  for (int off = 1; off < 512; off <<= 1) {
    int x = (t >= off) ? sd[t - off] : 0;
    __syncthreads();
    sd[t] += x;
    __syncthreads();
  }
  int segstart = (t < BUK_H) ? 0 : (t < BUK_IN) ? BUK_H : (t < BUK_SS) ? BUK_IN : BUK_SS;
  int excl = ((t > 0) ? sd[t - 1] : 0) - ((segstart > 0) ? sd[segstart - 1] : 0);
  if (t < NBTOT) { bbase[t] = excl; cb[t] = excl; }
}

// ---- stage 1: bucket-grouped binning, coalesced run writes ----
__global__ __launch_bounds__(256)
void k_fill_vv_s1(const int* __restrict__ src, const int* __restrict__ dst,
                  const int* __restrict__ et,
                  int* __restrict__ cur_b, unsigned* __restrict__ temp) {
  __shared__ int hist[NBUK], lbase[NBUK], run[NBUK], gb[NBUK];
  __shared__ int sc[256];
  __shared__ unsigned stage[T1];
  __shared__ int gpos[T1];
  const int tid = threadIdx.x;
  const int base = blockIdx.x * T1;
  const int nvalid = min(T1, E_VV - base);
  for (int i = tid; i < NBUK; i += 256) { hist[i] = 0; run[i] = 0; }
  __syncthreads();
  int dv[16]; unsigned pk[16];
#pragma unroll
  for (int k = 0; k < 16; k++) {
    int e = base + k * 256 + tid;
    if (e < E_VV) {
      int d = dst[e];
      dv[k] = d;
      pk[k] = (unsigned)(((d & 511) << 19) | (et[e] << 17) | src[e]);
      atomicAdd(&hist[d >> BSHIFT], 1);
    } else dv[k] = -1;
  }
  __syncthreads();
  int my = (tid < NBUK) ? hist[tid] : 0;
  sc[tid] = my; __syncthreads();
  for (int off = 1; off < 256; off <<= 1) {
    int t = (tid >= off) ? sc[tid - off] : 0;
    __syncthreads();
    sc[tid] += t;
    __syncthreads();
  }
  if (tid < NBUK) {
    lbase[tid] = sc[tid] - my;
    gb[tid] = my ? atomicAdd(&cur_b[tid], my) : 0;
  }
  __syncthreads();
#pragma unroll
  for (int k = 0; k < 16; k++) {
    if (dv[k] >= 0) {
      int b = dv[k] >> BSHIFT;
      int loc = atomicAdd(&run[b], 1);
      int li = lbase[b] + loc;
      stage[li] = pk[k];
      gpos[li] = gb[b] + loc;
    }
  }
  __syncthreads();
  for (int i = tid; i < nvalid; i += 256) temp[gpos[i]] = stage[i];
}

__global__ __launch_bounds__(256)
void k_fill_s1(const int* __restrict__ src, const int* __restrict__ dst, int ne,
               int* __restrict__ cur_b, unsigned* __restrict__ temp) {
  __shared__ int hist[NBUKS], lbase[NBUKS], run[NBUKS], gb[NBUKS];
  __shared__ int sc[256];
  __shared__ unsigned stage[T1];
  __shared__ int gpos[T1];
  const int tid = threadIdx.x;
  const int base = blockIdx.x * T1;
  const int nvalid = min(T1, ne - base);
  for (int i = tid; i < NBUKS; i += 256) { hist[i] = 0; run[i] = 0; }
  __syncthreads();
  int dv[16]; unsigned pk[16];
#pragma unroll
  for (int k = 0; k < 16; k++) {
    int e = base + k * 256 + tid;
    if (e < ne) {
      int d = dst[e];
      dv[k] = d;
      pk[k] = (unsigned)(((d & 511) << 17) | src[e]);
      atomicAdd(&hist[d >> BSHIFT], 1);
    } else dv[k] = -1;
  }
  __syncthreads();
  int my = (tid < NBUKS) ? hist[tid] : 0;
  sc[tid] = my; __syncthreads();
  for (int off = 1; off < 256; off <<= 1) {
    int t = (tid >= off) ? sc[tid - off] : 0;
    __syncthreads();
    sc[tid] += t;
    __syncthreads();
  }
  if (tid < NBUKS) {
    lbase[tid] = sc[tid] - my;
    gb[tid] = my ? atomicAdd(&cur_b[tid], my) : 0;
  }
  __syncthreads();
#pragma unroll
  for (int k = 0; k < 16; k++) {
    if (dv[k] >= 0) {
      int b = dv[k] >> BSHIFT;
      int loc = atomicAdd(&run[b], 1);
      int li = lbase[b] + loc;
      stage[li] = pk[k];
      gpos[li] = gb[b] + loc;
    }
  }
  __syncthreads();
  for (int i = tid; i < nvalid; i += 256) temp[gpos[i]] = stage[i];
}

__global__ __launch_bounds__(256)
void k_fill_h_s1(const int* __restrict__ src, const int* __restrict__ dst,
                 const float* __restrict__ ew,
                 int* __restrict__ cur_b, uint2* __restrict__ temp) {
  __shared__ int hist[NBUKS], lbase[NBUKS], run[NBUKS], gb[NBUKS];
  __shared__ int sc[256];
  __shared__ uint2 stage[T1];
  __shared__ int gpos[T1];
  const int tid = threadIdx.x;
  const int base = blockIdx.x * T1;
  const int nvalid = min(T1, E_H - base);
  for (int i = tid; i < NBUKS; i += 256) { hist[i] = 0; run[i] = 0; }
  __syncthreads();
  int dv[16]; uint2 pk[16];
#pragma unroll
  for (int k = 0; k < 16; k++) {
    int e = base + k * 256 + tid;
    if (e < E_H) {
      int d = dst[e];
      dv[k] = d;
      pk[k] = make_uint2((unsigned)(((d & 511) << 17) | src[e]), (unsigned)__float_as_int(ew[e]));
      atomicAdd(&hist[d >> BSHIFT], 1);
    } else dv[k] = -1;
  }
  __syncthreads();
  int my = (tid < NBUKS) ? hist[tid] : 0;
  sc[tid] = my; __syncthreads();
  for (int off = 1; off < 256; off <<= 1) {
    int t = (tid >= off) ? sc[tid - off] : 0;
    __syncthreads();
    sc[tid] += t;
    __syncthreads();
  }
  if (tid < NBUKS) {
    lbase[tid] = sc[tid] - my;
    gb[tid] = my ? atomicAdd(&cur_b[tid], my) : 0;
  }
  __syncthreads();
#pragma unroll
  for (int k = 0; k < 16; k++) {
    if (dv[k] >= 0) {
      int b = dv[k] >> BSHIFT;
      int loc = atomicAdd(&run[b], 1);
      int li = lbase[b] + loc;
      stage[li] = pk[k];
      gpos[li] = gb[b] + loc;
    }
  }
  __syncthreads();
  for (int i = tid; i < nvalid; i += 256) temp[gpos[i]] = stage[i];
}

// ---- stage 2: per-bucket LDS count + scan -> cnt/rs coalesced; then in-window scatter ----

__global__ __launch_bounds__(256)
void k_fill_vv_s2(const unsigned* __restrict__ temp, const int* __restrict__ bbase,
                  unsigned* __restrict__ payload, int* __restrict__ rs, int* __restrict__ cnt) {
  __shared__ int lcnt[512], lpos[512];
  __shared__ int sc[256];
  const int b = blockIdx.x, tid = threadIdx.x;
  const int d0 = b << BSHIFT;
  lcnt[tid] = 0; lcnt[tid + 256] = 0;
  __syncthreads();
  const int gstart = bbase[b];
  const int gend = (b == NBUK - 1) ? E_VV : bbase[b + 1];
  for (int i = gstart + tid; i < gend; i += 256) atomicAdd(&lcnt[temp[i] >> 19], 1);
  __syncthreads();
  int c0 = lcnt[2 * tid], c1 = lcnt[2 * tid + 1];
  int ps = c0 + c1;
  sc[tid] = ps; __syncthreads();
  for (int off = 1; off < 256; off <<= 1) {
    int x = (tid >= off) ? sc[tid - off] : 0;
    __syncthreads();
    sc[tid] += x;
    __syncthreads();
  }
  int basep = gstart + sc[tid] - ps;
  lpos[2 * tid] = basep;
  lpos[2 * tid + 1] = basep + c0;
  __syncthreads();
  for (int d = tid; d < 512; d += 256) {
    int gd = d0 + d;
    if (gd < NVV) { rs[gd] = lpos[d]; cnt[gd] = lcnt[d]; }
  }
  __syncthreads();
  for (int i = gstart + tid; i < gend; i += 256) {
    unsigned en = temp[i];
    int pos = atomicAdd(&lpos[en >> 19], 1);
    payload[pos] = en & 0x7FFFFu;
  }
}

__global__ __launch_bounds__(256)
void k_fill_s2(const unsigned* __restrict__ temp, const int* __restrict__ bbase, int buk0,
               int nloc, int* __restrict__ payload, int* __restrict__ rs, int* __restrict__ cnt) {
  __shared__ int lcnt[512], lpos[512];
  __shared__ int sc[256];
  const int b = blockIdx.x, tid = threadIdx.x;
  const int d0 = b << BSHIFT;
  lcnt[tid] = 0; lcnt[tid + 256] = 0;
  __syncthreads();
  const int gstart = bbase[buk0 + b];
  const int gend = (b == NBUKS - 1) ? nloc : bbase[buk0 + b + 1];
  for (int i = gstart + tid; i < gend; i += 256) atomicAdd(&lcnt[temp[i] >> 17], 1);
  __syncthreads();
  int c0 = lcnt[2 * tid], c1 = lcnt[2 * tid + 1];
  int ps = c0 + c1;
  sc[tid] = ps; __syncthreads();
  for (int off = 1; off < 256; off <<= 1) {
    int x = (tid >= off) ? sc[tid - off] : 0;
    __syncthreads();
    sc[tid] += x;
    __syncthreads();
  }
  int basep = gstart + sc[tid] - ps;
  lpos[2 * tid] = basep;
  lpos[2 * tid + 1] = basep + c0;
  __syncthreads();
  for (int d = tid; d < 512; d += 256) {
    int gd = d0 + d;
    if (gd < NSV) { rs[gd] = lpos[d]; cnt[gd] = lcnt[d]; }
  }
  __syncthreads();
  for (int i = gstart + tid; i < gend; i += 256) {
    unsigned en = temp[i];
    int pos = atomicAdd(&lpos[en >> 17], 1);
    payload[pos] = (int)(en & 0x1FFFFu);
  }
}

__global__ __launch_bounds__(256)
void k_fill_h_s2(const uint2* __restrict__ temp, const int* __restrict__ bbase,
                 int2* __restrict__ eh, int* __restrict__ rs, int* __restrict__ cnt) {
  __shared__ int lcnt[512], lpos[512];
  __shared__ int sc[256];
  const int b = blockIdx.x, tid = threadIdx.x;
  const int d0 = b << BSHIFT;
  lcnt[tid] = 0; lcnt[tid + 256] = 0;
  __syncthreads();
  const int gstart = bbase[BUK_H + b];
  const int gend = (b == NBUKS - 1) ? E_H : bbase[BUK_H + b + 1];
  for (int i = gstart + tid; i < gend; i += 256) atomicAdd(&lcnt[temp[i].x >> 17], 1);
  __syncthreads();
  int c0 = lcnt[2 * tid], c1 = lcnt[2 * tid + 1];
  int ps = c0 + c1;
  sc[tid] = ps; __syncthreads();
  for (int off = 1; off < 256; off <<= 1) {
    int x = (tid >= off) ? sc[tid - off] : 0;
    __syncthreads();
    sc[tid] += x;
    __syncthreads();
  }
  int basep = gstart + sc[tid] - ps;
  lpos[2 * tid] = basep;
  lpos[2 * tid + 1] = basep + c0;
  __syncthreads();
  for (int d = tid; d < 512; d += 256) {
    int gd = d0 + d;
    if (gd < NSV) { rs[gd] = lpos[d]; cnt[gd] = lcnt[d]; }
  }
  __syncthreads();
  for (int i = gstart + tid; i < gend; i += 256) {
    uint2 en = temp[i];
    int pos = atomicAdd(&lpos[en.x >> 17], 1);
    eh[pos] = make_int2((int)(en.x & 0x1FFFFu), (int)en.y);
  }
}

__global__ void k_rsqrt_deg(const int* __restrict__ deg, float* __restrict__ dinv, int n) {
  int i = blockIdx.x * 256 + threadIdx.x;
  if (i >= n) return;
  float d = (float)deg[i];
  dinv[i] = d > 0.f ? rsqrtf(d) : 0.f;
}

// ====================== Phase A: v-graph (5-dim, padded rows) ======================

__global__ void k_prep_x(const float* __restrict__ x, const int* __restrict__ cnt,
                         float4* __restrict__ xp) {
  int v = blockIdx.x * 256 + threadIdx.x;
  if (v >= NVV) return;
  float d = (float)cnt[v];
  float di = d > 0.f ? rsqrtf(d) : 0.f;
  const float* xr = x + v * 5;
  xp[v * 2]     = make_float4(xr[0], xr[1], xr[2], xr[3]);
  xp[v * 2 + 1] = make_float4(xr[4], di, 0.f, 0.f);
}

// 2-way unrolled gather: RGCN rel-sums + TAG hop-1; relall packed as 5 float4/node
__global__ __launch_bounds__(256)
void k_vv_pass1(const float4* __restrict__ xp,
                const int* __restrict__ rowstart, const int* __restrict__ cnt,
                const unsigned* __restrict__ payload,
                float4* __restrict__ ra4all, float4* __restrict__ h1p) {
  int d = blockIdx.x * 256 + threadIdx.x;
  if (d >= NVV) return;
  int rs = rowstart[d], c = cnt[d];
  float a0[5] = {0,0,0,0,0}, a1[5] = {0,0,0,0,0}, a2[5] = {0,0,0,0,0}, h[5] = {0,0,0,0,0};
  float c0 = 0.f, c1 = 0.f, c2 = 0.f;
  int j = 0;
  for (; j + 2 <= c; j += 2) {
    unsigned pA = payload[rs + j], pB = payload[rs + j + 1];
    int sA = pA & 0x1FFFF, rA = pA >> 17;
    int sB = pB & 0x1FFFF, rB = pB >> 17;
    float4 xA0 = xp[sA * 2], xA1 = xp[sA * 2 + 1];
    float4 xB0 = xp[sB * 2], xB1 = xp[sB * 2 + 1];
    float xsA[5] = {xA0.x, xA0.y, xA0.z, xA0.w, xA1.x};
    float xsB[5] = {xB0.x, xB0.y, xB0.z, xB0.w, xB1.x};
    float wA = xA1.y, wB = xB1.y;
    float mA0 = (rA == 0) ? 1.f : 0.f, mA1 = (rA == 1) ? 1.f : 0.f, mA2 = (rA == 2) ? 1.f : 0.f;
    float mB0 = (rB == 0) ? 1.f : 0.f, mB1 = (rB == 1) ? 1.f : 0.f, mB2 = (rB == 2) ? 1.f : 0.f;
    c0 += mA0 + mB0; c1 += mA1 + mB1; c2 += mA2 + mB2;
#pragma unroll
    for (int k = 0; k < 5; k++) {
      h[k] += wA * xsA[k] + wB * xsB[k];
      a0[k] += mA0 * xsA[k] + mB0 * xsB[k];
      a1[k] += mA1 * xsA[k] + mB1 * xsB[k];
      a2[k] += mA2 * xsA[k] + mB2 * xsB[k];
    }
  }
  for (; j < c; j++) {
    unsigned p = payload[rs + j];
    int s = p & 0x1FFFF, r = p >> 17;
    float4 x0 = xp[s * 2], x1 = xp[s * 2 + 1];
    float xs[5] = {x0.x, x0.y, x0.z, x0.w, x1.x};
    float wsc = x1.y;
    float m0 = (r == 0) ? 1.f : 0.f, m1 = (r == 1) ? 1.f : 0.f, m2 = (r == 2) ? 1.f : 0.f;
    c0 += m0; c1 += m1; c2 += m2;
#pragma unroll
    for (int k = 0; k < 5; k++) {
      h[k] += wsc * xs[k];
      a0[k] += m0 * xs[k]; a1[k] += m1 * xs[k]; a2[k] += m2 * xs[k];
    }
  }
  float dv = xp[d * 2 + 1].y;
  float4* ra4 = ra4all + d * 5;
  ra4[0] = make_float4(a0[0], a0[1], a0[2], a0[3]);
  ra4[1] = make_float4(a0[4], a1[0], a1[1], a1[2]);
  ra4[2] = make_float4(a1[3], a1[4], a2[0], a2[1]);
  ra4[3] = make_float4(a2[2], a2[3], a2[4], c0);
  ra4[4] = make_float4(c1, c2, 0.f, 0.f);
  h1p[d * 2]     = make_float4(dv * h[0], dv * h[1], dv * h[2], dv * h[3]);
  h1p[d * 2 + 1] = make_float4(dv * h[4], dv, 0.f, 0.f);
}

// 4-way unrolled sym-norm 5-dim hop
__global__ __launch_bounds__(256)
void k_vv_hop(const float4* __restrict__ hinp,
              const int* __restrict__ rowstart, const int* __restrict__ cnt,
              const unsigned* __restrict__ payload, float4* __restrict__ houtp) {
  int d = blockIdx.x * 256 + threadIdx.x;
  if (d >= NVV) return;
  int rs = rowstart[d], c = cnt[d];
  float h[5] = {0,0,0,0,0};
  int j = 0;
  for (; j + 4 <= c; j += 4) {
    unsigned p0 = payload[rs + j], p1 = payload[rs + j + 1];
    unsigned p2 = payload[rs + j + 2], p3 = payload[rs + j + 3];
    int s0 = p0 & 0x1FFFF, s1 = p1 & 0x1FFFF, s2 = p2 & 0x1FFFF, s3 = p3 & 0x1FFFF;
    float4 a0 = hinp[s0 * 2], b0 = hinp[s0 * 2 + 1];
    float4 a1 = hinp[s1 * 2], b1 = hinp[s1 * 2 + 1];
    float4 a2 = hinp[s2 * 2], b2 = hinp[s2 * 2 + 1];
    float4 a3 = hinp[s3 * 2], b3 = hinp[s3 * 2 + 1];
    float w0 = b0.y, w1 = b1.y, w2 = b2.y, w3 = b3.y;
    h[0] += w0 * a0.x + w1 * a1.x + w2 * a2.x + w3 * a3.x;
    h[1] += w0 * a0.y + w1 * a1.y + w2 * a2.y + w3 * a3.y;
    h[2] += w0 * a0.z + w1 * a1.z + w2 * a2.z + w3 * a3.z;
    h[3] += w0 * a0.w + w1 * a1.w + w2 * a2.w + w3 * a3.w;
    h[4] += w0 * b0.x + w1 * b1.x + w2 * b2.x + w3 * b3.x;
  }
  for (; j < c; j++) {
    int s = payload[rs + j] & 0x1FFFF;
    float4 x0 = hinp[s * 2], x1 = hinp[s * 2 + 1];
    float wsc = x1.y;
    h[0] += wsc * x0.x; h[1] += wsc * x0.y; h[2] += wsc * x0.z; h[3] += wsc * x0.w;
    h[4] += wsc * x1.x;
  }
  float dv = hinp[d * 2 + 1].y;
  houtp[d * 2]     = make_float4(dv * h[0], dv * h[1], dv * h[2], dv * h[3]);
  houtp[d * 2 + 1] = make_float4(dv * h[4], dv, 0.f, 0.f);
}

// v2: 8 nodes/thread, Ws column in 35 VGPRs, float4 relall loads.
__global__ __launch_bounds__(256)
void k_combine_gx(const float4* __restrict__ xp,
                  const float4* __restrict__ ra4all,
                  const float4* __restrict__ h1p, const float4* __restrict__ h2p,
                  const float4* __restrict__ h3p,
                  const float* __restrict__ W1_rel, const float* __restrict__ W1_root,
                  const float* __restrict__ b1,
                  const float* __restrict__ W12, const float* __restrict__ b12,
                  unsigned short* __restrict__ gx16) {
  __shared__ float Ws[7 * 320];
  __shared__ float bs[64];
  int tid = threadIdx.x;
  for (int i = tid; i < 320; i += 256) {
    Ws[i]        = W1_root[i] + W12[i];
    Ws[320 + i]  = W1_rel[i];
    Ws[640 + i]  = W1_rel[320 + i];
    Ws[960 + i]  = W1_rel[640 + i];
    Ws[1280 + i] = W12[320 + i];
    Ws[1600 + i] = W12[640 + i];
    Ws[1920 + i] = W12[960 + i];
  }
  if (tid < 64) bs[tid] = b1[tid] + b12[tid];
  __syncthreads();
  const int f = tid & 63;
  const int grp = tid >> 6;
  float wcol[35];
#pragma unroll
  for (int t = 0; t < 35; t++) wcol[t] = Ws[t * 64 + f];
  const float bias = bs[f];
  const int v0 = blockIdx.x * 32 + grp * 8;
  for (int n = 0; n < 8; n++) {
    int v = v0 + n;
    if (v >= NVV) return;
    float in[35];
    {
      float4 x0 = xp[v * 2], x1 = xp[v * 2 + 1];
      in[0] = x0.x; in[1] = x0.y; in[2] = x0.z; in[3] = x0.w; in[4] = x1.x;
    }
    {
      const float4* ra = ra4all + v * 5;
      float4 r0 = ra[0], r1 = ra[1], r2 = ra[2], r3 = ra[3], r4 = ra[4];
      float i0 = 1.0f / fmaxf(r3.w, 1.0f);
      float i1 = 1.0f / fmaxf(r4.x, 1.0f);
      float i2 = 1.0f / fmaxf(r4.y, 1.0f);
      in[5]  = r0.x * i0; in[6]  = r0.y * i0; in[7]  = r0.z * i0; in[8]  = r0.w * i0; in[9]  = r1.x * i0;
      in[10] = r1.y * i1; in[11] = r1.z * i1; in[12] = r1.w * i1; in[13] = r2.x * i1; in[14] = r2.y * i1;
      in[15] = r2.z * i2; in[16] = r2.w * i2; in[17] = r3.x * i2; in[18] = r3.y * i2; in[19] = r3.z * i2;
    }
    {
      float4 a = h1p[v * 2], b = h1p[v * 2 + 1];
      in[20] = a.x; in[21] = a.y; in[22] = a.z; in[23] = a.w; in[24] = b.x;
      a = h2p[v * 2]; b = h2p[v * 2 + 1];
      in[25] = a.x; in[26] = a.y; in[27] = a.z; in[28] = a.w; in[29] = b.x;
      a = h3p[v * 2]; b = h3p[v * 2 + 1];
      in[30] = a.x; in[31] = a.y; in[32] = a.z; in[33] = a.w; in[34] = b.x;
    }
    float acc = bias;
#pragma unroll
    for (int t = 0; t < 35; t++) acc += in[t] * wcol[t];
    gx16[v * 64 + f] = f2bf(acc);
  }
}

// ================= 64-dim CSR gathers (wave per dst, lane=feature, 8-way MLP) =================

__global__ __launch_bounds__(256)
void k_agg_h64(const unsigned short* __restrict__ X16,
               const int* __restrict__ rowstart, const int* __restrict__ cnt,
               const int2* __restrict__ eh,
               float* __restrict__ outw, float* __restrict__ outu) {
  int wid = blockIdx.x * 4 + (threadIdx.x >> 6);
  if (wid >= NSV) return;
  int lane = threadIdx.x & 63;
  int rs = rowstart[wid], c = cnt[wid];
  float aw = 0.f, au = 0.f;
  int j = 0;
  for (; j + 8 <= c; j += 8) {
    int2 p0 = eh[rs + j],     p1 = eh[rs + j + 1], p2 = eh[rs + j + 2], p3 = eh[rs + j + 3];
    int2 p4 = eh[rs + j + 4], p5 = eh[rs + j + 5], p6 = eh[rs + j + 6], p7 = eh[rs + j + 7];
    float v0 = bf2f(X16[p0.x * 64 + lane]);
    float v1 = bf2f(X16[p1.x * 64 + lane]);
    float v2 = bf2f(X16[p2.x * 64 + lane]);
    float v3 = bf2f(X16[p3.x * 64 + lane]);
    float v4 = bf2f(X16[p4.x * 64 + lane]);
    float v5 = bf2f(X16[p5.x * 64 + lane]);
    float v6 = bf2f(X16[p6.x * 64 + lane]);
    float v7 = bf2f(X16[p7.x * 64 + lane]);
    au += ((v0 + v1) + (v2 + v3)) + ((v4 + v5) + (v6 + v7));
    aw += __int_as_float(p0.y) * v0 + __int_as_float(p1.y) * v1
        + __int_as_float(p2.y) * v2 + __int_as_float(p3.y) * v3
        + __int_as_float(p4.y) * v4 + __int_as_float(p5.y) * v5
        + __int_as_float(p6.y) * v6 + __int_as_float(p7.y) * v7;
  }
  for (; j < c; j++) {
    int2 p = eh[rs + j];
    float v = bf2f(X16[p.x * 64 + lane]);
    au += v; aw += __int_as_float(p.y) * v;
  }
  outw[wid * 64 + lane] = aw;
  outu[wid * 64 + lane] = au;
}

__global__ __launch_bounds__(256)
void k_agg64b(const unsigned short* __restrict__ X16,
              const int* __restrict__ rowstart, const int* __restrict__ cnt,
              const int* __restrict__ srcs, float* __restrict__ out, int n) {
  int wid = blockIdx.x * 4 + (threadIdx.x >> 6);
  if (wid >= n) return;
  int lane = threadIdx.x & 63;
  int rs = rowstart[wid], c = cnt[wid];
  float a = 0.f;
  int j = 0;
  for (; j + 8 <= c; j += 8) {
    int s0 = srcs[rs + j],     s1 = srcs[rs + j + 1], s2 = srcs[rs + j + 2], s3 = srcs[rs + j + 3];
    int s4 = srcs[rs + j + 4], s5 = srcs[rs + j + 5], s6 = srcs[rs + j + 6], s7 = srcs[rs + j + 7];
    float v0 = bf2f(X16[s0 * 64 + lane]);
    float v1 = bf2f(X16[s1 * 64 + lane]);
    float v2 = bf2f(X16[s2 * 64 + lane]);
    float v3 = bf2f(X16[s3 * 64 + lane]);
    float v4 = bf2f(X16[s4 * 64 + lane]);
    float v5 = bf2f(X16[s5 * 64 + lane]);
    float v6 = bf2f(X16[s6 * 64 + lane]);
    float v7 = bf2f(X16[s7 * 64 + lane]);
    a += ((v0 + v1) + (v2 + v3)) + ((v4 + v5) + (v6 + v7));
  }
  for (; j < c; j++) a += bf2f(X16[srcs[rs + j] * 64 + lane]);
  out[wid * 64 + lane] = a;
}

__global__ __launch_bounds__(256)
void k_tag64b(const unsigned short* __restrict__ X16,
              const int* __restrict__ rowstart, const int* __restrict__ cnt,
              const int* __restrict__ srcs, const float* __restrict__ dinv,
              unsigned short* __restrict__ out16, int n) {
  int wid = blockIdx.x * 4 + (threadIdx.x >> 6);
  if (wid >= n) return;
  int lane = threadIdx.x & 63;
  int rs = rowstart[wid], c = cnt[wid];
  float a = 0.f;
  int j = 0;
  for (; j + 8 <= c; j += 8) {
    int s0 = srcs[rs + j],     s1 = srcs[rs + j + 1], s2 = srcs[rs + j + 2], s3 = srcs[rs + j + 3];
    int s4 = srcs[rs + j + 4], s5 = srcs[rs + j + 5], s6 = srcs[rs + j + 6], s7 = srcs[rs + j + 7];
    float w0 = dinv[s0], w1 = dinv[s1], w2 = dinv[s2], w3 = dinv[s3];
    float w4 = dinv[s4], w5 = dinv[s5], w6 = dinv[s6], w7 = dinv[s7];
    float v0 = bf2f(X16[s0 * 64 + lane]);
    float v1 = bf2f(X16[s1 * 64 + lane]);
    float v2 = bf2f(X16[s2 * 64 + lane]);
    float v3 = bf2f(X16[s3 * 64 + lane]);
    float v4 = bf2f(X16[s4 * 64 + lane]);
    float v5 = bf2f(X16[s5 * 64 + lane]);
    float v6 = bf2f(X16[s6 * 64 + lane]);
    float v7 = bf2f(X16[s7 * 64 + lane]);
    a += (w0 * v0 + w1 * v1 + w2 * v2 + w3 * v3) + (w4 * v4 + w5 * v5 + w6 * v6 + w7 * v7);
  }
  for (; j < c; j++) {
    int s = srcs[rs + j];
    a += dinv[s] * bf2f(X16[s * 64 + lane]);
  }
  out16[wid * 64 + lane] = f2bf(dinv[wid] * a);
}

// ---------------- Fused node matmul ----------------
// out = [relu]( [out +] A'@WA + B@WB + bias ), A' = A/max(cnt,1); A/B f32 or bf16.

__global__ __launch_bounds__(256)
void k_node_mm(const void* __restrict__ Av, int a16f, const int* __restrict__ cntA,
               const float* __restrict__ WA,
               const void* __restrict__ Bv, int DB, int b16f,
               const float* __restrict__ WB,
               const float* __restrict__ bias,
               float* __restrict__ out, unsigned short* __restrict__ out16,
               int n, int dorelu, int accum) {
  __shared__ float WAs[64 * 64];
  __shared__ float WBs[64 * 64];
  __shared__ float bs[64];
  __shared__ float as[64 * 68];
  const int tid = threadIdx.x;
  {
    const float4* w4 = (const float4*)WA;
    float4* s4 = (float4*)WAs;
    for (int i = tid; i < 1024; i += 256) s4[i] = w4[i];
    if (Bv) {
      const float4* wb4 = (const float4*)WB;
      float4* sb4 = (float4*)WBs;
      int nb = DB * 16;
      for (int i = tid; i < nb; i += 256) sb4[i] = wb4[i];
    }
    if (tid < 64) bs[tid] = bias ? bias[tid] : 0.0f;
  }
  const int gb = blockIdx.x * 64;
  for (int i = tid; i < 1024; i += 256) {
    int nl = i >> 4, k4 = i & 15;
    int g = gb + nl;
    float4 v = make_float4(0.f, 0.f, 0.f, 0.f);
    if (g < n) {
      if (a16f) {
        uint2 u = ((const uint2*)((const unsigned short*)Av + (size_t)g * 64))[k4];
        v.x = bf2f((unsigned short)(u.x & 0xFFFF));
        v.y = bf2f((unsigned short)(u.x >> 16));
        v.z = bf2f((unsigned short)(u.y & 0xFFFF));
        v.w = bf2f((unsigned short)(u.y >> 16));
      } else {
        v = ((const float4*)Av)[g * 16 + k4];
      }
      if (cntA) {
        float sc = 1.0f / fmaxf((float)cntA[g], 1.0f);
        v.x *= sc; v.y *= sc; v.z *= sc; v.w *= sc;
      }
    }
    *(float4*)(&as[nl * 68 + k4 * 4]) = v;
  }
  __syncthreads();
  const int lane = tid & 63;
  const int fq = lane & 15, nq = lane >> 4;
  const int f0 = fq * 4;
  const int nl0 = (tid >> 6) * 16 + nq * 4;
  float acc[4][4];
#pragma unroll
  for (int j = 0; j < 4; j++)
#pragma unroll
    for (int jj = 0; jj < 4; jj++) acc[j][jj] = 0.f;
#pragma unroll 4
  for (int k = 0; k < 64; k++) {
    float4 w = *(const float4*)(&WAs[k * 64 + f0]);
#pragma unroll
    for (int j = 0; j < 4; j++) {
      float a = as[(nl0 + j) * 68 + k];
      acc[j][0] += a * w.x; acc[j][1] += a * w.y; acc[j][2] += a * w.z; acc[j][3] += a * w.w;
    }
  }
  if (Bv) {
    __syncthreads();
    if (DB == 64) {
      for (int i = tid; i < 1024; i += 256) {
        int nl = i >> 4, k4 = i & 15;
        int g = gb + nl;
        float4 v = make_float4(0.f, 0.f, 0.f, 0.f);
        if (g < n) {
          if (b16f) {
            uint2 u = ((const uint2*)((const unsigned short*)Bv + (size_t)g * 64))[k4];
            v.x = bf2f((unsigned short)(u.x & 0xFFFF));
            v.y = bf2f((unsigned short)(u.x >> 16));
            v.z = bf2f((unsigned short)(u.y & 0xFFFF));
            v.w = bf2f((unsigned short)(u.y >> 16));
          } else {
            v = ((const float4*)Bv)[g * 16 + k4];
          }
        }
        *(float4*)(&as[nl * 68 + k4 * 4]) = v;
      }
    } else {
      const float* Bf = (const float*)Bv;
      for (int i = tid; i < 64 * DB; i += 256) {
        int nl = i / DB, k = i - nl * DB;
        int g = gb + nl;
        as[nl * 68 + k] = (g < n) ? Bf[g * DB + k] : 0.f;
      }
    }
    __syncthreads();
    for (int k = 0; k < DB; k++) {
      float4 w = *(const float4*)(&WBs[k * 64 + f0]);
#pragma unroll
      for (int j = 0; j < 4; j++) {
        float a = as[(nl0 + j) * 68 + k];
        acc[j][0] += a * w.x; acc[j][1] += a * w.y; acc[j][2] += a * w.z; acc[j][3] += a * w.w;
      }
    }
  }
#pragma unroll
  for (int j = 0; j < 4; j++) {
    int g = gb + nl0 + j;
    if (g < n) {
#pragma unroll
      for (int jj = 0; jj < 4; jj++) {
        int f = f0 + jj;
        float v = acc[j][jj] + bs[f];
        if (accum) v += out[g * 64 + f];
        if (dorelu) v = fmaxf(v, 0.f);
        out[g * 64 + f] = v;
        if (out16) out16[g * 64 + f] = f2bf(v);
      }
    }
  }
}

// ---------------- Final projection ----------------

__global__ void k_final(const float* __restrict__ X, const float* __restrict__ Wl,
                        const float* __restrict__ bl, float* __restrict__ out) {
  __shared__ float Ws[64 * 8];
  __shared__ float bsh[8];
  int tid = threadIdx.x;
  for (int i = tid; i < 512; i += 256) Ws[i] = Wl[i];
  if (tid < 8) bsh[tid] = bl[tid];
  __syncthreads();
  int gid = blockIdx.x * 256 + tid;
  if (gid >= NSV * 8) return;
  int v = gid >> 3, f = gid & 7;
  float acc = bsh[f];
  const float* xr = X + v * 64;
#pragma unroll 8
  for (int k = 0; k < 64; k++) acc += xr[k] * Ws[k * 8 + f];
  out[gid] = acc;
}

// ---------------- Host ----------------

extern "C" void kernel_launch(void* const* d_in, const int* in_sizes, int n_in,
                              void* d_out, int out_size, void* d_ws, size_t ws_size,
                              hipStream_t stream) {
  const float* game_x  = (const float*)d_in[0];
  const float* state_x = (const float*)d_in[1];
  const int*   ei_vv   = (const int*)d_in[2];
  const int*   et_vv   = (const int*)d_in[3];
  const int*   ei_h    = (const int*)d_in[4];
  const float* ew_h    = (const float*)d_in[5];
  const int*   ei_in   = (const int*)d_in[6];
  const int*   ei_ss   = (const int*)d_in[7];
  const float* W1_rel  = (const float*)d_in[8];
  const float* W1_root = (const float*)d_in[9];
  const float* b1      = (const float*)d_in[10];
  const float* W12     = (const float*)d_in[11];
  const float* b12     = (const float*)d_in[12];
  const float* W2      = (const float*)d_in[13];
  const float* b2      = (const float*)d_in[14];
  const float* W3_rel  = (const float*)d_in[15];
  const float* W3_root = (const float*)d_in[16];
  const float* b3      = (const float*)d_in[17];
  const float* W32_l   = (const float*)d_in[18];
  const float* W32_r   = (const float*)d_in[19];
  const float* b32     = (const float*)d_in[20];
  const float* W4_l    = (const float*)d_in[21];
  const float* W4_r    = (const float*)d_in[22];
  const float* b4      = (const float*)d_in[23];
  const float* W42_l   = (const float*)d_in[24];
  const float* W42_r   = (const float*)d_in[25];
  const float* b42     = (const float*)d_in[26];
  const float* W5_l    = (const float*)d_in[27];
  const float* W5_r    = (const float*)d_in[28];
  const float* b5      = (const float*)d_in[29];
  const float* Wl      = (const float*)d_in[30];
  const float* bl      = (const float*)d_in[31];

  // Workspace (4B slots), peak 26.05M slots = 104.2 MiB (== round-1-proven budget).
  float* ws = (float*)d_ws;
  int*   cnt_all = (int*)(ws + 0);              // 250K (vv|h|in|ss)
  int*   rs_all  = (int*)(ws + 250000);         // 250K (graph-local values)
  int*   bcnt    = (int*)(ws + 500000);         // 512
  int*   bbase   = (int*)(ws + 500512);         // 512
  int*   cb      = (int*)(ws + 501024);         // 512
  int*   srcs_ss = (int*)(ws + 760000);         // 0.8M  (lives through phase E)
  float4* x_pad  = (float4*)(ws + 1600000);     // 800K
  float4* h1p    = (float4*)(ws + 2400000);
  float4* h2p    = (float4*)(ws + 3200000);
  float4* h3p    = (float4*)(ws + 4000000);
  float4* ra4all = (float4*)(ws + 4800000);     // [NVV][5] float4 = 2.0M slots -> 6.8M
  float* dinvS   = ws + 6800000;                // 50K
  unsigned short* gx16 = (unsigned short*)(ws + 6850000);  // [NVV][64] bf16 = 3.2M slots -> 10.05M
  unsigned* temp_vv    = (unsigned*)(ws + 6850000);        // 1.6M, overlays gx16 front (dead before combine)
  float* aggHw = ws + 10050000;                 // 3.2M
  float* aggHu = ws + 13250000;                 // 3.2M
  float* aggIN = ws + 16450000;                 // 3.2M
  float* S1    = ws + 19650000;                 // 3.2M
  float* S2    = ws + 22850000;                 // 3.2M -> ends 26.05M
  // fill temps overlay agg regions (dead until phase B):
  uint2*    temp_h  = (uint2*)aggHw;
  unsigned* temp_in = (unsigned*)(aggHw + 1600000);
  unsigned* temp_ss = (unsigned*)(aggHw + 2400000);
  // other overlays (aliases verified dead-before-write):
  unsigned short* S2b = (unsigned short*)aggHw;              // C4 shadow; aggHw dead after MM-C1
  float*          aggSS = aggHw + 1600000;                   // phase E; S2b/t1b dead by then
  unsigned short* t1b = (unsigned short*)aggHu;              // aggHu dead after MM-C2
  unsigned short* t2b = (unsigned short*)(aggHu + 1600000);
  unsigned short* t3b = (unsigned short*)aggIN;              // aggIN dead after MM-C4
  unsigned short* S1b = (unsigned short*)(aggIN + 1600000);  // D2 shadow
  unsigned* payload_vv = (unsigned*)S1;                      // dead before MM-C1 writes S1
  int2*     eh         = (int2*)S2;                          // dead before MM-C2 writes S2
  int*      srcs_in    = (int*)(S2 + 1600000);

  const int* src_vv = ei_vv;  const int* dst_vv = ei_vv + E_VV;
  const int* src_h  = ei_h;   const int* dst_h  = ei_h + E_H;
  const int* src_in = ei_in;  const int* dst_in = ei_in + E_IN;
  const int* src_ss = ei_ss;  const int* dst_ss = ei_ss + E_SS;

  auto nblk = [](long long n) { return dim3((unsigned)((n + 255) / 256)); };
  const int NB64 = (NSV + 3) / 4;
  const int NB   = (NSV + 63) / 64;
  const int G1VV = (E_VV + T1 - 1) / T1;
  const int G1S  = (E_H + T1 - 1) / T1;
  const int GC   = (ETOT + TC - 1) / TC;

  int* cnt_h  = cnt_all + H_ROW;
  int* cnt_in = cnt_all + IN_ROW;
  int* cnt_ss = cnt_all + SS_ROW;
  int* rs_vv  = rs_all;
  int* rs_h   = rs_all + H_ROW;
  int* rs_in  = rs_all + IN_ROW;
  int* rs_ss  = rs_all + SS_ROW;

  // ---- CSR build ----
  hipMemsetAsync(bcnt, 0, NBTOT * sizeof(int), stream);
  k_bucket_count<<<GC, 256, 0, stream>>>(dst_vv, dst_h, dst_in, dst_ss, bcnt);
  k_bucket_scan<<<1, 512, 0, stream>>>(bcnt, bbase, cb);
  k_fill_vv_s1<<<G1VV, 256, 0, stream>>>(src_vv, dst_vv, et_vv, cb, temp_vv);
  k_fill_h_s1<<<G1S, 256, 0, stream>>>(src_h, dst_h, ew_h, cb + BUK_H, temp_h);
  k_fill_s1<<<G1S, 256, 0, stream>>>(src_in, dst_in, E_IN, cb + BUK_IN, temp_in);
  k_fill_s1<<<G1S, 256, 0, stream>>>(src_ss, dst_ss, E_SS, cb + BUK_SS, temp_ss);
  k_fill_vv_s2<<<NBUK, 256, 0, stream>>>(temp_vv, bbase, payload_vv, rs_vv, cnt_all);
  k_fill_h_s2<<<NBUKS, 256, 0, stream>>>(temp_h, bbase, eh, rs_h, cnt_h);
  k_fill_s2<<<NBUKS, 256, 0, stream>>>(temp_in, bbase, BUK_IN, E_IN, srcs_in, rs_in, cnt_in);
  k_fill_s2<<<NBUKS, 256, 0, stream>>>(temp_ss, bbase, BUK_SS, E_SS, srcs_ss, rs_ss, cnt_ss);
  k_prep_x<<<nblk(NVV), 256, 0, stream>>>(game_x, cnt_all, x_pad);
  k_rsqrt_deg<<<nblk(NSV), 256, 0, stream>>>(cnt_ss, dinvS, NSV);

  // ---- Phase A: v-graph 5-dim ----
  k_vv_pass1<<<nblk(NVV), 256, 0, stream>>>(x_pad, rs_vv, cnt_all, payload_vv, ra4all, h1p);
  k_vv_hop<<<nblk(NVV), 256, 0, stream>>>(h1p, rs_vv, cnt_all, payload_vv, h2p);
  k_vv_hop<<<nblk(NVV), 256, 0, stream>>>(h2p, rs_vv, cnt_all, payload_vv, h3p);
  k_combine_gx<<<dim3((NVV + 31) / 32), 256, 0, stream>>>(x_pad, ra4all, h1p, h2p, h3p,
                                                          W1_rel, W1_root, b1, W12, b12, gx16);

  // ---- Phase B: 64-dim bf16 gathers ----
  k_agg_h64<<<NB64, 256, 0, stream>>>(gx16, rs_h, cnt_h, eh, aggHw, aggHu);
  k_agg64b<<<NB64, 256, 0, stream>>>(gx16, rs_in, cnt_in, srcs_in, aggIN, NSV);

  // ---- Phase C: graph_conv + 3x SAGE ----
  k_node_mm<<<NB, 256, 0, stream>>>(aggHw, 0, nullptr, W3_rel, state_x, 5, 0, W3_root, b3, S1, nullptr, NSV, 1, 0);
  k_node_mm<<<NB, 256, 0, stream>>>(aggHu, 0, cnt_h,   W32_l, S1, 64, 0, W32_r, b32, S2, nullptr, NSV, 1, 0);
  k_node_mm<<<NB, 256, 0, stream>>>(aggIN, 0, cnt_in,  W4_l,  S2, 64, 0, W4_r,  b4,  S1, nullptr, NSV, 1, 0);
  k_node_mm<<<NB, 256, 0, stream>>>(aggIN, 0, cnt_in,  W42_l, S1, 64, 0, W42_r, b42, S2, S2b,     NSV, 1, 0);

  // ---- Phase D: TAG on s-s (bf16 hops) ----
  k_tag64b<<<NB64, 256, 0, stream>>>(S2b, rs_ss, cnt_ss, srcs_ss, dinvS, t1b, NSV);
  k_tag64b<<<NB64, 256, 0, stream>>>(t1b, rs_ss, cnt_ss, srcs_ss, dinvS, t2b, NSV);
  k_tag64b<<<NB64, 256, 0, stream>>>(t2b, rs_ss, cnt_ss, srcs_ss, dinvS, t3b, NSV);
  k_node_mm<<<NB, 256, 0, stream>>>(S2, 0, nullptr, W2,        t1b, 64, 1, W2 + 4096,  b2,      S1, nullptr, NSV, 0, 0);
  k_node_mm<<<NB, 256, 0, stream>>>(t2b, 1, nullptr, W2 + 8192, t3b, 64, 1, W2 + 12288, nullptr, S1, S1b,    NSV, 1, 1);

  // ---- Phase E: SAGE on s-s ----
  k_agg64b<<<NB64, 256, 0, stream>>>(S1b, rs_ss, cnt_ss, srcs_ss, aggSS, NSV);
  k_node_mm<<<NB, 256, 0, stream>>>(aggSS, 0, cnt_ss, W5_l, S1, 64, 0, W5_r, b5, S2, nullptr, NSV, 1, 0);

  // ---- Final projection ----
  k_final<<<nblk(NSV * 8), 256, 0, stream>>>(S2, Wl, bl, (float*)d_out);
}

// Round 10
// 748.835 us; speedup vs baseline: 4.5496x; 1.1033x over previous
//
#include <hip/hip_runtime.h>

#define NVV 100000
#define NSV 50000
#define E_VV 1600000
#define E_H  800000
#define E_IN 800000
#define E_SS 800000
#define ETOT 4000000
#define DIN 5
#define H_ROW 100000          // concatenated cnt/rs space: vv|h|in|ss
#define IN_ROW 150000
#define SS_ROW 200000
#define NROWS 250000
#define POS_H  E_VV
#define POS_IN (E_VV + E_H)
#define POS_SS (E_VV + E_H + E_IN)
#define NBUK 196              // vv buckets (dst >> 9)
#define NBUKS 98              // NSV-graph buckets
#define NBTOT 490             // vv|h|in|ss bucket space
#define BUK_H  196
#define BUK_IN 294
#define BUK_SS 392
#define BSHIFT 9
#define T1 4096               // edges per fill-stage-1 block
#define TC 16384              // edges per bucket-count block
#define G1VV 391              // ceil(E_VV/T1)
#define G1S  196              // ceil(E_H/T1)
#define SB1  (G1VV + 3 * G1S) // 979 fused stage-1 blocks

__device__ __forceinline__ unsigned short f2bf(float x) {
  unsigned b = __float_as_uint(x);
  return (unsigned short)((b + 0x7FFFu + ((b >> 16) & 1u)) >> 16);
}
__device__ __forceinline__ float bf2f(unsigned short u) {
  return __uint_as_float(((unsigned)u) << 16);
}

// ====================== CSR build: bucket counts -> bases -> fused binned fills ======================

__global__ __launch_bounds__(256)
void k_bucket_count(const int* __restrict__ d_vv, const int* __restrict__ d_h,
                    const int* __restrict__ d_in, const int* __restrict__ d_ss,
                    int* __restrict__ bcnt) {
  __shared__ int h[NBTOT];
  const int tid = threadIdx.x;
  for (int i = tid; i < NBTOT; i += 256) h[i] = 0;
  __syncthreads();
  const int base = blockIdx.x * TC;
#pragma unroll 4
  for (int k = 0; k < TC / 256; k++) {
    int e = base + k * 256 + tid;
    int bi = -1;
    if (e < E_VV) bi = d_vv[e] >> BSHIFT;
    else if (e < POS_IN) bi = BUK_H + (d_h[e - POS_H] >> BSHIFT);
    else if (e < POS_SS) bi = BUK_IN + (d_in[e - POS_IN] >> BSHIFT);
    else if (e < ETOT) bi = BUK_SS + (d_ss[e - POS_SS] >> BSHIFT);
    if (bi >= 0) atomicAdd(&h[bi], 1);
  }
  __syncthreads();
  for (int i = tid; i < NBTOT; i += 256) if (h[i]) atomicAdd(&bcnt[i], h[i]);
}

__global__ __launch_bounds__(512)
void k_bucket_scan(const int* __restrict__ bcnt, int* __restrict__ bbase, int* __restrict__ cb) {
  __shared__ int sd[512];
  int t = threadIdx.x;
  int v = (t < NBTOT) ? bcnt[t] : 0;
  sd[t] = v; __syncthreads();
  for (int off = 1; off < 512; off <<= 1) {
    int x = (t >= off) ? sd[t - off] : 0;
    __syncthreads();
    sd[t] += x;
    __syncthreads();
  }
  int segstart = (t < BUK_H) ? 0 : (t < BUK_IN) ? BUK_H : (t < BUK_SS) ? BUK_IN : BUK_SS;
  int excl = ((t > 0) ? sd[t - 1] : 0) - ((segstart > 0) ? sd[segstart - 1] : 0);
  if (t < NBTOT) { bbase[t] = excl; cb[t] = excl; }
}

// ---- fused stage 1: all 4 graphs, bucket-grouped binning, coalesced run writes ----
// vv entry: [dstloc:9][et:2][src:17]; others: [dstloc:9][src:17] (+weight word for h)
__global__ __launch_bounds__(256)
void k_fill_s1_all(const int* __restrict__ s_vv, const int* __restrict__ d_vv,
                   const int* __restrict__ et,
                   const int* __restrict__ s_h, const int* __restrict__ d_h,
                   const float* __restrict__ ew,
                   const int* __restrict__ s_in, const int* __restrict__ d_in,
                   const int* __restrict__ s_ss, const int* __restrict__ d_ss,
                   int* __restrict__ cb,
                   unsigned* __restrict__ temp_vv, uint2* __restrict__ temp_h,
                   unsigned* __restrict__ temp_in, unsigned* __restrict__ temp_ss) {
  __shared__ int hist[NBUK], lbase[NBUK], run[NBUK], gb[NBUK];
  __shared__ int sc[256];
  __shared__ unsigned stage[T1];
  __shared__ unsigned stageW[T1];
  __shared__ int gpos[T1];
  const int tid = threadIdx.x;
  const int b = blockIdx.x;
  int g, tile;
  if (b < G1VV) { g = 0; tile = b; }
  else if (b < G1VV + G1S) { g = 1; tile = b - G1VV; }
  else if (b < G1VV + 2 * G1S) { g = 2; tile = b - G1VV - G1S; }
  else { g = 3; tile = b - G1VV - 2 * G1S; }
  const int ne = (g == 0) ? E_VV : E_H;
  const int nbuk = (g == 0) ? NBUK : NBUKS;
  const int cboff = (g == 0) ? 0 : (g == 1) ? BUK_H : (g == 2) ? BUK_IN : BUK_SS;
  const int* S = (g == 0) ? s_vv : (g == 1) ? s_h : (g == 2) ? s_in : s_ss;
  const int* D = (g == 0) ? d_vv : (g == 1) ? d_h : (g == 2) ? d_in : d_ss;
  const int base = tile * T1;
  const int nvalid = min(T1, ne - base);
  for (int i = tid; i < nbuk; i += 256) { hist[i] = 0; run[i] = 0; }
  __syncthreads();
  int dv[16]; unsigned pk[16], pkw[16];
#pragma unroll
  for (int k = 0; k < 16; k++) {
    int e = base + k * 256 + tid;
    if (e - base < nvalid) {
      int d = D[e];
      dv[k] = d;
      if (g == 0) pk[k] = (unsigned)(((d & 511) << 19) | (et[e] << 17) | S[e]);
      else pk[k] = (unsigned)(((d & 511) << 17) | S[e]);
      if (g == 1) pkw[k] = (unsigned)__float_as_int(ew[e]);
      atomicAdd(&hist[d >> BSHIFT], 1);
    } else dv[k] = -1;
  }
  __syncthreads();
  int my = (tid < nbuk) ? hist[tid] : 0;
  sc[tid] = my; __syncthreads();
  for (int off = 1; off < 256; off <<= 1) {
    int t = (tid >= off) ? sc[tid - off] : 0;
    __syncthreads();
    sc[tid] += t;
    __syncthreads();
  }
  if (tid < nbuk) {
    lbase[tid] = sc[tid] - my;
    gb[tid] = my ? atomicAdd(&cb[cboff + tid], my) : 0;
  }
  __syncthreads();
#pragma unroll
  for (int k = 0; k < 16; k++) {
    if (dv[k] >= 0) {
      int bu = dv[k] >> BSHIFT;
      int loc = atomicAdd(&run[bu], 1);
      int li = lbase[bu] + loc;
      stage[li] = pk[k];
      if (g == 1) stageW[li] = pkw[k];
      gpos[li] = gb[bu] + loc;
    }
  }
  __syncthreads();
  if (g == 0)      for (int i = tid; i < nvalid; i += 256) temp_vv[gpos[i]] = stage[i];
  else if (g == 1) for (int i = tid; i < nvalid; i += 256) temp_h[gpos[i]] = make_uint2(stage[i], stageW[i]);
  else if (g == 2) for (int i = tid; i < nvalid; i += 256) temp_in[gpos[i]] = stage[i];
  else             for (int i = tid; i < nvalid; i += 256) temp_ss[gpos[i]] = stage[i];
}

// ---- fused stage 2: per-bucket LDS count+scan -> cnt/rs coalesced; in-window scatter;
//      epilogues fold prep_x (vv) and rsqrt_deg (ss) ----
__global__ __launch_bounds__(256)
void k_fill_s2_all(const unsigned* __restrict__ temp_vv, const uint2* __restrict__ temp_h,
                   const unsigned* __restrict__ temp_in, const unsigned* __restrict__ temp_ss,
                   const int* __restrict__ bbase,
                   unsigned* __restrict__ payload_vv, int2* __restrict__ eh,
                   int* __restrict__ srcs_in, int* __restrict__ srcs_ss,
                   int* __restrict__ rs_all, int* __restrict__ cnt_all,
                   const float* __restrict__ x, float4* __restrict__ xp,
                   float* __restrict__ dinvS) {
  __shared__ int lcnt[512], lpos[512];
  __shared__ int sc[256];
  const int b = blockIdx.x, tid = threadIdx.x;
  int g, lb;
  if (b < BUK_H) { g = 0; lb = b; }
  else if (b < BUK_IN) { g = 1; lb = b - BUK_H; }
  else if (b < BUK_SS) { g = 2; lb = b - BUK_IN; }
  else { g = 3; lb = b - BUK_SS; }
  const int d0 = lb << BSHIFT;
  const int nrows = (g == 0) ? NVV : NSV;
  const int rowbase = (g == 0) ? 0 : (g == 1) ? H_ROW : (g == 2) ? IN_ROW : SS_ROW;
  const int ne = (g == 0) ? E_VV : E_H;
  const int lastb = (g == 0) ? NBUK - 1 : NBUKS - 1;
  const int shift = (g == 0) ? 19 : 17;
  lcnt[tid] = 0; lcnt[tid + 256] = 0;
  __syncthreads();
  const int gstart = bbase[b];
  const int gend = (lb == lastb) ? ne : bbase[b + 1];
  if (g == 1) {
    for (int i = gstart + tid; i < gend; i += 256) atomicAdd(&lcnt[temp_h[i].x >> 17], 1);
  } else {
    const unsigned* tp = (g == 0) ? temp_vv : (g == 2) ? temp_in : temp_ss;
    for (int i = gstart + tid; i < gend; i += 256) atomicAdd(&lcnt[tp[i] >> shift], 1);
  }
  __syncthreads();
  int c0 = lcnt[2 * tid], c1 = lcnt[2 * tid + 1];
  int ps = c0 + c1;
  sc[tid] = ps; __syncthreads();
  for (int off = 1; off < 256; off <<= 1) {
    int x2 = (tid >= off) ? sc[tid - off] : 0;
    __syncthreads();
    sc[tid] += x2;
    __syncthreads();
  }
  int basep = gstart + sc[tid] - ps;
  lpos[2 * tid] = basep;
  lpos[2 * tid + 1] = basep + c0;
  __syncthreads();
  for (int d = tid; d < 512; d += 256) {
    int gd = d0 + d;
    if (gd < nrows) {
      rs_all[rowbase + gd] = lpos[d];
      cnt_all[rowbase + gd] = lcnt[d];
      if (g == 0) {  // fold prep_x
        float dc = (float)lcnt[d];
        float di = dc > 0.f ? rsqrtf(dc) : 0.f;
        const float* xr = x + (size_t)gd * 5;
        xp[gd * 2]     = make_float4(xr[0], xr[1], xr[2], xr[3]);
        xp[gd * 2 + 1] = make_float4(xr[4], di, 0.f, 0.f);
      } else if (g == 3) {  // fold rsqrt_deg
        float dc = (float)lcnt[d];
        dinvS[gd] = dc > 0.f ? rsqrtf(dc) : 0.f;
      }
    }
  }
  __syncthreads();
  if (g == 0) {
    for (int i = gstart + tid; i < gend; i += 256) {
      unsigned en = temp_vv[i];
      int pos = atomicAdd(&lpos[en >> 19], 1);
      payload_vv[pos] = en & 0x7FFFFu;
    }
  } else if (g == 1) {
    for (int i = gstart + tid; i < gend; i += 256) {
      uint2 en = temp_h[i];
      int pos = atomicAdd(&lpos[en.x >> 17], 1);
      eh[pos] = make_int2((int)(en.x & 0x1FFFFu), (int)en.y);
    }
  } else if (g == 2) {
    for (int i = gstart + tid; i < gend; i += 256) {
      unsigned en = temp_in[i];
      int pos = atomicAdd(&lpos[en >> 17], 1);
      srcs_in[pos] = (int)(en & 0x1FFFFu);
    }
  } else {
    for (int i = gstart + tid; i < gend; i += 256) {
      unsigned en = temp_ss[i];
      int pos = atomicAdd(&lpos[en >> 17], 1);
      srcs_ss[pos] = (int)(en & 0x1FFFFu);
    }
  }
}

// ====================== Phase A: v-graph (5-dim, padded rows) ======================

__global__ __launch_bounds__(256)
void k_vv_pass1(const float4* __restrict__ xp,
                const int* __restrict__ rowstart, const int* __restrict__ cnt,
                const unsigned* __restrict__ payload,
                float4* __restrict__ ra4all, float4* __restrict__ h1p) {
  int d = blockIdx.x * 256 + threadIdx.x;
  if (d >= NVV) return;
  int rs = rowstart[d], c = cnt[d];
  float a0[5] = {0,0,0,0,0}, a1[5] = {0,0,0,0,0}, a2[5] = {0,0,0,0,0}, h[5] = {0,0,0,0,0};
  float c0 = 0.f, c1 = 0.f, c2 = 0.f;
  int j = 0;
  for (; j + 2 <= c; j += 2) {
    unsigned pA = payload[rs + j], pB = payload[rs + j + 1];
    int sA = pA & 0x1FFFF, rA = pA >> 17;
    int sB = pB & 0x1FFFF, rB = pB >> 17;
    float4 xA0 = xp[sA * 2], xA1 = xp[sA * 2 + 1];
    float4 xB0 = xp[sB * 2], xB1 = xp[sB * 2 + 1];
    float xsA[5] = {xA0.x, xA0.y, xA0.z, xA0.w, xA1.x};
    float xsB[5] = {xB0.x, xB0.y, xB0.z, xB0.w, xB1.x};
    float wA = xA1.y, wB = xB1.y;
    float mA0 = (rA == 0) ? 1.f : 0.f, mA1 = (rA == 1) ? 1.f : 0.f, mA2 = (rA == 2) ? 1.f : 0.f;
    float mB0 = (rB == 0) ? 1.f : 0.f, mB1 = (rB == 1) ? 1.f : 0.f, mB2 = (rB == 2) ? 1.f : 0.f;
    c0 += mA0 + mB0; c1 += mA1 + mB1; c2 += mA2 + mB2;
#pragma unroll
    for (int k = 0; k < 5; k++) {
      h[k] += wA * xsA[k] + wB * xsB[k];
      a0[k] += mA0 * xsA[k] + mB0 * xsB[k];
      a1[k] += mA1 * xsA[k] + mB1 * xsB[k];
      a2[k] += mA2 * xsA[k] + mB2 * xsB[k];
    }
  }
  for (; j < c; j++) {
    unsigned p = payload[rs + j];
    int s = p & 0x1FFFF, r = p >> 17;
    float4 x0 = xp[s * 2], x1 = xp[s * 2 + 1];
    float xs[5] = {x0.x, x0.y, x0.z, x0.w, x1.x};
    float wsc = x1.y;
    float m0 = (r == 0) ? 1.f : 0.f, m1 = (r == 1) ? 1.f : 0.f, m2 = (r == 2) ? 1.f : 0.f;
    c0 += m0; c1 += m1; c2 += m2;
#pragma unroll
    for (int k = 0; k < 5; k++) {
      h[k] += wsc * xs[k];
      a0[k] += m0 * xs[k]; a1[k] += m1 * xs[k]; a2[k] += m2 * xs[k];
    }
  }
  float dv = xp[d * 2 + 1].y;
  float4* ra4 = ra4all + d * 5;
  ra4[0] = make_float4(a0[0], a0[1], a0[2], a0[3]);
  ra4[1] = make_float4(a0[4], a1[0], a1[1], a1[2]);
  ra4[2] = make_float4(a1[3], a1[4], a2[0], a2[1]);
  ra4[3] = make_float4(a2[2], a2[3], a2[4], c0);
  ra4[4] = make_float4(c1, c2, 0.f, 0.f);
  h1p[d * 2]     = make_float4(dv * h[0], dv * h[1], dv * h[2], dv * h[3]);
  h1p[d * 2 + 1] = make_float4(dv * h[4], dv, 0.f, 0.f);
}

__global__ __launch_bounds__(256)
void k_vv_hop(const float4* __restrict__ hinp,
              const int* __restrict__ rowstart, const int* __restrict__ cnt,
              const unsigned* __restrict__ payload, float4* __restrict__ houtp) {
  int d = blockIdx.x * 256 + threadIdx.x;
  if (d >= NVV) return;
  int rs = rowstart[d], c = cnt[d];
  float h[5] = {0,0,0,0,0};
  int j = 0;
  for (; j + 4 <= c; j += 4) {
    unsigned p0 = payload[rs + j], p1 = payload[rs + j + 1];
    unsigned p2 = payload[rs + j + 2], p3 = payload[rs + j + 3];
    int s0 = p0 & 0x1FFFF, s1 = p1 & 0x1FFFF, s2 = p2 & 0x1FFFF, s3 = p3 & 0x1FFFF;
    float4 a0 = hinp[s0 * 2], b0 = hinp[s0 * 2 + 1];
    float4 a1 = hinp[s1 * 2], b1 = hinp[s1 * 2 + 1];
    float4 a2 = hinp[s2 * 2], b2 = hinp[s2 * 2 + 1];
    float4 a3 = hinp[s3 * 2], b3 = hinp[s3 * 2 + 1];
    float w0 = b0.y, w1 = b1.y, w2 = b2.y, w3 = b3.y;
    h[0] += w0 * a0.x + w1 * a1.x + w2 * a2.x + w3 * a3.x;
    h[1] += w0 * a0.y + w1 * a1.y + w2 * a2.y + w3 * a3.y;
    h[2] += w0 * a0.z + w1 * a1.z + w2 * a2.z + w3 * a3.z;
    h[3] += w0 * a0.w + w1 * a1.w + w2 * a2.w + w3 * a3.w;
    h[4] += w0 * b0.x + w1 * b1.x + w2 * b2.x + w3 * b3.x;
  }
  for (; j < c; j++) {
    int s = payload[rs + j] & 0x1FFFF;
    float4 x0 = hinp[s * 2], x1 = hinp[s * 2 + 1];
    float wsc = x1.y;
    h[0] += wsc * x0.x; h[1] += wsc * x0.y; h[2] += wsc * x0.z; h[3] += wsc * x0.w;
    h[4] += wsc * x1.x;
  }
  float dv = hinp[d * 2 + 1].y;
  houtp[d * 2]     = make_float4(dv * h[0], dv * h[1], dv * h[2], dv * h[3]);
  houtp[d * 2 + 1] = make_float4(dv * h[4], dv, 0.f, 0.f);
}

// 8 nodes/thread, Ws column in 35 VGPRs, float4 relall loads.
__global__ __launch_bounds__(256)
void k_combine_gx(const float4* __restrict__ xp,
                  const float4* __restrict__ ra4all,
                  const float4* __restrict__ h1p, const float4* __restrict__ h2p,
                  const float4* __restrict__ h3p,
                  const float* __restrict__ W1_rel, const float* __restrict__ W1_root,
                  const float* __restrict__ b1,
                  const float* __restrict__ W12, const float* __restrict__ b12,
                  unsigned short* __restrict__ gx16) {
  __shared__ float Ws[7 * 320];
  __shared__ float bs[64];
  int tid = threadIdx.x;
  for (int i = tid; i < 320; i += 256) {
    Ws[i]        = W1_root[i] + W12[i];
    Ws[320 + i]  = W1_rel[i];
    Ws[640 + i]  = W1_rel[320 + i];
    Ws[960 + i]  = W1_rel[640 + i];
    Ws[1280 + i] = W12[320 + i];
    Ws[1600 + i] = W12[640 + i];
    Ws[1920 + i] = W12[960 + i];
  }
  if (tid < 64) bs[tid] = b1[tid] + b12[tid];
  __syncthreads();
  const int f = tid & 63;
  const int grp = tid >> 6;
  float wcol[35];
#pragma unroll
  for (int t = 0; t < 35; t++) wcol[t] = Ws[t * 64 + f];
  const float bias = bs[f];
  const int v0 = blockIdx.x * 32 + grp * 8;
  for (int n = 0; n < 8; n++) {
    int v = v0 + n;
    if (v >= NVV) return;
    float in[35];
    {
      float4 x0 = xp[v * 2], x1 = xp[v * 2 + 1];
      in[0] = x0.x; in[1] = x0.y; in[2] = x0.z; in[3] = x0.w; in[4] = x1.x;
    }
    {
      const float4* ra = ra4all + v * 5;
      float4 r0 = ra[0], r1 = ra[1], r2 = ra[2], r3 = ra[3], r4 = ra[4];
      float i0 = 1.0f / fmaxf(r3.w, 1.0f);
      float i1 = 1.0f / fmaxf(r4.x, 1.0f);
      float i2 = 1.0f / fmaxf(r4.y, 1.0f);
      in[5]  = r0.x * i0; in[6]  = r0.y * i0; in[7]  = r0.z * i0; in[8]  = r0.w * i0; in[9]  = r1.x * i0;
      in[10] = r1.y * i1; in[11] = r1.z * i1; in[12] = r1.w * i1; in[13] = r2.x * i1; in[14] = r2.y * i1;
      in[15] = r2.z * i2; in[16] = r2.w * i2; in[17] = r3.x * i2; in[18] = r3.y * i2; in[19] = r3.z * i2;
    }
    {
      float4 a = h1p[v * 2], b = h1p[v * 2 + 1];
      in[20] = a.x; in[21] = a.y; in[22] = a.z; in[23] = a.w; in[24] = b.x;
      a = h2p[v * 2]; b = h2p[v * 2 + 1];
      in[25] = a.x; in[26] = a.y; in[27] = a.z; in[28] = a.w; in[29] = b.x;
      a = h3p[v * 2]; b = h3p[v * 2 + 1];
      in[30] = a.x; in[31] = a.y; in[32] = a.z; in[33] = a.w; in[34] = b.x;
    }
    float acc = bias;
#pragma unroll
    for (int t = 0; t < 35; t++) acc += in[t] * wcol[t];
    gx16[v * 64 + f] = f2bf(acc);
  }
}

// ================= 64-dim CSR gathers (wave per dst, lane=feature, 8-way MLP) =================

// fused phase-B: blocks [0,NB64) do h-graph (weighted+plain), [NB64,2*NB64) do in-graph
__global__ __launch_bounds__(256)
void k_aggB(const unsigned short* __restrict__ X16,
            const int* __restrict__ rs_h, const int* __restrict__ cnt_h,
            const int2* __restrict__ eh,
            const int* __restrict__ rs_in, const int* __restrict__ cnt_in,
            const int* __restrict__ srcs_in,
            float* __restrict__ outw, float* __restrict__ outu, float* __restrict__ outIN,
            int nb64) {
  int bb = blockIdx.x;
  int lane = threadIdx.x & 63;
  if (bb < nb64) {
    int wid = bb * 4 + (threadIdx.x >> 6);
    if (wid >= NSV) return;
    int rs = rs_h[wid], c = cnt_h[wid];
    float aw = 0.f, au = 0.f;
    int j = 0;
    for (; j + 8 <= c; j += 8) {
      int2 p0 = eh[rs + j],     p1 = eh[rs + j + 1], p2 = eh[rs + j + 2], p3 = eh[rs + j + 3];
      int2 p4 = eh[rs + j + 4], p5 = eh[rs + j + 5], p6 = eh[rs + j + 6], p7 = eh[rs + j + 7];
      float v0 = bf2f(X16[p0.x * 64 + lane]);
      float v1 = bf2f(X16[p1.x * 64 + lane]);
      float v2 = bf2f(X16[p2.x * 64 + lane]);
      float v3 = bf2f(X16[p3.x * 64 + lane]);
      float v4 = bf2f(X16[p4.x * 64 + lane]);
      float v5 = bf2f(X16[p5.x * 64 + lane]);
      float v6 = bf2f(X16[p6.x * 64 + lane]);
      float v7 = bf2f(X16[p7.x * 64 + lane]);
      au += ((v0 + v1) + (v2 + v3)) + ((v4 + v5) + (v6 + v7));
      aw += __int_as_float(p0.y) * v0 + __int_as_float(p1.y) * v1
          + __int_as_float(p2.y) * v2 + __int_as_float(p3.y) * v3
          + __int_as_float(p4.y) * v4 + __int_as_float(p5.y) * v5
          + __int_as_float(p6.y) * v6 + __int_as_float(p7.y) * v7;
    }
    for (; j < c; j++) {
      int2 p = eh[rs + j];
      float v = bf2f(X16[p.x * 64 + lane]);
      au += v; aw += __int_as_float(p.y) * v;
    }
    outw[wid * 64 + lane] = aw;
    outu[wid * 64 + lane] = au;
  } else {
    int wid = (bb - nb64) * 4 + (threadIdx.x >> 6);
    if (wid >= NSV) return;
    int rs = rs_in[wid], c = cnt_in[wid];
    float a = 0.f;
    int j = 0;
    for (; j + 8 <= c; j += 8) {
      int s0 = srcs_in[rs + j],     s1 = srcs_in[rs + j + 1], s2 = srcs_in[rs + j + 2], s3 = srcs_in[rs + j + 3];
      int s4 = srcs_in[rs + j + 4], s5 = srcs_in[rs + j + 5], s6 = srcs_in[rs + j + 6], s7 = srcs_in[rs + j + 7];
      float v0 = bf2f(X16[s0 * 64 + lane]);
      float v1 = bf2f(X16[s1 * 64 + lane]);
      float v2 = bf2f(X16[s2 * 64 + lane]);
      float v3 = bf2f(X16[s3 * 64 + lane]);
      float v4 = bf2f(X16[s4 * 64 + lane]);
      float v5 = bf2f(X16[s5 * 64 + lane]);
      float v6 = bf2f(X16[s6 * 64 + lane]);
      float v7 = bf2f(X16[s7 * 64 + lane]);
      a += ((v0 + v1) + (v2 + v3)) + ((v4 + v5) + (v6 + v7));
    }
    for (; j < c; j++) a += bf2f(X16[srcs_in[rs + j] * 64 + lane]);
    outIN[wid * 64 + lane] = a;
  }
}

__global__ __launch_bounds__(256)
void k_agg64b(const unsigned short* __restrict__ X16,
              const int* __restrict__ rowstart, const int* __restrict__ cnt,
              const int* __restrict__ srcs, float* __restrict__ out, int n) {
  int wid = blockIdx.x * 4 + (threadIdx.x >> 6);
  if (wid >= n) return;
  int lane = threadIdx.x & 63;
  int rs = rowstart[wid], c = cnt[wid];
  float a = 0.f;
  int j = 0;
  for (; j + 8 <= c; j += 8) {
    int s0 = srcs[rs + j],     s1 = srcs[rs + j + 1], s2 = srcs[rs + j + 2], s3 = srcs[rs + j + 3];
    int s4 = srcs[rs + j + 4], s5 = srcs[rs + j + 5], s6 = srcs[rs + j + 6], s7 = srcs[rs + j + 7];
    float v0 = bf2f(X16[s0 * 64 + lane]);
    float v1 = bf2f(X16[s1 * 64 + lane]);
    float v2 = bf2f(X16[s2 * 64 + lane]);
    float v3 = bf2f(X16[s3 * 64 + lane]);
    float v4 = bf2f(X16[s4 * 64 + lane]);
    float v5 = bf2f(X16[s5 * 64 + lane]);
    float v6 = bf2f(X16[s6 * 64 + lane]);
    float v7 = bf2f(X16[s7 * 64 + lane]);
    a += ((v0 + v1) + (v2 + v3)) + ((v4 + v5) + (v6 + v7));
  }
  for (; j < c; j++) a += bf2f(X16[srcs[rs + j] * 64 + lane]);
  out[wid * 64 + lane] = a;
}

// prescaled TAG hop: U = dinv ⊙ t (bf16). t_out = dinv[d]*Σ U[s]; u_out = dinv[d]*t_out.
__global__ __launch_bounds__(256)
void k_tag64b(const unsigned short* __restrict__ U16,
              const int* __restrict__ rowstart, const int* __restrict__ cnt,
              const int* __restrict__ srcs, const float* __restrict__ dinv,
              unsigned short* __restrict__ t_out, unsigned short* __restrict__ u_out, int n) {
  int wid = blockIdx.x * 4 + (threadIdx.x >> 6);
  if (wid >= n) return;
  int lane = threadIdx.x & 63;
  int rs = rowstart[wid], c = cnt[wid];
  float a = 0.f;
  int j = 0;
  for (; j + 8 <= c; j += 8) {
    int s0 = srcs[rs + j],     s1 = srcs[rs + j + 1], s2 = srcs[rs + j + 2], s3 = srcs[rs + j + 3];
    int s4 = srcs[rs + j + 4], s5 = srcs[rs + j + 5], s6 = srcs[rs + j + 6], s7 = srcs[rs + j + 7];
    float v0 = bf2f(U16[s0 * 64 + lane]);
    float v1 = bf2f(U16[s1 * 64 + lane]);
    float v2 = bf2f(U16[s2 * 64 + lane]);
    float v3 = bf2f(U16[s3 * 64 + lane]);
    float v4 = bf2f(U16[s4 * 64 + lane]);
    float v5 = bf2f(U16[s5 * 64 + lane]);
    float v6 = bf2f(U16[s6 * 64 + lane]);
    float v7 = bf2f(U16[s7 * 64 + lane]);
    a += ((v0 + v1) + (v2 + v3)) + ((v4 + v5) + (v6 + v7));
  }
  for (; j < c; j++) a += bf2f(U16[srcs[rs + j] * 64 + lane]);
  float dv = dinv[wid];
  float t = dv * a;
  t_out[wid * 64 + lane] = f2bf(t);
  if (u_out) u_out[wid * 64 + lane] = f2bf(dv * t);
}

// ---------------- Fused node matmul ----------------
// out = [relu]( [out +] A'@WA + B@WB + bias ), A' = A/max(cnt,1); A/B f32 or bf16.
// out16 (optional) = bf16(v * (oscale ? oscale[g] : 1))

__global__ __launch_bounds__(256)
void k_node_mm(const void* __restrict__ Av, int a16f, const int* __restrict__ cntA,
               const float* __restrict__ WA,
               const void* __restrict__ Bv, int DB, int b16f,
               const float* __restrict__ WB,
               const float* __restrict__ bias,
               float* __restrict__ out, unsigned short* __restrict__ out16,
               const float* __restrict__ oscale,
               int n, int dorelu, int accum) {
  __shared__ float WAs[64 * 64];
  __shared__ float WBs[64 * 64];
  __shared__ float bs[64];
  __shared__ float as[64 * 68];
  const int tid = threadIdx.x;
  {
    const float4* w4 = (const float4*)WA;
    float4* s4 = (float4*)WAs;
    for (int i = tid; i < 1024; i += 256) s4[i] = w4[i];
    if (Bv) {
      const float4* wb4 = (const float4*)WB;
      float4* sb4 = (float4*)WBs;
      int nb = DB * 16;
      for (int i = tid; i < nb; i += 256) sb4[i] = wb4[i];
    }
    if (tid < 64) bs[tid] = bias ? bias[tid] : 0.0f;
  }
  const int gb = blockIdx.x * 64;
  for (int i = tid; i < 1024; i += 256) {
    int nl = i >> 4, k4 = i & 15;
    int g = gb + nl;
    float4 v = make_float4(0.f, 0.f, 0.f, 0.f);
    if (g < n) {
      if (a16f) {
        uint2 u = ((const uint2*)((const unsigned short*)Av + (size_t)g * 64))[k4];
        v.x = bf2f((unsigned short)(u.x & 0xFFFF));
        v.y = bf2f((unsigned short)(u.x >> 16));
        v.z = bf2f((unsigned short)(u.y & 0xFFFF));
        v.w = bf2f((unsigned short)(u.y >> 16));
      } else {
        v = ((const float4*)Av)[g * 16 + k4];
      }
      if (cntA) {
        float sc = 1.0f / fmaxf((float)cntA[g], 1.0f);
        v.x *= sc; v.y *= sc; v.z *= sc; v.w *= sc;
      }
    }
    *(float4*)(&as[nl * 68 + k4 * 4]) = v;
  }
  __syncthreads();
  const int lane = tid & 63;
  const int fq = lane & 15, nq = lane >> 4;
  const int f0 = fq * 4;
  const int nl0 = (tid >> 6) * 16 + nq * 4;
  float acc[4][4];
#pragma unroll
  for (int j = 0; j < 4; j++)
#pragma unroll
    for (int jj = 0; jj < 4; jj++) acc[j][jj] = 0.f;
#pragma unroll 4
  for (int k = 0; k < 64; k++) {
    float4 w = *(const float4*)(&WAs[k * 64 + f0]);
#pragma unroll
    for (int j = 0; j < 4; j++) {
      float a = as[(nl0 + j) * 68 + k];
      acc[j][0] += a * w.x; acc[j][1] += a * w.y; acc[j][2] += a * w.z; acc[j][3] += a * w.w;
    }
  }
  if (Bv) {
    __syncthreads();
    if (DB == 64) {
      for (int i = tid; i < 1024; i += 256) {
        int nl = i >> 4, k4 = i & 15;
        int g = gb + nl;
        float4 v = make_float4(0.f, 0.f, 0.f, 0.f);
        if (g < n) {
          if (b16f) {
            uint2 u = ((const uint2*)((const unsigned short*)Bv + (size_t)g * 64))[k4];
            v.x = bf2f((unsigned short)(u.x & 0xFFFF));
            v.y = bf2f((unsigned short)(u.x >> 16));
            v.z = bf2f((unsigned short)(u.y & 0xFFFF));
            v.w = bf2f((unsigned short)(u.y >> 16));
          } else {
            v = ((const float4*)Bv)[g * 16 + k4];
          }
        }
        *(float4*)(&as[nl * 68 + k4 * 4]) = v;
      }
    } else {
      const float* Bf = (const float*)Bv;
      for (int i = tid; i < 64 * DB; i += 256) {
        int nl = i / DB, k = i - nl * DB;
        int g = gb + nl;
        as[nl * 68 + k] = (g < n) ? Bf[g * DB + k] : 0.f;
      }
    }
    __syncthreads();
    for (int k = 0; k < DB; k++) {
      float4 w = *(const float4*)(&WBs[k * 64 + f0]);
#pragma unroll
      for (int j = 0; j < 4; j++) {
        float a = as[(nl0 + j) * 68 + k];
        acc[j][0] += a * w.x; acc[j][1] += a * w.y; acc[j][2] += a * w.z; acc[j][3] += a * w.w;
      }
    }
  }
#pragma unroll
  for (int j = 0; j < 4; j++) {
    int g = gb + nl0 + j;
    if (g < n) {
      float osc = oscale ? oscale[g] : 1.0f;
#pragma unroll
      for (int jj = 0; jj < 4; jj++) {
        int f = f0 + jj;
        float v = acc[j][jj] + bs[f];
        if (accum) v += out[g * 64 + f];
        if (dorelu) v = fmaxf(v, 0.f);
        out[g * 64 + f] = v;
        if (out16) out16[g * 64 + f] = f2bf(v * osc);
      }
    }
  }
}

// ---------------- Final projection ----------------

__global__ void k_final(const float* __restrict__ X, const float* __restrict__ Wl,
                        const float* __restrict__ bl, float* __restrict__ out) {
  __shared__ float Ws[64 * 8];
  __shared__ float bsh[8];
  int tid = threadIdx.x;
  for (int i = tid; i < 512; i += 256) Ws[i] = Wl[i];
  if (tid < 8) bsh[tid] = bl[tid];
  __syncthreads();
  int gid = blockIdx.x * 256 + tid;
  if (gid >= NSV * 8) return;
  int v = gid >> 3, f = gid & 7;
  float acc = bsh[f];
  const float* xr = X + v * 64;
#pragma unroll 8
  for (int k = 0; k < 64; k++) acc += xr[k] * Ws[k * 8 + f];
  out[gid] = acc;
}

// ---------------- Host ----------------

extern "C" void kernel_launch(void* const* d_in, const int* in_sizes, int n_in,
                              void* d_out, int out_size, void* d_ws, size_t ws_size,
                              hipStream_t stream) {
  const float* game_x  = (const float*)d_in[0];
  const float* state_x = (const float*)d_in[1];
  const int*   ei_vv   = (const int*)d_in[2];
  const int*   et_vv   = (const int*)d_in[3];
  const int*   ei_h    = (const int*)d_in[4];
  const float* ew_h    = (const float*)d_in[5];
  const int*   ei_in   = (const int*)d_in[6];
  const int*   ei_ss   = (const int*)d_in[7];
  const float* W1_rel  = (const float*)d_in[8];
  const float* W1_root = (const float*)d_in[9];
  const float* b1      = (const float*)d_in[10];
  const float* W12     = (const float*)d_in[11];
  const float* b12     = (const float*)d_in[12];
  const float* W2      = (const float*)d_in[13];
  const float* b2      = (const float*)d_in[14];
  const float* W3_rel  = (const float*)d_in[15];
  const float* W3_root = (const float*)d_in[16];
  const float* b3      = (const float*)d_in[17];
  const float* W32_l   = (const float*)d_in[18];
  const float* W32_r   = (const float*)d_in[19];
  const float* b32     = (const float*)d_in[20];
  const float* W4_l    = (const float*)d_in[21];
  const float* W4_r    = (const float*)d_in[22];
  const float* b4      = (const float*)d_in[23];
  const float* W42_l   = (const float*)d_in[24];
  const float* W42_r   = (const float*)d_in[25];
  const float* b42     = (const float*)d_in[26];
  const float* W5_l    = (const float*)d_in[27];
  const float* W5_r    = (const float*)d_in[28];
  const float* b5      = (const float*)d_in[29];
  const float* Wl      = (const float*)d_in[30];
  const float* bl      = (const float*)d_in[31];

  // Workspace (4B slots), peak 26.05M slots = 104.2 MiB.
  float* ws = (float*)d_ws;
  int*   cnt_all = (int*)(ws + 0);              // 250K (vv|h|in|ss)
  int*   rs_all  = (int*)(ws + 250000);         // 250K (graph-local values)
  int*   bcnt    = (int*)(ws + 500000);         // 512
  int*   bbase   = (int*)(ws + 500512);         // 512
  int*   cb      = (int*)(ws + 501024);         // 512
  int*   srcs_ss = (int*)(ws + 760000);         // 0.8M  (lives through phase E)
  float4* x_pad  = (float4*)(ws + 1600000);     // 800K
  float4* h1p    = (float4*)(ws + 2400000);
  float4* h2p    = (float4*)(ws + 3200000);
  float4* h3p    = (float4*)(ws + 4000000);
  float4* ra4all = (float4*)(ws + 4800000);     // [NVV][5] float4 = 2.0M slots -> 6.8M
  float* dinvS   = ws + 6800000;                // 50K
  unsigned short* gx16 = (unsigned short*)(ws + 6850000);  // 3.2M slots -> 10.05M
  unsigned* temp_vv    = (unsigned*)(ws + 6850000);        // 1.6M, overlays gx16 front (dead before combine)
  float* aggHw = ws + 10050000;                 // 3.2M
  float* aggHu = ws + 13250000;                 // 3.2M
  float* aggIN = ws + 16450000;                 // 3.2M
  float* S1    = ws + 19650000;                 // 3.2M
  float* S2    = ws + 22850000;                 // 3.2M -> ends 26.05M
  // fill temps overlay agg regions (dead until phase B):
  uint2*    temp_h  = (uint2*)aggHw;                         // [10.05M,11.65M)
  unsigned* temp_in = (unsigned*)(aggHw + 1600000);          // [11.65M,12.45M)
  unsigned* temp_ss = (unsigned*)(aggHw + 2400000);          // [12.45M,13.25M)
  // phase D/E overlays (dead-before-write verified in stream order):
  unsigned short* S2b = (unsigned short*)aggHw;              // u0; aggHw dead after MM-C1
  unsigned short* u1b = (unsigned short*)(aggHw + 1600000);  // hop1 out; dead after hop2
  float*          aggSS = aggHw + 1600000;                   // phase E (after u1b dead)
  unsigned short* t1b = (unsigned short*)aggHu;              // aggHu dead after MM-C2
  unsigned short* t2b = (unsigned short*)(aggHu + 1600000);
  unsigned short* t3b = (unsigned short*)aggIN;              // aggIN dead after MM-C4
  unsigned short* S1b = (unsigned short*)(aggIN + 1600000);  // D2 shadow
  unsigned* payload_vv = (unsigned*)S1;                      // dead before MM-C1 writes S1
  unsigned short* u2b  = (unsigned short*)S1;                // hop2 out, read hop3, then MM-D1 overwrites S1
  int2*     eh         = (int2*)S2;                          // dead before MM-C2 writes S2
  int*      srcs_in    = (int*)(S2 + 1600000);

  const int* src_vv = ei_vv;  const int* dst_vv = ei_vv + E_VV;
  const int* src_h  = ei_h;   const int* dst_h  = ei_h + E_H;
  const int* src_in = ei_in;  const int* dst_in = ei_in + E_IN;
  const int* src_ss = ei_ss;  const int* dst_ss = ei_ss + E_SS;

  auto nblk = [](long long n) { return dim3((unsigned)((n + 255) / 256)); };
  const int NB64 = (NSV + 3) / 4;
  const int NB   = (NSV + 63) / 64;
  const int GC   = (ETOT + TC - 1) / TC;

  int* cnt_h  = cnt_all + H_ROW;
  int* cnt_in = cnt_all + IN_ROW;
  int* cnt_ss = cnt_all + SS_ROW;
  int* rs_vv  = rs_all;
  int* rs_h   = rs_all + H_ROW;
  int* rs_in  = rs_all + IN_ROW;
  int* rs_ss  = rs_all + SS_ROW;

  // ---- CSR build (fused) ----
  hipMemsetAsync(bcnt, 0, NBTOT * sizeof(int), stream);
  k_bucket_count<<<GC, 256, 0, stream>>>(dst_vv, dst_h, dst_in, dst_ss, bcnt);
  k_bucket_scan<<<1, 512, 0, stream>>>(bcnt, bbase, cb);
  k_fill_s1_all<<<SB1, 256, 0, stream>>>(src_vv, dst_vv, et_vv, src_h, dst_h, ew_h,
                                         src_in, dst_in, src_ss, dst_ss, cb,
                                         temp_vv, temp_h, temp_in, temp_ss);
  k_fill_s2_all<<<NBTOT, 256, 0, stream>>>(temp_vv, temp_h, temp_in, temp_ss, bbase,
                                           payload_vv, eh, srcs_in, srcs_ss,
                                           rs_all, cnt_all, game_x, x_pad, dinvS);

  // ---- Phase A: v-graph 5-dim ----
  k_vv_pass1<<<nblk(NVV), 256, 0, stream>>>(x_pad, rs_vv, cnt_all, payload_vv, ra4all, h1p);
  k_vv_hop<<<nblk(NVV), 256, 0, stream>>>(h1p, rs_vv, cnt_all, payload_vv, h2p);
  k_vv_hop<<<nblk(NVV), 256, 0, stream>>>(h2p, rs_vv, cnt_all, payload_vv, h3p);
  k_combine_gx<<<dim3((NVV + 31) / 32), 256, 0, stream>>>(x_pad, ra4all, h1p, h2p, h3p,
                                                          W1_rel, W1_root, b1, W12, b12, gx16);

  // ---- Phase B: fused 64-dim bf16 gathers ----
  k_aggB<<<2 * NB64, 256, 0, stream>>>(gx16, rs_h, cnt_h, eh, rs_in, cnt_in, srcs_in,
                                       aggHw, aggHu, aggIN, NB64);

  // ---- Phase C: graph_conv + 3x SAGE ----
  k_node_mm<<<NB, 256, 0, stream>>>(aggHw, 0, nullptr, W3_rel, state_x, 5, 0, W3_root, b3, S1, nullptr, nullptr, NSV, 1, 0);
  k_node_mm<<<NB, 256, 0, stream>>>(aggHu, 0, cnt_h,   W32_l, S1, 64, 0, W32_r, b32, S2, nullptr, nullptr, NSV, 1, 0);
  k_node_mm<<<NB, 256, 0, stream>>>(aggIN, 0, cnt_in,  W4_l,  S2, 64, 0, W4_r,  b4,  S1, nullptr, nullptr, NSV, 1, 0);
  k_node_mm<<<NB, 256, 0, stream>>>(aggIN, 0, cnt_in,  W42_l, S1, 64, 0, W42_r, b42, S2, S2b,     dinvS,   NSV, 1, 0);

  // ---- Phase D: TAG on s-s (prescaled bf16 hops) ----
  k_tag64b<<<NB64, 256, 0, stream>>>(S2b, rs_ss, cnt_ss, srcs_ss, dinvS, t1b, u1b, NSV);
  k_tag64b<<<NB64, 256, 0, stream>>>(u1b, rs_ss, cnt_ss, srcs_ss, dinvS, t2b, u2b, NSV);
  k_tag64b<<<NB64, 256, 0, stream>>>(u2b, rs_ss, cnt_ss, srcs_ss, dinvS, t3b, nullptr, NSV);
  k_node_mm<<<NB, 256, 0, stream>>>(S2, 0, nullptr, W2,        t1b, 64, 1, W2 + 4096,  b2,      S1, nullptr, nullptr, NSV, 0, 0);
  k_node_mm<<<NB, 256, 0, stream>>>(t2b, 1, nullptr, W2 + 8192, t3b, 64, 1, W2 + 12288, nullptr, S1, S1b,    nullptr, NSV, 1, 1);

  // ---- Phase E: SAGE on s-s ----
  k_agg64b<<<NB64, 256, 0, stream>>>(S1b, rs_ss, cnt_ss, srcs_ss, aggSS, NSV);
  k_node_mm<<<NB, 256, 0, stream>>>(aggSS, 0, cnt_ss, W5_l, S1, 64, 0, W5_r, b5, S2, nullptr, nullptr, NSV, 1, 0);

  // ---- Final projection ----
  k_final<<<nblk(NSV * 8), 256, 0, stream>>>(S2, Wl, bl, (float*)d_out);
}

// Round 11
// 675.638 us; speedup vs baseline: 5.0425x; 1.1083x over previous
//
#include <hip/hip_runtime.h>

#define NVV 100000
#define NSV 50000
#define E_VV 1600000
#define E_H  800000
#define E_IN 800000
#define E_SS 800000
#define ETOT 4000000
#define DIN 5
#define H_ROW 100000          // concatenated cnt/rs space: vv|h|in|ss
#define IN_ROW 150000
#define SS_ROW 200000
#define NROWS 250000
#define POS_H  E_VV
#define POS_IN (E_VV + E_H)
#define POS_SS (E_VV + E_H + E_IN)
#define NBUK 196              // vv buckets (dst >> 9)
#define NBUKS 98              // NSV-graph buckets
#define NBTOT 490             // vv|h|in|ss bucket space
#define BUK_H  196
#define BUK_IN 294
#define BUK_SS 392
#define BSHIFT 9
#define T1 4096               // edges per fill-stage-1 block
#define TC 16384              // edges per bucket-count block
#define G1VV 391              // ceil(E_VV/T1)
#define G1S  196              // ceil(E_H/T1)
#define SB1  (G1VV + 3 * G1S) // 979 fused stage-1 blocks

__device__ __forceinline__ unsigned short f2bf(float x) {
  unsigned b = __float_as_uint(x);
  return (unsigned short)((b + 0x7FFFu + ((b >> 16) & 1u)) >> 16);
}
__device__ __forceinline__ float bf2f(unsigned short u) {
  return __uint_as_float(((unsigned)u) << 16);
}

// ====================== CSR build: bucket counts -> bases -> fused binned fills ======================

__global__ __launch_bounds__(256)
void k_bucket_count(const int* __restrict__ d_vv, const int* __restrict__ d_h,
                    const int* __restrict__ d_in, const int* __restrict__ d_ss,
                    int* __restrict__ bcnt) {
  __shared__ int h[NBTOT];
  const int tid = threadIdx.x;
  for (int i = tid; i < NBTOT; i += 256) h[i] = 0;
  __syncthreads();
  const int base = blockIdx.x * TC;
#pragma unroll 4
  for (int k = 0; k < TC / 256; k++) {
    int e = base + k * 256 + tid;
    int bi = -1;
    if (e < E_VV) bi = d_vv[e] >> BSHIFT;
    else if (e < POS_IN) bi = BUK_H + (d_h[e - POS_H] >> BSHIFT);
    else if (e < POS_SS) bi = BUK_IN + (d_in[e - POS_IN] >> BSHIFT);
    else if (e < ETOT) bi = BUK_SS + (d_ss[e - POS_SS] >> BSHIFT);
    if (bi >= 0) atomicAdd(&h[bi], 1);
  }
  __syncthreads();
  for (int i = tid; i < NBTOT; i += 256) if (h[i]) atomicAdd(&bcnt[i], h[i]);
}

__global__ __launch_bounds__(512)
void k_bucket_scan(const int* __restrict__ bcnt, int* __restrict__ bbase, int* __restrict__ cb) {
  __shared__ int sd[512];
  int t = threadIdx.x;
  int v = (t < NBTOT) ? bcnt[t] : 0;
  sd[t] = v; __syncthreads();
  for (int off = 1; off < 512; off <<= 1) {
    int x = (t >= off) ? sd[t - off] : 0;
    __syncthreads();
    sd[t] += x;
    __syncthreads();
  }
  int segstart = (t < BUK_H) ? 0 : (t < BUK_IN) ? BUK_H : (t < BUK_SS) ? BUK_IN : BUK_SS;
  int excl = ((t > 0) ? sd[t - 1] : 0) - ((segstart > 0) ? sd[segstart - 1] : 0);
  if (t < NBTOT) { bbase[t] = excl; cb[t] = excl; }
}

// ---- fused stage 1: all 4 graphs, bucket-grouped binning, coalesced run writes ----
__global__ __launch_bounds__(256)
void k_fill_s1_all(const int* __restrict__ s_vv, const int* __restrict__ d_vv,
                   const int* __restrict__ et,
                   const int* __restrict__ s_h, const int* __restrict__ d_h,
                   const float* __restrict__ ew,
                   const int* __restrict__ s_in, const int* __restrict__ d_in,
                   const int* __restrict__ s_ss, const int* __restrict__ d_ss,
                   int* __restrict__ cb,
                   unsigned* __restrict__ temp_vv, uint2* __restrict__ temp_h,
                   unsigned* __restrict__ temp_in, unsigned* __restrict__ temp_ss) {
  __shared__ int hist[NBUK], lbase[NBUK], run[NBUK], gb[NBUK];
  __shared__ int sc[256];
  __shared__ unsigned stage[T1];
  __shared__ unsigned stageW[T1];
  __shared__ int gpos[T1];
  const int tid = threadIdx.x;
  const int b = blockIdx.x;
  int g, tile;
  if (b < G1VV) { g = 0; tile = b; }
  else if (b < G1VV + G1S) { g = 1; tile = b - G1VV; }
  else if (b < G1VV + 2 * G1S) { g = 2; tile = b - G1VV - G1S; }
  else { g = 3; tile = b - G1VV - 2 * G1S; }
  const int ne = (g == 0) ? E_VV : E_H;
  const int nbuk = (g == 0) ? NBUK : NBUKS;
  const int cboff = (g == 0) ? 0 : (g == 1) ? BUK_H : (g == 2) ? BUK_IN : BUK_SS;
  const int* S = (g == 0) ? s_vv : (g == 1) ? s_h : (g == 2) ? s_in : s_ss;
  const int* D = (g == 0) ? d_vv : (g == 1) ? d_h : (g == 2) ? d_in : d_ss;
  const int base = tile * T1;
  const int nvalid = min(T1, ne - base);
  for (int i = tid; i < nbuk; i += 256) { hist[i] = 0; run[i] = 0; }
  __syncthreads();
  int dv[16]; unsigned pk[16], pkw[16];
#pragma unroll
  for (int k = 0; k < 16; k++) {
    int e = base + k * 256 + tid;
    if (e - base < nvalid) {
      int d = D[e];
      dv[k] = d;
      if (g == 0) pk[k] = (unsigned)(((d & 511) << 19) | (et[e] << 17) | S[e]);
      else pk[k] = (unsigned)(((d & 511) << 17) | S[e]);
      if (g == 1) pkw[k] = (unsigned)__float_as_int(ew[e]);
      atomicAdd(&hist[d >> BSHIFT], 1);
    } else dv[k] = -1;
  }
  __syncthreads();
  int my = (tid < nbuk) ? hist[tid] : 0;
  sc[tid] = my; __syncthreads();
  for (int off = 1; off < 256; off <<= 1) {
    int t = (tid >= off) ? sc[tid - off] : 0;
    __syncthreads();
    sc[tid] += t;
    __syncthreads();
  }
  if (tid < nbuk) {
    lbase[tid] = sc[tid] - my;
    gb[tid] = my ? atomicAdd(&cb[cboff + tid], my) : 0;
  }
  __syncthreads();
#pragma unroll
  for (int k = 0; k < 16; k++) {
    if (dv[k] >= 0) {
      int bu = dv[k] >> BSHIFT;
      int loc = atomicAdd(&run[bu], 1);
      int li = lbase[bu] + loc;
      stage[li] = pk[k];
      if (g == 1) stageW[li] = pkw[k];
      gpos[li] = gb[bu] + loc;
    }
  }
  __syncthreads();
  if (g == 0)      for (int i = tid; i < nvalid; i += 256) temp_vv[gpos[i]] = stage[i];
  else if (g == 1) for (int i = tid; i < nvalid; i += 256) temp_h[gpos[i]] = make_uint2(stage[i], stageW[i]);
  else if (g == 2) for (int i = tid; i < nvalid; i += 256) temp_in[gpos[i]] = stage[i];
  else             for (int i = tid; i < nvalid; i += 256) temp_ss[gpos[i]] = stage[i];
}

// ---- fused stage 2: per-bucket LDS count+scan -> cnt/rs coalesced; in-window scatter;
//      epilogues fold prep_x (vv) and rsqrt_deg (ss) ----
__global__ __launch_bounds__(256)
void k_fill_s2_all(const unsigned* __restrict__ temp_vv, const uint2* __restrict__ temp_h,
                   const unsigned* __restrict__ temp_in, const unsigned* __restrict__ temp_ss,
                   const int* __restrict__ bbase,
                   unsigned* __restrict__ payload_vv, int2* __restrict__ eh,
                   int* __restrict__ srcs_in, int* __restrict__ srcs_ss,
                   int* __restrict__ rs_all, int* __restrict__ cnt_all,
                   const float* __restrict__ x, float4* __restrict__ xp,
                   float* __restrict__ dinvS) {
  __shared__ int lcnt[512], lpos[512];
  __shared__ int sc[256];
  const int b = blockIdx.x, tid = threadIdx.x;
  int g, lb;
  if (b < BUK_H) { g = 0; lb = b; }
  else if (b < BUK_IN) { g = 1; lb = b - BUK_H; }
  else if (b < BUK_SS) { g = 2; lb = b - BUK_IN; }
  else { g = 3; lb = b - BUK_SS; }
  const int d0 = lb << BSHIFT;
  const int nrows = (g == 0) ? NVV : NSV;
  const int rowbase = (g == 0) ? 0 : (g == 1) ? H_ROW : (g == 2) ? IN_ROW : SS_ROW;
  const int ne = (g == 0) ? E_VV : E_H;
  const int lastb = (g == 0) ? NBUK - 1 : NBUKS - 1;
  const int shift = (g == 0) ? 19 : 17;
  lcnt[tid] = 0; lcnt[tid + 256] = 0;
  __syncthreads();
  const int gstart = bbase[b];
  const int gend = (lb == lastb) ? ne : bbase[b + 1];
  if (g == 1) {
    for (int i = gstart + tid; i < gend; i += 256) atomicAdd(&lcnt[temp_h[i].x >> 17], 1);
  } else {
    const unsigned* tp = (g == 0) ? temp_vv : (g == 2) ? temp_in : temp_ss;
    for (int i = gstart + tid; i < gend; i += 256) atomicAdd(&lcnt[tp[i] >> shift], 1);
  }
  __syncthreads();
  int c0 = lcnt[2 * tid], c1 = lcnt[2 * tid + 1];
  int ps = c0 + c1;
  sc[tid] = ps; __syncthreads();
  for (int off = 1; off < 256; off <<= 1) {
    int x2 = (tid >= off) ? sc[tid - off] : 0;
    __syncthreads();
    sc[tid] += x2;
    __syncthreads();
  }
  int basep = gstart + sc[tid] - ps;
  lpos[2 * tid] = basep;
  lpos[2 * tid + 1] = basep + c0;
  __syncthreads();
  for (int d = tid; d < 512; d += 256) {
    int gd = d0 + d;
    if (gd < nrows) {
      rs_all[rowbase + gd] = lpos[d];
      cnt_all[rowbase + gd] = lcnt[d];
      if (g == 0) {
        float dc = (float)lcnt[d];
        float di = dc > 0.f ? rsqrtf(dc) : 0.f;
        const float* xr = x + (size_t)gd * 5;
        xp[gd * 2]     = make_float4(xr[0], xr[1], xr[2], xr[3]);
        xp[gd * 2 + 1] = make_float4(xr[4], di, 0.f, 0.f);
      } else if (g == 3) {
        float dc = (float)lcnt[d];
        dinvS[gd] = dc > 0.f ? rsqrtf(dc) : 0.f;
      }
    }
  }
  __syncthreads();
  if (g == 0) {
    for (int i = gstart + tid; i < gend; i += 256) {
      unsigned en = temp_vv[i];
      int pos = atomicAdd(&lpos[en >> 19], 1);
      payload_vv[pos] = en & 0x7FFFFu;
    }
  } else if (g == 1) {
    for (int i = gstart + tid; i < gend; i += 256) {
      uint2 en = temp_h[i];
      int pos = atomicAdd(&lpos[en.x >> 17], 1);
      eh[pos] = make_int2((int)(en.x & 0x1FFFFu), (int)en.y);
    }
  } else if (g == 2) {
    for (int i = gstart + tid; i < gend; i += 256) {
      unsigned en = temp_in[i];
      int pos = atomicAdd(&lpos[en >> 17], 1);
      srcs_in[pos] = (int)(en & 0x1FFFFu);
    }
  } else {
    for (int i = gstart + tid; i < gend; i += 256) {
      unsigned en = temp_ss[i];
      int pos = atomicAdd(&lpos[en >> 17], 1);
      srcs_ss[pos] = (int)(en & 0x1FFFFu);
    }
  }
}

// ====================== Phase A: v-graph (5-dim, padded rows) ======================

__global__ __launch_bounds__(256)
void k_vv_pass1(const float4* __restrict__ xp,
                const int* __restrict__ rowstart, const int* __restrict__ cnt,
                const unsigned* __restrict__ payload,
                float4* __restrict__ ra4all, float4* __restrict__ h1p) {
  int d = blockIdx.x * 256 + threadIdx.x;
  if (d >= NVV) return;
  int rs = rowstart[d], c = cnt[d];
  float a0[5] = {0,0,0,0,0}, a1[5] = {0,0,0,0,0}, a2[5] = {0,0,0,0,0}, h[5] = {0,0,0,0,0};
  float c0 = 0.f, c1 = 0.f, c2 = 0.f;
  int j = 0;
  for (; j + 2 <= c; j += 2) {
    unsigned pA = payload[rs + j], pB = payload[rs + j + 1];
    int sA = pA & 0x1FFFF, rA = pA >> 17;
    int sB = pB & 0x1FFFF, rB = pB >> 17;
    float4 xA0 = xp[sA * 2], xA1 = xp[sA * 2 + 1];
    float4 xB0 = xp[sB * 2], xB1 = xp[sB * 2 + 1];
    float xsA[5] = {xA0.x, xA0.y, xA0.z, xA0.w, xA1.x};
    float xsB[5] = {xB0.x, xB0.y, xB0.z, xB0.w, xB1.x};
    float wA = xA1.y, wB = xB1.y;
    float mA0 = (rA == 0) ? 1.f : 0.f, mA1 = (rA == 1) ? 1.f : 0.f, mA2 = (rA == 2) ? 1.f : 0.f;
    float mB0 = (rB == 0) ? 1.f : 0.f, mB1 = (rB == 1) ? 1.f : 0.f, mB2 = (rB == 2) ? 1.f : 0.f;
    c0 += mA0 + mB0; c1 += mA1 + mB1; c2 += mA2 + mB2;
#pragma unroll
    for (int k = 0; k < 5; k++) {
      h[k] += wA * xsA[k] + wB * xsB[k];
      a0[k] += mA0 * xsA[k] + mB0 * xsB[k];
      a1[k] += mA1 * xsA[k] + mB1 * xsB[k];
      a2[k] += mA2 * xsA[k] + mB2 * xsB[k];
    }
  }
  for (; j < c; j++) {
    unsigned p = payload[rs + j];
    int s = p & 0x1FFFF, r = p >> 17;
    float4 x0 = xp[s * 2], x1 = xp[s * 2 + 1];
    float xs[5] = {x0.x, x0.y, x0.z, x0.w, x1.x};
    float wsc = x1.y;
    float m0 = (r == 0) ? 1.f : 0.f, m1 = (r == 1) ? 1.f : 0.f, m2 = (r == 2) ? 1.f : 0.f;
    c0 += m0; c1 += m1; c2 += m2;
#pragma unroll
    for (int k = 0; k < 5; k++) {
      h[k] += wsc * xs[k];
      a0[k] += m0 * xs[k]; a1[k] += m1 * xs[k]; a2[k] += m2 * xs[k];
    }
  }
  float dv = xp[d * 2 + 1].y;
  float4* ra4 = ra4all + d * 5;
  ra4[0] = make_float4(a0[0], a0[1], a0[2], a0[3]);
  ra4[1] = make_float4(a0[4], a1[0], a1[1], a1[2]);
  ra4[2] = make_float4(a1[3], a1[4], a2[0], a2[1]);
  ra4[3] = make_float4(a2[2], a2[3], a2[4], c0);
  ra4[4] = make_float4(c1, c2, 0.f, 0.f);
  h1p[d * 2]     = make_float4(dv * h[0], dv * h[1], dv * h[2], dv * h[3]);
  h1p[d * 2 + 1] = make_float4(dv * h[4], dv, 0.f, 0.f);
}

__global__ __launch_bounds__(256)
void k_vv_hop(const float4* __restrict__ hinp,
              const int* __restrict__ rowstart, const int* __restrict__ cnt,
              const unsigned* __restrict__ payload, float4* __restrict__ houtp) {
  int d = blockIdx.x * 256 + threadIdx.x;
  if (d >= NVV) return;
  int rs = rowstart[d], c = cnt[d];
  float h[5] = {0,0,0,0,0};
  int j = 0;
  for (; j + 4 <= c; j += 4) {
    unsigned p0 = payload[rs + j], p1 = payload[rs + j + 1];
    unsigned p2 = payload[rs + j + 2], p3 = payload[rs + j + 3];
    int s0 = p0 & 0x1FFFF, s1 = p1 & 0x1FFFF, s2 = p2 & 0x1FFFF, s3 = p3 & 0x1FFFF;
    float4 a0 = hinp[s0 * 2], b0 = hinp[s0 * 2 + 1];
    float4 a1 = hinp[s1 * 2], b1 = hinp[s1 * 2 + 1];
    float4 a2 = hinp[s2 * 2], b2 = hinp[s2 * 2 + 1];
    float4 a3 = hinp[s3 * 2], b3 = hinp[s3 * 2 + 1];
    float w0 = b0.y, w1 = b1.y, w2 = b2.y, w3 = b3.y;
    h[0] += w0 * a0.x + w1 * a1.x + w2 * a2.x + w3 * a3.x;
    h[1] += w0 * a0.y + w1 * a1.y + w2 * a2.y + w3 * a3.y;
    h[2] += w0 * a0.z + w1 * a1.z + w2 * a2.z + w3 * a3.z;
    h[3] += w0 * a0.w + w1 * a1.w + w2 * a2.w + w3 * a3.w;
    h[4] += w0 * b0.x + w1 * b1.x + w2 * b2.x + w3 * b3.x;
  }
  for (; j < c; j++) {
    int s = payload[rs + j] & 0x1FFFF;
    float4 x0 = hinp[s * 2], x1 = hinp[s * 2 + 1];
    float wsc = x1.y;
    h[0] += wsc * x0.x; h[1] += wsc * x0.y; h[2] += wsc * x0.z; h[3] += wsc * x0.w;
    h[4] += wsc * x1.x;
  }
  float dv = hinp[d * 2 + 1].y;
  houtp[d * 2]     = make_float4(dv * h[0], dv * h[1], dv * h[2], dv * h[3]);
  houtp[d * 2 + 1] = make_float4(dv * h[4], dv, 0.f, 0.f);
}

// 8 nodes/thread, Ws column in 35 VGPRs, float4 relall loads.
__global__ __launch_bounds__(256)
void k_combine_gx(const float4* __restrict__ xp,
                  const float4* __restrict__ ra4all,
                  const float4* __restrict__ h1p, const float4* __restrict__ h2p,
                  const float4* __restrict__ h3p,
                  const float* __restrict__ W1_rel, const float* __restrict__ W1_root,
                  const float* __restrict__ b1,
                  const float* __restrict__ W12, const float* __restrict__ b12,
                  unsigned short* __restrict__ gx16) {
  __shared__ float Ws[7 * 320];
  __shared__ float bs[64];
  int tid = threadIdx.x;
  for (int i = tid; i < 320; i += 256) {
    Ws[i]        = W1_root[i] + W12[i];
    Ws[320 + i]  = W1_rel[i];
    Ws[640 + i]  = W1_rel[320 + i];
    Ws[960 + i]  = W1_rel[640 + i];
    Ws[1280 + i] = W12[320 + i];
    Ws[1600 + i] = W12[640 + i];
    Ws[1920 + i] = W12[960 + i];
  }
  if (tid < 64) bs[tid] = b1[tid] + b12[tid];
  __syncthreads();
  const int f = tid & 63;
  const int grp = tid >> 6;
  float wcol[35];
#pragma unroll
  for (int t = 0; t < 35; t++) wcol[t] = Ws[t * 64 + f];
  const float bias = bs[f];
  const int v0 = blockIdx.x * 32 + grp * 8;
  for (int n = 0; n < 8; n++) {
    int v = v0 + n;
    if (v >= NVV) return;
    float in[35];
    {
      float4 x0 = xp[v * 2], x1 = xp[v * 2 + 1];
      in[0] = x0.x; in[1] = x0.y; in[2] = x0.z; in[3] = x0.w; in[4] = x1.x;
    }
    {
      const float4* ra = ra4all + v * 5;
      float4 r0 = ra[0], r1 = ra[1], r2 = ra[2], r3 = ra[3], r4 = ra[4];
      float i0 = 1.0f / fmaxf(r3.w, 1.0f);
      float i1 = 1.0f / fmaxf(r4.x, 1.0f);
      float i2 = 1.0f / fmaxf(r4.y, 1.0f);
      in[5]  = r0.x * i0; in[6]  = r0.y * i0; in[7]  = r0.z * i0; in[8]  = r0.w * i0; in[9]  = r1.x * i0;
      in[10] = r1.y * i1; in[11] = r1.z * i1; in[12] = r1.w * i1; in[13] = r2.x * i1; in[14] = r2.y * i1;
      in[15] = r2.z * i2; in[16] = r2.w * i2; in[17] = r3.x * i2; in[18] = r3.y * i2; in[19] = r3.z * i2;
    }
    {
      float4 a = h1p[v * 2], b = h1p[v * 2 + 1];
      in[20] = a.x; in[21] = a.y; in[22] = a.z; in[23] = a.w; in[24] = b.x;
      a = h2p[v * 2]; b = h2p[v * 2 + 1];
      in[25] = a.x; in[26] = a.y; in[27] = a.z; in[28] = a.w; in[29] = b.x;
      a = h3p[v * 2]; b = h3p[v * 2 + 1];
      in[30] = a.x; in[31] = a.y; in[32] = a.z; in[33] = a.w; in[34] = b.x;
    }
    float acc = bias;
#pragma unroll
    for (int t = 0; t < 35; t++) acc += in[t] * wcol[t];
    gx16[v * 64 + f] = f2bf(acc);
  }
}

// ================= 64-dim CSR gathers (wave per dst, lane=feature, 8-way MLP) =================

__global__ __launch_bounds__(256)
void k_aggB(const unsigned short* __restrict__ X16,
            const int* __restrict__ rs_h, const int* __restrict__ cnt_h,
            const int2* __restrict__ eh,
            const int* __restrict__ rs_in, const int* __restrict__ cnt_in,
            const int* __restrict__ srcs_in,
            float* __restrict__ outw, float* __restrict__ outu, float* __restrict__ outIN,
            int nb64) {
  int bb = blockIdx.x;
  int lane = threadIdx.x & 63;
  if (bb < nb64) {
    int wid = bb * 4 + (threadIdx.x >> 6);
    if (wid >= NSV) return;
    int rs = rs_h[wid], c = cnt_h[wid];
    float aw = 0.f, au = 0.f;
    int j = 0;
    for (; j + 8 <= c; j += 8) {
      int2 p0 = eh[rs + j],     p1 = eh[rs + j + 1], p2 = eh[rs + j + 2], p3 = eh[rs + j + 3];
      int2 p4 = eh[rs + j + 4], p5 = eh[rs + j + 5], p6 = eh[rs + j + 6], p7 = eh[rs + j + 7];
      float v0 = bf2f(X16[p0.x * 64 + lane]);
      float v1 = bf2f(X16[p1.x * 64 + lane]);
      float v2 = bf2f(X16[p2.x * 64 + lane]);
      float v3 = bf2f(X16[p3.x * 64 + lane]);
      float v4 = bf2f(X16[p4.x * 64 + lane]);
      float v5 = bf2f(X16[p5.x * 64 + lane]);
      float v6 = bf2f(X16[p6.x * 64 + lane]);
      float v7 = bf2f(X16[p7.x * 64 + lane]);
      au += ((v0 + v1) + (v2 + v3)) + ((v4 + v5) + (v6 + v7));
      aw += __int_as_float(p0.y) * v0 + __int_as_float(p1.y) * v1
          + __int_as_float(p2.y) * v2 + __int_as_float(p3.y) * v3
          + __int_as_float(p4.y) * v4 + __int_as_float(p5.y) * v5
          + __int_as_float(p6.y) * v6 + __int_as_float(p7.y) * v7;
    }
    for (; j < c; j++) {
      int2 p = eh[rs + j];
      float v = bf2f(X16[p.x * 64 + lane]);
      au += v; aw += __int_as_float(p.y) * v;
    }
    outw[wid * 64 + lane] = aw;
    outu[wid * 64 + lane] = au;
  } else {
    int wid = (bb - nb64) * 4 + (threadIdx.x >> 6);
    if (wid >= NSV) return;
    int rs = rs_in[wid], c = cnt_in[wid];
    float a = 0.f;
    int j = 0;
    for (; j + 8 <= c; j += 8) {
      int s0 = srcs_in[rs + j],     s1 = srcs_in[rs + j + 1], s2 = srcs_in[rs + j + 2], s3 = srcs_in[rs + j + 3];
      int s4 = srcs_in[rs + j + 4], s5 = srcs_in[rs + j + 5], s6 = srcs_in[rs + j + 6], s7 = srcs_in[rs + j + 7];
      float v0 = bf2f(X16[s0 * 64 + lane]);
      float v1 = bf2f(X16[s1 * 64 + lane]);
      float v2 = bf2f(X16[s2 * 64 + lane]);
      float v3 = bf2f(X16[s3 * 64 + lane]);
      float v4 = bf2f(X16[s4 * 64 + lane]);
      float v5 = bf2f(X16[s5 * 64 + lane]);
      float v6 = bf2f(X16[s6 * 64 + lane]);
      float v7 = bf2f(X16[s7 * 64 + lane]);
      a += ((v0 + v1) + (v2 + v3)) + ((v4 + v5) + (v6 + v7));
    }
    for (; j < c; j++) a += bf2f(X16[srcs_in[rs + j] * 64 + lane]);
    outIN[wid * 64 + lane] = a;
  }
}

__global__ __launch_bounds__(256)
void k_agg64b(const unsigned short* __restrict__ X16,
              const int* __restrict__ rowstart, const int* __restrict__ cnt,
              const int* __restrict__ srcs, float* __restrict__ out, int n) {
  int wid = blockIdx.x * 4 + (threadIdx.x >> 6);
  if (wid >= n) return;
  int lane = threadIdx.x & 63;
  int rs = rowstart[wid], c = cnt[wid];
  float a = 0.f;
  int j = 0;
  for (; j + 8 <= c; j += 8) {
    int s0 = srcs[rs + j],     s1 = srcs[rs + j + 1], s2 = srcs[rs + j + 2], s3 = srcs[rs + j + 3];
    int s4 = srcs[rs + j + 4], s5 = srcs[rs + j + 5], s6 = srcs[rs + j + 6], s7 = srcs[rs + j + 7];
    float v0 = bf2f(X16[s0 * 64 + lane]);
    float v1 = bf2f(X16[s1 * 64 + lane]);
    float v2 = bf2f(X16[s2 * 64 + lane]);
    float v3 = bf2f(X16[s3 * 64 + lane]);
    float v4 = bf2f(X16[s4 * 64 + lane]);
    float v5 = bf2f(X16[s5 * 64 + lane]);
    float v6 = bf2f(X16[s6 * 64 + lane]);
    float v7 = bf2f(X16[s7 * 64 + lane]);
    a += ((v0 + v1) + (v2 + v3)) + ((v4 + v5) + (v6 + v7));
  }
  for (; j < c; j++) a += bf2f(X16[srcs[rs + j] * 64 + lane]);
  out[wid * 64 + lane] = a;
}

// prescaled TAG hop: U = dinv ⊙ t (bf16). t_out = dinv[d]*Σ U[s]; u_out = dinv[d]*t_out.
__global__ __launch_bounds__(256)
void k_tag64b(const unsigned short* __restrict__ U16,
              const int* __restrict__ rowstart, const int* __restrict__ cnt,
              const int* __restrict__ srcs, const float* __restrict__ dinv,
              unsigned short* __restrict__ t_out, unsigned short* __restrict__ u_out, int n) {
  int wid = blockIdx.x * 4 + (threadIdx.x >> 6);
  if (wid >= n) return;
  int lane = threadIdx.x & 63;
  int rs = rowstart[wid], c = cnt[wid];
  float a = 0.f;
  int j = 0;
  for (; j + 8 <= c; j += 8) {
    int s0 = srcs[rs + j],     s1 = srcs[rs + j + 1], s2 = srcs[rs + j + 2], s3 = srcs[rs + j + 3];
    int s4 = srcs[rs + j + 4], s5 = srcs[rs + j + 5], s6 = srcs[rs + j + 6], s7 = srcs[rs + j + 7];
    float v0 = bf2f(U16[s0 * 64 + lane]);
    float v1 = bf2f(U16[s1 * 64 + lane]);
    float v2 = bf2f(U16[s2 * 64 + lane]);
    float v3 = bf2f(U16[s3 * 64 + lane]);
    float v4 = bf2f(U16[s4 * 64 + lane]);
    float v5 = bf2f(U16[s5 * 64 + lane]);
    float v6 = bf2f(U16[s6 * 64 + lane]);
    float v7 = bf2f(U16[s7 * 64 + lane]);
    a += ((v0 + v1) + (v2 + v3)) + ((v4 + v5) + (v6 + v7));
  }
  for (; j < c; j++) a += bf2f(U16[srcs[rs + j] * 64 + lane]);
  float dv = dinv[wid];
  float t = dv * a;
  t_out[wid * 64 + lane] = f2bf(t);
  if (u_out) u_out[wid * 64 + lane] = f2bf(dv * t);
}

// ====================== Fused MM building blocks ======================

__device__ __forceinline__ void mm_zero(float acc[4][4]) {
#pragma unroll
  for (int j = 0; j < 4; j++)
#pragma unroll
    for (int jj = 0; jj < 4; jj++) acc[j][jj] = 0.f;
}

__device__ __forceinline__ void mm_acc(const float* sA, const float* sW, int K,
                                       int nl0, int f0, float acc[4][4]) {
  for (int k = 0; k < K; k++) {
    float4 w = *(const float4*)(&sW[k * 64 + f0]);
#pragma unroll
    for (int j = 0; j < 4; j++) {
      float a = sA[(nl0 + j) * 68 + k];
      acc[j][0] += a * w.x; acc[j][1] += a * w.y; acc[j][2] += a * w.z; acc[j][3] += a * w.w;
    }
  }
}

__device__ __forceinline__ void mm_loadw(float* Ws, const float* W, int tid) {
  const float4* w4 = (const float4*)W;
  float4* s4 = (float4*)Ws;
  for (int i = tid; i < 1024; i += 256) s4[i] = w4[i];
}

__device__ __forceinline__ void mm_stage_f32(float* as, const float* A, const int* cntA,
                                             int gb, int n, int tid) {
  for (int i = tid; i < 1024; i += 256) {
    int nl = i >> 4, k4 = i & 15;
    int g = gb + nl;
    float4 v = make_float4(0.f, 0.f, 0.f, 0.f);
    if (g < n) {
      v = ((const float4*)A)[g * 16 + k4];
      if (cntA) {
        float sc = 1.0f / fmaxf((float)cntA[g], 1.0f);
        v.x *= sc; v.y *= sc; v.z *= sc; v.w *= sc;
      }
    }
    *(float4*)(&as[nl * 68 + k4 * 4]) = v;
  }
}

__device__ __forceinline__ void mm_stage_bf16(float* as, const unsigned short* A,
                                              int gb, int n, int tid) {
  for (int i = tid; i < 1024; i += 256) {
    int nl = i >> 4, k4 = i & 15;
    int g = gb + nl;
    float4 v = make_float4(0.f, 0.f, 0.f, 0.f);
    if (g < n) {
      uint2 u = ((const uint2*)(A + (size_t)g * 64))[k4];
      v.x = bf2f((unsigned short)(u.x & 0xFFFF));
      v.y = bf2f((unsigned short)(u.x >> 16));
      v.z = bf2f((unsigned short)(u.y & 0xFFFF));
      v.w = bf2f((unsigned short)(u.y >> 16));
    }
    *(float4*)(&as[nl * 68 + k4 * 4]) = v;
  }
}

// ---- phase-C chain: S2 = relu(aggIN'@W42_l + relu(aggIN'@W4_l + relu(aggHu'@W32_l +
//      relu(aggHw@W3_rel + sx@W3_root + b3)@W32_r + b32)@W4_r + b4)@W42_r + b42) ----
__global__ __launch_bounds__(256)
void k_mm_chainC(const float* __restrict__ aggHw, const float* __restrict__ state_x,
                 const float* __restrict__ aggHu, const int* __restrict__ cnt_h,
                 const float* __restrict__ aggIN, const int* __restrict__ cnt_in,
                 const float* __restrict__ W3_rel, const float* __restrict__ W3_root,
                 const float* __restrict__ b3,
                 const float* __restrict__ W32_l, const float* __restrict__ W32_r,
                 const float* __restrict__ b32,
                 const float* __restrict__ W4_l, const float* __restrict__ W4_r,
                 const float* __restrict__ b4,
                 const float* __restrict__ W42_l, const float* __restrict__ W42_r,
                 const float* __restrict__ b42,
                 float* __restrict__ S2out, unsigned short* __restrict__ S2b,
                 const float* __restrict__ dinvS, int n) {
  __shared__ float Ws[4096];
  __shared__ float as[64 * 68];
  __shared__ float cs[64 * 68];
  const int tid = threadIdx.x;
  const int gb = blockIdx.x * 64;
  const int lane = tid & 63;
  const int fq = lane & 15, nq = lane >> 4;
  const int f0 = fq * 4;
  const int nl0 = (tid >> 6) * 16 + nq * 4;
  float acc[4][4];

  // --- C1: aggHw@W3_rel + state_x@W3_root + b3, relu -> cs ---
  mm_loadw(Ws, W3_rel, tid);
  mm_stage_f32(as, aggHw, nullptr, gb, n, tid);
  __syncthreads();
  mm_zero(acc);
  mm_acc(as, Ws, 64, nl0, f0, acc);
  __syncthreads();
  for (int i = tid; i < 320; i += 256) {
    int nl = i / 5, k = i - nl * 5;
    int g = gb + nl;
    as[nl * 68 + k] = (g < n) ? state_x[(size_t)g * 5 + k] : 0.f;
  }
  for (int i = tid; i < 320; i += 256) Ws[i] = W3_root[i];
  __syncthreads();
  mm_acc(as, Ws, 5, nl0, f0, acc);
#pragma unroll
  for (int j = 0; j < 4; j++)
#pragma unroll
    for (int jj = 0; jj < 4; jj++)
      cs[(nl0 + j) * 68 + f0 + jj] = fmaxf(acc[j][jj] + b3[f0 + jj], 0.f);
  __syncthreads();

  // --- C2: aggHu'@W32_l + cs@W32_r + b32, relu -> cs ---
  mm_loadw(Ws, W32_l, tid);
  mm_stage_f32(as, aggHu, cnt_h, gb, n, tid);
  __syncthreads();
  mm_zero(acc);
  mm_acc(as, Ws, 64, nl0, f0, acc);
  __syncthreads();
  mm_loadw(Ws, W32_r, tid);
  __syncthreads();
  mm_acc(cs, Ws, 64, nl0, f0, acc);
  __syncthreads();
#pragma unroll
  for (int j = 0; j < 4; j++)
#pragma unroll
    for (int jj = 0; jj < 4; jj++)
      cs[(nl0 + j) * 68 + f0 + jj] = fmaxf(acc[j][jj] + b32[f0 + jj], 0.f);
  __syncthreads();

  // --- C3: aggIN'@W4_l + cs@W4_r + b4, relu -> cs ---
  mm_loadw(Ws, W4_l, tid);
  mm_stage_f32(as, aggIN, cnt_in, gb, n, tid);
  __syncthreads();
  mm_zero(acc);
  mm_acc(as, Ws, 64, nl0, f0, acc);
  __syncthreads();
  mm_loadw(Ws, W4_r, tid);
  __syncthreads();
  mm_acc(cs, Ws, 64, nl0, f0, acc);
  __syncthreads();
#pragma unroll
  for (int j = 0; j < 4; j++)
#pragma unroll
    for (int jj = 0; jj < 4; jj++)
      cs[(nl0 + j) * 68 + f0 + jj] = fmaxf(acc[j][jj] + b4[f0 + jj], 0.f);
  __syncthreads();

  // --- C4: aggIN'@W42_l + cs@W42_r + b42, relu -> S2 + S2b(dinv-scaled) ---
  mm_loadw(Ws, W42_l, tid);
  mm_stage_f32(as, aggIN, cnt_in, gb, n, tid);
  __syncthreads();
  mm_zero(acc);
  mm_acc(as, Ws, 64, nl0, f0, acc);
  __syncthreads();
  mm_loadw(Ws, W42_r, tid);
  __syncthreads();
  mm_acc(cs, Ws, 64, nl0, f0, acc);
#pragma unroll
  for (int j = 0; j < 4; j++) {
    int g = gb + nl0 + j;
    if (g < n) {
      float osc = dinvS[g];
#pragma unroll
      for (int jj = 0; jj < 4; jj++) {
        int f = f0 + jj;
        float v = fmaxf(acc[j][jj] + b42[f], 0.f);
        S2out[(size_t)g * 64 + f] = v;
        S2b[(size_t)g * 64 + f] = f2bf(v * osc);
      }
    }
  }
}

// ---- phase-D quad MM: S1 = relu(S2@W2_0 + t1@W2_1 + t2@W2_2 + t3@W2_3 + b2); S1b = bf16 ----
__global__ __launch_bounds__(256)
void k_mm_d(const float* __restrict__ S2, const unsigned short* __restrict__ t1b,
            const unsigned short* __restrict__ t2b, const unsigned short* __restrict__ t3b,
            const float* __restrict__ W2, const float* __restrict__ b2,
            float* __restrict__ S1, unsigned short* __restrict__ S1b, int n) {
  __shared__ float Ws[4096];
  __shared__ float as[64 * 68];
  const int tid = threadIdx.x;
  const int gb = blockIdx.x * 64;
  const int lane = tid & 63;
  const int fq = lane & 15, nq = lane >> 4;
  const int f0 = fq * 4;
  const int nl0 = (tid >> 6) * 16 + nq * 4;
  float acc[4][4];
  mm_zero(acc);
  // op 0: S2 (f32)
  mm_loadw(Ws, W2, tid);
  mm_stage_f32(as, S2, nullptr, gb, n, tid);
  __syncthreads();
  mm_acc(as, Ws, 64, nl0, f0, acc);
  __syncthreads();
  // op 1: t1 (bf16)
  mm_loadw(Ws, W2 + 4096, tid);
  mm_stage_bf16(as, t1b, gb, n, tid);
  __syncthreads();
  mm_acc(as, Ws, 64, nl0, f0, acc);
  __syncthreads();
  // op 2: t2 (bf16)
  mm_loadw(Ws, W2 + 8192, tid);
  mm_stage_bf16(as, t2b, gb, n, tid);
  __syncthreads();
  mm_acc(as, Ws, 64, nl0, f0, acc);
  __syncthreads();
  // op 3: t3 (bf16)
  mm_loadw(Ws, W2 + 12288, tid);
  mm_stage_bf16(as, t3b, gb, n, tid);
  __syncthreads();
  mm_acc(as, Ws, 64, nl0, f0, acc);
#pragma unroll
  for (int j = 0; j < 4; j++) {
    int g = gb + nl0 + j;
    if (g < n) {
#pragma unroll
      for (int jj = 0; jj < 4; jj++) {
        int f = f0 + jj;
        float v = fmaxf(acc[j][jj] + b2[f], 0.f);
        S1[(size_t)g * 64 + f] = v;
        S1b[(size_t)g * 64 + f] = f2bf(v);
      }
    }
  }
}

// ---- phase-E MM + final projection: out = relu(aggSS'@W5_l + S1@W5_r + b5) @ Wl + bl ----
__global__ __launch_bounds__(256)
void k_mm_e(const float* __restrict__ aggSS, const int* __restrict__ cnt_ss,
            const float* __restrict__ W5_l, const float* __restrict__ S1,
            const float* __restrict__ W5_r, const float* __restrict__ b5,
            const float* __restrict__ Wl, const float* __restrict__ bl,
            float* __restrict__ out, int n) {
  __shared__ float Ws[4096];
  __shared__ float as[64 * 68];
  __shared__ float cs[64 * 68];
  const int tid = threadIdx.x;
  const int gb = blockIdx.x * 64;
  const int lane = tid & 63;
  const int fq = lane & 15, nq = lane >> 4;
  const int f0 = fq * 4;
  const int nl0 = (tid >> 6) * 16 + nq * 4;
  float acc[4][4];
  mm_zero(acc);
  mm_loadw(Ws, W5_l, tid);
  mm_stage_f32(as, aggSS, cnt_ss, gb, n, tid);
  __syncthreads();
  mm_acc(as, Ws, 64, nl0, f0, acc);
  __syncthreads();
  mm_loadw(Ws, W5_r, tid);
  mm_stage_f32(cs, S1, nullptr, gb, n, tid);
  __syncthreads();
  mm_acc(cs, Ws, 64, nl0, f0, acc);
  // stage relu'd result into as, then project 64->8
  __syncthreads();
#pragma unroll
  for (int j = 0; j < 4; j++)
#pragma unroll
    for (int jj = 0; jj < 4; jj++)
      as[(nl0 + j) * 68 + f0 + jj] = fmaxf(acc[j][jj] + b5[f0 + jj], 0.f);
  for (int i = tid; i < 512; i += 256) Ws[i] = Wl[i];
  __syncthreads();
#pragma unroll
  for (int q = 0; q < 2; q++) {
    int idx = tid * 2 + q;
    int nl = idx >> 3, o = idx & 7;
    int g = gb + nl;
    if (g < n) {
      float a2 = bl[o];
#pragma unroll 8
      for (int k = 0; k < 64; k++) a2 += as[nl * 68 + k] * Ws[k * 8 + o];
      out[(size_t)g * 8 + o] = a2;
    }
  }
}

// ---------------- Host ----------------

extern "C" void kernel_launch(void* const* d_in, const int* in_sizes, int n_in,
                              void* d_out, int out_size, void* d_ws, size_t ws_size,
                              hipStream_t stream) {
  const float* game_x  = (const float*)d_in[0];
  const float* state_x = (const float*)d_in[1];
  const int*   ei_vv   = (const int*)d_in[2];
  const int*   et_vv   = (const int*)d_in[3];
  const int*   ei_h    = (const int*)d_in[4];
  const float* ew_h    = (const float*)d_in[5];
  const int*   ei_in   = (const int*)d_in[6];
  const int*   ei_ss   = (const int*)d_in[7];
  const float* W1_rel  = (const float*)d_in[8];
  const float* W1_root = (const float*)d_in[9];
  const float* b1      = (const float*)d_in[10];
  const float* W12     = (const float*)d_in[11];
  const float* b12     = (const float*)d_in[12];
  const float* W2      = (const float*)d_in[13];
  const float* b2      = (const float*)d_in[14];
  const float* W3_rel  = (const float*)d_in[15];
  const float* W3_root = (const float*)d_in[16];
  const float* b3      = (const float*)d_in[17];
  const float* W32_l   = (const float*)d_in[18];
  const float* W32_r   = (const float*)d_in[19];
  const float* b32     = (const float*)d_in[20];
  const float* W4_l    = (const float*)d_in[21];
  const float* W4_r    = (const float*)d_in[22];
  const float* b4      = (const float*)d_in[23];
  const float* W42_l   = (const float*)d_in[24];
  const float* W42_r   = (const float*)d_in[25];
  const float* b42     = (const float*)d_in[26];
  const float* W5_l    = (const float*)d_in[27];
  const float* W5_r    = (const float*)d_in[28];
  const float* b5      = (const float*)d_in[29];
  const float* Wl      = (const float*)d_in[30];
  const float* bl      = (const float*)d_in[31];

  // Workspace (4B slots), peak 26.05M slots = 104.2 MiB.
  float* ws = (float*)d_ws;
  int*   cnt_all = (int*)(ws + 0);              // 250K (vv|h|in|ss)
  int*   rs_all  = (int*)(ws + 250000);         // 250K (graph-local values)
  int*   bcnt    = (int*)(ws + 500000);         // 512
  int*   bbase   = (int*)(ws + 500512);         // 512
  int*   cb      = (int*)(ws + 501024);         // 512
  int*   srcs_ss = (int*)(ws + 760000);         // 0.8M  (lives through phase E)
  float4* x_pad  = (float4*)(ws + 1600000);     // 800K
  float4* h1p    = (float4*)(ws + 2400000);
  float4* h2p    = (float4*)(ws + 3200000);
  float4* h3p    = (float4*)(ws + 4000000);
  float4* ra4all = (float4*)(ws + 4800000);     // [NVV][5] float4 = 2.0M slots -> 6.8M
  float* dinvS   = ws + 6800000;                // 50K
  unsigned short* gx16 = (unsigned short*)(ws + 6850000);  // 3.2M slots -> 10.05M
  unsigned* temp_vv    = (unsigned*)(ws + 6850000);        // 1.6M, overlays gx16 front (dead before combine)
  float* aggHw = ws + 10050000;                 // 3.2M
  float* aggHu = ws + 13250000;                 // 3.2M
  float* aggIN = ws + 16450000;                 // 3.2M
  float* S1    = ws + 19650000;                 // 3.2M
  float* S2    = ws + 22850000;                 // 3.2M -> ends 26.05M
  // fill temps overlay agg regions (dead until phase B):
  uint2*    temp_h  = (uint2*)aggHw;
  unsigned* temp_in = (unsigned*)(aggHw + 1600000);
  unsigned* temp_ss = (unsigned*)(aggHw + 2400000);
  // overlays (dead-before-write verified in stream order; chainC writes S2b must NOT
  // alias any of its own inputs -> S2b lives in the ra4all region, dead after combine_gx):
  unsigned short* S2b = (unsigned short*)(ws + 4800000);     // 1.6M slots of ra4all's 2.0M
  unsigned short* u1b = (unsigned short*)(aggHw + 1600000);  // hop1 aux; aggHw dead after chainC
  float*          aggSS = aggHw + 1600000;                   // phase E (after u1b dead)
  unsigned short* t1b = (unsigned short*)aggHu;              // aggHu dead after chainC
  unsigned short* t2b = (unsigned short*)(aggHu + 1600000);
  unsigned short* t3b = (unsigned short*)aggIN;              // aggIN dead after chainC
  unsigned short* S1b = (unsigned short*)(aggIN + 1600000);  // k_mm_d shadow
  unsigned* payload_vv = (unsigned*)S1;                      // dead after phase A
  unsigned short* u2b  = (unsigned short*)S1;                // hop2 aux; S1 written later by k_mm_d
  int2*     eh         = (int2*)S2;                          // dead after aggB; S2 written by chainC
  int*      srcs_in    = (int*)(S2 + 1600000);

  const int* src_vv = ei_vv;  const int* dst_vv = ei_vv + E_VV;
  const int* src_h  = ei_h;   const int* dst_h  = ei_h + E_H;
  const int* src_in = ei_in;  const int* dst_in = ei_in + E_IN;
  const int* src_ss = ei_ss;  const int* dst_ss = ei_ss + E_SS;

  auto nblk = [](long long n) { return dim3((unsigned)((n + 255) / 256)); };
  const int NB64 = (NSV + 3) / 4;
  const int NB   = (NSV + 63) / 64;
  const int GC   = (ETOT + TC - 1) / TC;

  int* cnt_h  = cnt_all + H_ROW;
  int* cnt_in = cnt_all + IN_ROW;
  int* cnt_ss = cnt_all + SS_ROW;
  int* rs_vv  = rs_all;
  int* rs_h   = rs_all + H_ROW;
  int* rs_in  = rs_all + IN_ROW;
  int* rs_ss  = rs_all + SS_ROW;

  // ---- CSR build (fused) ----
  hipMemsetAsync(bcnt, 0, NBTOT * sizeof(int), stream);
  k_bucket_count<<<GC, 256, 0, stream>>>(dst_vv, dst_h, dst_in, dst_ss, bcnt);
  k_bucket_scan<<<1, 512, 0, stream>>>(bcnt, bbase, cb);
  k_fill_s1_all<<<SB1, 256, 0, stream>>>(src_vv, dst_vv, et_vv, src_h, dst_h, ew_h,
                                         src_in, dst_in, src_ss, dst_ss, cb,
                                         temp_vv, temp_h, temp_in, temp_ss);
  k_fill_s2_all<<<NBTOT, 256, 0, stream>>>(temp_vv, temp_h, temp_in, temp_ss, bbase,
                                           payload_vv, eh, srcs_in, srcs_ss,
                                           rs_all, cnt_all, game_x, x_pad, dinvS);

  // ---- Phase A: v-graph 5-dim ----
  k_vv_pass1<<<nblk(NVV), 256, 0, stream>>>(x_pad, rs_vv, cnt_all, payload_vv, ra4all, h1p);
  k_vv_hop<<<nblk(NVV), 256, 0, stream>>>(h1p, rs_vv, cnt_all, payload_vv, h2p);
  k_vv_hop<<<nblk(NVV), 256, 0, stream>>>(h2p, rs_vv, cnt_all, payload_vv, h3p);
  k_combine_gx<<<dim3((NVV + 31) / 32), 256, 0, stream>>>(x_pad, ra4all, h1p, h2p, h3p,
                                                          W1_rel, W1_root, b1, W12, b12, gx16);

  // ---- Phase B: fused 64-dim bf16 gathers ----
  k_aggB<<<2 * NB64, 256, 0, stream>>>(gx16, rs_h, cnt_h, eh, rs_in, cnt_in, srcs_in,
                                       aggHw, aggHu, aggIN, NB64);

  // ---- Phase C: fused 4-MM chain -> S2 (+ dinv-prescaled bf16 shadow) ----
  k_mm_chainC<<<NB, 256, 0, stream>>>(aggHw, state_x, aggHu, cnt_h, aggIN, cnt_in,
                                      W3_rel, W3_root, b3, W32_l, W32_r, b32,
                                      W4_l, W4_r, b4, W42_l, W42_r, b42,
                                      S2, S2b, dinvS, NSV);

  // ---- Phase D: TAG on s-s (prescaled bf16 hops) + fused quad MM ----
  k_tag64b<<<NB64, 256, 0, stream>>>(S2b, rs_ss, cnt_ss, srcs_ss, dinvS, t1b, u1b, NSV);
  k_tag64b<<<NB64, 256, 0, stream>>>(u1b, rs_ss, cnt_ss, srcs_ss, dinvS, t2b, u2b, NSV);
  k_tag64b<<<NB64, 256, 0, stream>>>(u2b, rs_ss, cnt_ss, srcs_ss, dinvS, t3b, nullptr, NSV);
  k_mm_d<<<NB, 256, 0, stream>>>(S2, t1b, t2b, t3b, W2, b2, S1, S1b, NSV);

  // ---- Phase E: SAGE on s-s + final projection ----
  k_agg64b<<<NB64, 256, 0, stream>>>(S1b, rs_ss, cnt_ss, srcs_ss, aggSS, NSV);
  k_mm_e<<<NB, 256, 0, stream>>>(aggSS, cnt_ss, W5_l, S1, W5_r, b5, Wl, bl, (float*)d_out, NSV);
}